// Round 8
// baseline (684.843 us; speedup 1.0000x reference)
//
#include <hip/hip_runtime.h>
#include <hip/hip_bf16.h>
#include <cstddef>
#include <cstdint>

#define NA 50000
#define NB 10000
#define D_IN 32
#define D_OUT 64
#define EA2A 800000
#define EA2B 400000
#define EB2A 400000
#define NCAT (NA + NB + NA)
#define ETOT (EA2A + EA2B + EB2A)
#define NXCD 8
#define CHUNK (NCAT / NXCD)            // 13750 nodes per XCD-affine chunk
#define NSLICE 16
#define ESLICE (ETOT / NSLICE)         // 100000 edges per slice

typedef unsigned int u32;
typedef unsigned short u16;
typedef __attribute__((ext_vector_type(8))) short short8_t;
typedef __attribute__((ext_vector_type(4))) float f32x4;

// ---------------- helpers ----------------
__device__ __forceinline__ u32 bf16r(float x) {          // round-to-nearest-even bf16 bits
    u32 u = __float_as_uint(x);
    u += 0x7fffu + ((u >> 16) & 1u);
    return u >> 16;
}
__device__ __forceinline__ float ubf(u32 bits) { return __uint_as_float(bits); }
__device__ __forceinline__ float sigm(float x) { return 1.f / (1.f + __expf(-x)); }
__device__ __forceinline__ u32 cvtpk(float lo, float hi) {   // bf16(lo) | bf16(hi)<<16
    u32 r;
    asm("v_cvt_pk_bf16_f32 %0, %1, %2" : "=v"(r) : "v"(lo), "v"(hi));
    return r;
}

template <int CTRL, int RM>
__device__ __forceinline__ float dppf(float v) {
    return __int_as_float(__builtin_amdgcn_update_dpp(0, __float_as_int(v), CTRL, RM, 0xf, true));
}
__device__ __forceinline__ float wsum64(float v) {
    v += dppf<0x111, 0xf>(v);
    v += dppf<0x112, 0xf>(v);
    v += dppf<0x114, 0xf>(v);
    v += dppf<0x118, 0xf>(v);
    v += dppf<0x142, 0xa>(v);
    v += dppf<0x143, 0xc>(v);
    return __int_as_float(__builtin_amdgcn_readlane(__float_as_int(v), 63));
}
// max clamped at >= 0 (bound_ctrl injects 0) — safe: m only needs >= true max
__device__ __forceinline__ float wmax64(float v) {
    v = fmaxf(v, dppf<0x111, 0xf>(v));
    v = fmaxf(v, dppf<0x112, 0xf>(v));
    v = fmaxf(v, dppf<0x114, 0xf>(v));
    v = fmaxf(v, dppf<0x118, 0xf>(v));
    v = fmaxf(v, dppf<0x142, 0xa>(v));
    v = fmaxf(v, dppf<0x143, 0xc>(v));
    return __int_as_float(__builtin_amdgcn_readlane(__float_as_int(v), 63));
}

// ---------------- MFMA staging GEMM ----------------
struct MmArgs {
    const float* H; int ntiles;
    const float* W0; const float* W1;
    void* XS;
    const float* SW[8]; const float* SA[8]; float* SOUT[8];
    int sstride; int nsc;
};

template <int NMAT>
__global__ void __launch_bounds__(256) gemm_mfma(MmArgs a)
{
    __shared__ float wvec[8][64];
    __shared__ short8_t bfr[NMAT * 8 + 2][64];
    int t = threadIdx.x;
    for (int idx = t; idx < a.nsc * 64; idx += 256) {
        int c = idx >> 6, k = idx & 63;
        const float* w = a.SW[c] + k * 64;
        const float* av = a.SA[c];
        float s = 0.f;
#pragma unroll 16
        for (int e = 0; e < 64; ++e) s = fmaf(w[e], av[e], s);
        wvec[c][k] = s;
    }
    __syncthreads();
    for (int idx = t; idx < NMAT * 8 * 64; idx += 256) {
        int fid = idx >> 6, l = idx & 63;
        int m = fid >> 3, r3 = fid & 7, tn = r3 >> 1, q = r3 & 1;
        const float* W = (NMAT == 2 && m == 1) ? a.W1 : a.W0;
        int kbase = 32 * q + ((l >> 4) << 3);
        int d = 16 * tn + (l & 15);
        short8_t v;
#pragma unroll
        for (int e = 0; e < 8; ++e) v[e] = (short)bf16r(W[(size_t)(kbase + e) * 64 + d]);
        bfr[fid][l] = v;
    }
    for (int idx = t; idx < 128; idx += 256) {
        int q = idx >> 6, l = idx & 63;
        int c = l & 15;
        int kbase = 32 * q + ((l >> 4) << 3);
        short8_t v;
#pragma unroll
        for (int e = 0; e < 8; ++e) v[e] = (c < a.nsc) ? (short)bf16r(wvec[c][kbase + e]) : (short)0;
        bfr[NMAT * 8 + q][l] = v;
    }
    __syncthreads();
    int lane = t & 63, wid = t >> 6;
    short8_t bw[NMAT][4][2], bs0, bs1;
#pragma unroll
    for (int m = 0; m < NMAT; ++m)
#pragma unroll
        for (int tn = 0; tn < 4; ++tn)
#pragma unroll
            for (int q = 0; q < 2; ++q) bw[m][tn][q] = bfr[m * 8 + tn * 2 + q][lane];
    bs0 = bfr[NMAT * 8][lane];
    bs1 = bfr[NMAT * 8 + 1][lane];

    int rl = lane & 15, kg = lane >> 4;
    f32x4 zero = {0.f, 0.f, 0.f, 0.f};
    for (int tile = blockIdx.x * 4 + wid; tile < a.ntiles; tile += gridDim.x * 4) {
        const float4* hp = (const float4*)(a.H + (size_t)(tile * 16 + rl) * 64) + kg * 2;
        float4 a0 = hp[0], a1 = hp[1];
        float4 b0 = hp[8], b1 = hp[9];
        union { short8_t s; u32 w[4]; } A0, A1;
        A0.w[0] = cvtpk(a0.x, a0.y); A0.w[1] = cvtpk(a0.z, a0.w);
        A0.w[2] = cvtpk(a1.x, a1.y); A0.w[3] = cvtpk(a1.z, a1.w);
        A1.w[0] = cvtpk(b0.x, b0.y); A1.w[1] = cvtpk(b0.z, b0.w);
        A1.w[2] = cvtpk(b1.x, b1.y); A1.w[3] = cvtpk(b1.z, b1.w);

        f32x4 acc[NMAT][4];
#pragma unroll
        for (int m = 0; m < NMAT; ++m)
#pragma unroll
            for (int tn = 0; tn < 4; ++tn) {
                f32x4 c0 = __builtin_amdgcn_mfma_f32_16x16x32_bf16(A0.s, bw[m][tn][0], zero, 0, 0, 0);
                acc[m][tn] = __builtin_amdgcn_mfma_f32_16x16x32_bf16(A1.s, bw[m][tn][1], c0, 0, 0, 0);
            }
        f32x4 accs = __builtin_amdgcn_mfma_f32_16x16x32_bf16(A0.s, bs0, zero, 0, 0, 0);
        accs = __builtin_amdgcn_mfma_f32_16x16x32_bf16(A1.s, bs1, accs, 0, 0, 0);

        int rbase = tile * 16 + kg * 4;
        if (NMAT == 2) {
            u32* xo = (u32*)a.XS;
#pragma unroll
            for (int tn = 0; tn < 4; ++tn) {
                int d = tn * 16 + rl;
#pragma unroll
                for (int j = 0; j < 4; ++j)
                    xo[(size_t)(rbase + j) * 64 + d] = cvtpk(acc[0][tn][j], acc[1][tn][j]);
            }
        } else {
            u16* xo = (u16*)a.XS;
#pragma unroll
            for (int tn = 0; tn < 4; ++tn) {
                int d = tn * 16 + rl;
#pragma unroll
                for (int j = 0; j < 4; ++j)
                    xo[(size_t)(rbase + j) * 64 + d] = (u16)bf16r(acc[0][tn][j]);
            }
        }
        if (rl < a.nsc) {
            float* so = a.SOUT[rl];
#pragma unroll
            for (int j = 0; j < 4; ++j) so[(size_t)(rbase + j) * a.sstride] = accs[j];
        }
    }
}

// ---------------- dense precompute: d*(node,dim) = x @ Wx[g] + bx + sum(gat_b) ----
__global__ void __launch_bounds__(256) gemm_x_k(
    const float* __restrict__ xA, const float* __restrict__ xB,
    const float* __restrict__ Wx, const float* __restrict__ bx, const float* __restrict__ gb,
    u32* __restrict__ dzrA, u32* __restrict__ dzrB,
    u16* __restrict__ dnA, u16* __restrict__ dnB)
{
    __shared__ float Wsh[3 * 2048];
    __shared__ float cb[3 * 64];
    int t = threadIdx.x;
    int blk = blockIdx.x;
    bool isA = blk < (NA / 8);
    int ty = isA ? 0 : 1;
#pragma unroll
    for (int g = 0; g < 3; ++g) {
        const float4* s = (const float4*)(Wx + (size_t)(g * 2 + ty) * 2048);
        float4* d = (float4*)&Wsh[g * 2048];
        for (int i = t; i < 512; i += 256) d[i] = s[i];
    }
    if (t < 192) {
        int g = t >> 6, d = t & 63;
        float c = bx[(g * 2 + ty) * 64 + d];
        if (isA) c += gb[(g * 3 + 0) * 64 + d] + gb[(g * 3 + 2) * 64 + d];
        else     c += gb[(g * 3 + 1) * 64 + d];
        cb[t] = c;
    }
    __syncthreads();
    int lane = t & 63, wid = t >> 6;
    const float* X = isA ? xA : xB;
    int N = isA ? NA : NB;
    int rbase = (isA ? blk : blk - NA / 8) * 8 + wid * 2;
    float cz = cb[lane], cr = cb[64 + lane], cn = cb[128 + lane];
#pragma unroll
    for (int rr = 0; rr < 2; ++rr) {
        int r = rbase + rr;
        if (r >= N) break;
        float xv = (lane < 32) ? X[(size_t)r * 32 + lane] : 0.f;
        float az = cz, ar = cr, an = cn;
#pragma unroll
        for (int k = 0; k < 32; ++k) {
            float xk = __shfl(xv, k, 64);
            az = fmaf(xk, Wsh[k * 64 + lane], az);
            ar = fmaf(xk, Wsh[2048 + k * 64 + lane], ar);
            an = fmaf(xk, Wsh[4096 + k * 64 + lane], an);
        }
        u32 zr = bf16r(az) | (bf16r(ar) << 16);
        u16 nn = (u16)bf16r(an);
        if (isA) { dzrA[(size_t)r * 64 + lane] = zr; dnA[(size_t)r * 64 + lane] = nn; }
        else     { dzrB[(size_t)r * 64 + lane] = zr; dnB[(size_t)r * 64 + lane] = nn; }
    }
}

// ---------------- CSR build: no global atomics ----------------
// hist: block (chunk k, slice s) LDS-histograms slice s for chunk k's nodes,
// writes partial[s][g] with plain coalesced stores (fully overwritten -> no memset).
__global__ void __launch_bounds__(256) hist_k(
    const int* __restrict__ d0, const int* __restrict__ d1, const int* __restrict__ d2,
    int* __restrict__ partial)
{
    __shared__ int hcnt[CHUNK];
    int k = blockIdx.x & 7;
    int s = blockIdx.x >> 3;
    int lo = k * CHUNK;
    for (int i = threadIdx.x; i < CHUNK; i += 256) hcnt[i] = 0;
    __syncthreads();
    int e0 = s * ESLICE, e1 = e0 + ESLICE;
    for (int e = e0 + threadIdx.x; e < e1; e += 256) {
        int g;
        if (e < EA2A) g = d0[e];
        else if (e < EA2A + EA2B) g = NA + d1[e - EA2A];
        else g = NA + NB + d2[e - EA2A - EA2B];
        u32 rel = (u32)(g - lo);
        if (rel < CHUNK) atomicAdd(&hcnt[rel], 1);
    }
    __syncthreads();
    int* po = partial + s * NCAT + lo;
    for (int i = threadIdx.x; i < CHUNK; i += 256) po[i] = hcnt[i];
}

__global__ void scan_partial(const int* __restrict__ partial, int* __restrict__ bsum, int N)
{
    __shared__ int sd[256];
    int t = threadIdx.x;
    int i = blockIdx.x * 256 + t;
    int v = 0;
    if (i < N) {
#pragma unroll
        for (int s = 0; s < NSLICE; ++s) v += partial[s * NCAT + i];
    }
    sd[t] = v;
    __syncthreads();
    for (int off = 128; off; off >>= 1) {
        if (t < off) sd[t] += sd[t + off];
        __syncthreads();
    }
    if (t == 0) bsum[blockIdx.x] = sd[0];
}

__global__ void scan_tops(int* bsum, int nb)
{
    if (threadIdx.x == 0 && blockIdx.x == 0) {
        int run = 0;
        for (int b = 0; b < nb; ++b) { int v = bsum[b]; bsum[b] = run; run += v; }
    }
}

__global__ void scan_final(const int* __restrict__ partial, const int* __restrict__ bsum,
                           int* __restrict__ rowptr, int* __restrict__ cnt, int N)
{
    __shared__ int sd[256];
    int t = threadIdx.x;
    int i = blockIdx.x * 256 + t;
    int v = 0;
    if (i < N) {
#pragma unroll
        for (int s = 0; s < NSLICE; ++s) v += partial[s * NCAT + i];
    }
    sd[t] = v;
    __syncthreads();
    for (int off = 1; off < 256; off <<= 1) {
        int add = (t >= off) ? sd[t - off] : 0;
        __syncthreads();
        sd[t] += add;
        __syncthreads();
    }
    if (i < N) {
        rowptr[i] = bsum[blockIdx.x] + sd[t] - v;
        cnt[i] = v;
    }
}

// transform partial[s][g] in place into the slice's csr write offset
__global__ void soff_k(const int* __restrict__ rp, int* __restrict__ partial)
{
    int g = blockIdx.x * 256 + threadIdx.x;
    if (g >= NCAT) return;
    int run = rp[g];
#pragma unroll
    for (int s = 0; s < NSLICE; ++s) {
        int* p = &partial[s * NCAT + g];
        int v = *p;
        *p = run;
        run += v;
    }
}

__global__ void __launch_bounds__(256) fill_k(
    const int* __restrict__ s0, const int* __restrict__ d0,
    const int* __restrict__ s1, const int* __restrict__ d1,
    const int* __restrict__ s2, const int* __restrict__ d2,
    const int* __restrict__ partial, u16* __restrict__ csr)
{
    __shared__ int fpos[CHUNK];
    int k = blockIdx.x & 7;
    int s = blockIdx.x >> 3;
    int lo = k * CHUNK;
    const int* po = partial + s * NCAT + lo;
    for (int i = threadIdx.x; i < CHUNK; i += 256) fpos[i] = po[i];
    __syncthreads();
    int e0 = s * ESLICE, e1 = e0 + ESLICE;
    for (int e = e0 + threadIdx.x; e < e1; e += 256) {
        int g, sidx;
        const int* sp;
        if (e < EA2A) { g = d0[e]; sp = s0; sidx = e; }
        else if (e < EA2A + EA2B) { sidx = e - EA2A; g = NA + d1[sidx]; sp = s1; }
        else { sidx = e - EA2A - EA2B; g = NA + NB + d2[sidx]; sp = s2; }
        u32 rel = (u32)(g - lo);
        if (rel < CHUNK) {
            int src = sp[sidx];
            int p = atomicAdd(&fpos[rel], 1);   // LDS atomic only
            csr[p] = (u16)src;
        }
    }
}

// ---------------- GAT per-edge-type contributions ----------------
__device__ __forceinline__ void zr_fma(float az[4], float ar[4], uint4 v, float pz, float pr) {
    az[0] = fmaf(pz, ubf(v.x << 16), az[0]); ar[0] = fmaf(pr, ubf(v.x & 0xffff0000u), ar[0]);
    az[1] = fmaf(pz, ubf(v.y << 16), az[1]); ar[1] = fmaf(pr, ubf(v.y & 0xffff0000u), ar[1]);
    az[2] = fmaf(pz, ubf(v.z << 16), az[2]); ar[2] = fmaf(pr, ubf(v.z & 0xffff0000u), ar[2]);
    az[3] = fmaf(pz, ubf(v.w << 16), az[3]); ar[3] = fmaf(pr, ubf(v.w & 0xffff0000u), ar[3]);
}

__device__ __forceinline__ void gat_zr_et(
    int gnode, int inode, int lane, int sub, int grp,
    const int* __restrict__ rp, const int* __restrict__ cnt, const u16* __restrict__ csr,
    const float2* __restrict__ als, const float2* __restrict__ ald,
    const uint4* __restrict__ xs,
    float oz[4], float orr[4])
{
    int deg = cnt[gnode];
    if (deg <= 0) return;
    int beg = rp[gnode];
    float2 ad = ald[inode];
    float mz = 0.f, mr = 0.f, sz = 0.f, sr = 0.f;
    float az[4] = {0.f, 0.f, 0.f, 0.f}, ar[4] = {0.f, 0.f, 0.f, 0.f};
    for (int base = 0; base < deg; base += 64) {
        int j = base + lane;
        int sj = 0; float ez = -1e30f, er = -1e30f;
        if (j < deg) {
            sj = csr[beg + j];
            float2 al = als[sj];
            float tz = al.x + ad.x; ez = tz > 0.f ? tz : 0.2f * tz;
            float tr = al.y + ad.y; er = tr > 0.f ? tr : 0.2f * tr;
        }
        float cmz = wmax64(ez), cmr = wmax64(er);
        if (base == 0) { mz = cmz; mr = cmr; }
        else {
            if (cmz > mz) { float s = __expf(mz - cmz);
                az[0] *= s; az[1] *= s; az[2] *= s; az[3] *= s; sz *= s; mz = cmz; }
            if (cmr > mr) { float s = __expf(mr - cmr);
                ar[0] *= s; ar[1] *= s; ar[2] *= s; ar[3] *= s; sr *= s; mr = cmr; }
        }
        float pz = (j < deg) ? __expf(ez - mz) : 0.f;
        float pr = (j < deg) ? __expf(er - mr) : 0.f;
        sz += wsum64(pz);
        sr += wsum64(pr);
        u32 pk = (u32)sj | (bf16r(pz) << 16);   // invalid lanes: pk=0 -> contributes 0
        int c = deg - base; if (c > 64) c = 64;
        int b = 0;
        for (; b + 16 <= c; b += 16) {
            u32 k0 = (u32)__shfl((int)pk, b + grp, 64);
            u32 k1 = (u32)__shfl((int)pk, b + 4 + grp, 64);
            u32 k2 = (u32)__shfl((int)pk, b + 8 + grp, 64);
            u32 k3 = (u32)__shfl((int)pk, b + 12 + grp, 64);
            float q0 = __shfl(pr, b + grp, 64);
            float q1 = __shfl(pr, b + 4 + grp, 64);
            float q2 = __shfl(pr, b + 8 + grp, 64);
            float q3 = __shfl(pr, b + 12 + grp, 64);
            uint4 v0 = xs[(size_t)(k0 & 0xffffu) * 16 + sub];
            uint4 v1 = xs[(size_t)(k1 & 0xffffu) * 16 + sub];
            uint4 v2 = xs[(size_t)(k2 & 0xffffu) * 16 + sub];
            uint4 v3 = xs[(size_t)(k3 & 0xffffu) * 16 + sub];
            zr_fma(az, ar, v0, ubf(k0 & 0xffff0000u), q0);
            zr_fma(az, ar, v1, ubf(k1 & 0xffff0000u), q1);
            zr_fma(az, ar, v2, ubf(k2 & 0xffff0000u), q2);
            zr_fma(az, ar, v3, ubf(k3 & 0xffff0000u), q3);
        }
        for (; b < c; b += 4) {
            u32 k0 = (u32)__shfl((int)pk, b + grp, 64);
            float q0 = __shfl(pr, b + grp, 64);
            uint4 v0 = xs[(size_t)(k0 & 0xffffu) * 16 + sub];
            zr_fma(az, ar, v0, ubf(k0 & 0xffff0000u), q0);
        }
    }
    float rz = 1.f / (sz + 1e-16f), rr = 1.f / (sr + 1e-16f);
    oz[0] = fmaf(az[0], rz, oz[0]); orr[0] = fmaf(ar[0], rr, orr[0]);
    oz[1] = fmaf(az[1], rz, oz[1]); orr[1] = fmaf(ar[1], rr, orr[1]);
    oz[2] = fmaf(az[2], rz, oz[2]); orr[2] = fmaf(ar[2], rr, orr[2]);
    oz[3] = fmaf(az[3], rz, oz[3]); orr[3] = fmaf(ar[3], rr, orr[3]);
}

__device__ __forceinline__ void n_fma(float a[4], uint2 v, float p) {
    a[0] = fmaf(p, ubf(v.x << 16), a[0]);
    a[1] = fmaf(p, ubf(v.x & 0xffff0000u), a[1]);
    a[2] = fmaf(p, ubf(v.y << 16), a[2]);
    a[3] = fmaf(p, ubf(v.y & 0xffff0000u), a[3]);
}

__device__ __forceinline__ void gat_n_et(
    int gnode, int inode, int lane, int sub, int grp,
    const int* __restrict__ rp, const int* __restrict__ cnt, const u16* __restrict__ csr,
    const float* __restrict__ als, const float* __restrict__ ald,
    const uint2* __restrict__ xs,
    float oa[4])
{
    int deg = cnt[gnode];
    if (deg <= 0) return;
    int beg = rp[gnode];
    float ad = ald[inode];
    float m = 0.f, ss = 0.f;
    float ac[4] = {0.f, 0.f, 0.f, 0.f};
    for (int base = 0; base < deg; base += 64) {
        int j = base + lane;
        int sj = 0; float e = -1e30f;
        if (j < deg) {
            sj = csr[beg + j];
            float tv = als[sj] + ad;
            e = tv > 0.f ? tv : 0.2f * tv;
        }
        float cm = wmax64(e);
        if (base == 0) m = cm;
        else if (cm > m) {
            float s = __expf(m - cm);
            ac[0] *= s; ac[1] *= s; ac[2] *= s; ac[3] *= s; ss *= s; m = cm;
        }
        float p = (j < deg) ? __expf(e - m) : 0.f;
        ss += wsum64(p);
        u32 pk = (u32)sj | (bf16r(p) << 16);
        int c = deg - base; if (c > 64) c = 64;
        int b = 0;
        for (; b + 16 <= c; b += 16) {
            u32 k0 = (u32)__shfl((int)pk, b + grp, 64);
            u32 k1 = (u32)__shfl((int)pk, b + 4 + grp, 64);
            u32 k2 = (u32)__shfl((int)pk, b + 8 + grp, 64);
            u32 k3 = (u32)__shfl((int)pk, b + 12 + grp, 64);
            uint2 v0 = xs[(size_t)(k0 & 0xffffu) * 16 + sub];
            uint2 v1 = xs[(size_t)(k1 & 0xffffu) * 16 + sub];
            uint2 v2 = xs[(size_t)(k2 & 0xffffu) * 16 + sub];
            uint2 v3 = xs[(size_t)(k3 & 0xffffu) * 16 + sub];
            n_fma(ac, v0, ubf(k0 & 0xffff0000u));
            n_fma(ac, v1, ubf(k1 & 0xffff0000u));
            n_fma(ac, v2, ubf(k2 & 0xffff0000u));
            n_fma(ac, v3, ubf(k3 & 0xffff0000u));
        }
        for (; b < c; b += 4) {
            u32 k0 = (u32)__shfl((int)pk, b + grp, 64);
            uint2 v0 = xs[(size_t)(k0 & 0xffffu) * 16 + sub];
            n_fma(ac, v0, ubf(k0 & 0xffff0000u));
        }
    }
    float rs = 1.f / (ss + 1e-16f);
    oa[0] = fmaf(ac[0], rs, oa[0]);
    oa[1] = fmaf(ac[1], rs, oa[1]);
    oa[2] = fmaf(ac[2], rs, oa[2]);
    oa[3] = fmaf(ac[3], rs, oa[3]);
}

// ---------------- aggregate kernels (A and B merged) ----------------
struct ZrArgs {
    const int *rp, *cnt;
    const u16 *csr;
    const float2 *als0, *ald0, *als1, *ald1, *als2, *ald2;
    const uint4 *xs0, *xs1, *xs2;
    const u32 *dzrA, *dzrB;
    const float *hA, *hB;
    float *zA, *rhA, *zB, *rhB;
};

__global__ void __launch_bounds__(256) aggregate_zr_k(ZrArgs P)
{
    int t = threadIdx.x, lane = t & 63, wid = t >> 6;
    int sub = lane & 15, grp = lane >> 4;
    float oz[4] = {0.f, 0.f, 0.f, 0.f}, orr[4] = {0.f, 0.f, 0.f, 0.f};
    int blk = blockIdx.x;
    const u32* dzr; const float* Hp; float *Zp, *RHp;
    if (blk < NA / 4) {
        int i = blk * 4 + wid;
        gat_zr_et(i, i, lane, sub, grp, P.rp, P.cnt, P.csr, P.als0, P.ald0, P.xs0, oz, orr);
        gat_zr_et(NA + NB + i, i, lane, sub, grp, P.rp, P.cnt, P.csr, P.als2, P.ald2, P.xs2, oz, orr);
        dzr = P.dzrA + (size_t)i * 64; Hp = P.hA + (size_t)i * 64;
        Zp = P.zA + (size_t)i * 64; RHp = P.rhA + (size_t)i * 64;
    } else {
        int i = (blk - NA / 4) * 4 + wid;
        gat_zr_et(NA + i, i, lane, sub, grp, P.rp, P.cnt, P.csr, P.als1, P.ald1, P.xs1, oz, orr);
        dzr = P.dzrB + (size_t)i * 64; Hp = P.hB + (size_t)i * 64;
        Zp = P.zB + (size_t)i * 64; RHp = P.rhB + (size_t)i * 64;
    }
#pragma unroll
    for (int q = 0; q < 4; ++q) {
        oz[q] += __shfl_xor(oz[q], 16, 64); oz[q] += __shfl_xor(oz[q], 32, 64);
        orr[q] += __shfl_xor(orr[q], 16, 64); orr[q] += __shfl_xor(orr[q], 32, 64);
    }
    if (grp == 0) {
        uint4 d = *(const uint4*)(dzr + sub * 4);
        float4 h = *(const float4*)(Hp + sub * 4);
        float z0 = sigm(oz[0] + ubf(d.x << 16)), r0 = sigm(orr[0] + ubf(d.x & 0xffff0000u)) * h.x;
        float z1 = sigm(oz[1] + ubf(d.y << 16)), r1 = sigm(orr[1] + ubf(d.y & 0xffff0000u)) * h.y;
        float z2 = sigm(oz[2] + ubf(d.z << 16)), r2 = sigm(orr[2] + ubf(d.z & 0xffff0000u)) * h.z;
        float z3 = sigm(oz[3] + ubf(d.w << 16)), r3 = sigm(orr[3] + ubf(d.w & 0xffff0000u)) * h.w;
        *(float4*)(Zp + sub * 4) = make_float4(z0, z1, z2, z3);
        *(float4*)(RHp + sub * 4) = make_float4(r0, r1, r2, r3);
    }
}

struct NArgs {
    const int *rp, *cnt;
    const u16 *csr;
    const float *als0, *ald0, *als1, *ald1, *als2, *ald2;
    const uint2 *xs0, *xs1, *xs2;
    const u16 *dnA, *dnB;
    const float *hA, *hB, *zA, *zB;
    float *outA, *outB;
};

__global__ void __launch_bounds__(256) aggregate_n_k(NArgs P)
{
    int t = threadIdx.x, lane = t & 63, wid = t >> 6;
    int sub = lane & 15, grp = lane >> 4;
    float oa[4] = {0.f, 0.f, 0.f, 0.f};
    int blk = blockIdx.x;
    const u16* dn; const float *Hp, *Zp; float* Op;
    if (blk < NA / 4) {
        int i = blk * 4 + wid;
        gat_n_et(i, i, lane, sub, grp, P.rp, P.cnt, P.csr, P.als0, P.ald0, P.xs0, oa);
        gat_n_et(NA + NB + i, i, lane, sub, grp, P.rp, P.cnt, P.csr, P.als2, P.ald2, P.xs2, oa);
        dn = P.dnA + (size_t)i * 64; Hp = P.hA + (size_t)i * 64;
        Zp = P.zA + (size_t)i * 64; Op = P.outA + (size_t)i * 64;
    } else {
        int i = (blk - NA / 4) * 4 + wid;
        gat_n_et(NA + i, i, lane, sub, grp, P.rp, P.cnt, P.csr, P.als1, P.ald1, P.xs1, oa);
        dn = P.dnB + (size_t)i * 64; Hp = P.hB + (size_t)i * 64;
        Zp = P.zB + (size_t)i * 64; Op = P.outB + (size_t)i * 64;
    }
#pragma unroll
    for (int q = 0; q < 4; ++q) {
        oa[q] += __shfl_xor(oa[q], 16, 64); oa[q] += __shfl_xor(oa[q], 32, 64);
    }
    if (grp == 0) {
        uint2 d = *(const uint2*)(dn + sub * 4);
        float4 h = *(const float4*)(Hp + sub * 4);
        float4 zv = *(const float4*)(Zp + sub * 4);
        float pre[4];
        pre[0] = oa[0] + ubf(d.x << 16);
        pre[1] = oa[1] + ubf(d.x & 0xffff0000u);
        pre[2] = oa[2] + ubf(d.y << 16);
        pre[3] = oa[3] + ubf(d.y & 0xffff0000u);
        float o[4];
        float hh[4] = {h.x, h.y, h.z, h.w};
        float zz[4] = {zv.x, zv.y, zv.z, zv.w};
#pragma unroll
        for (int q = 0; q < 4; ++q) {
            float x2 = fminf(fmaxf(pre[q] * 2.f, -30.f), 30.f);
            float ex = __expf(x2);
            float nv = (ex - 1.f) / (ex + 1.f);
            o[q] = (1.f - zz[q]) * nv + zz[q] * hh[q];
        }
        *(float4*)(Op + sub * 4) = make_float4(o[0], o[1], o[2], o[3]);
    }
}

// ---------------- host side ----------------
extern "C" void kernel_launch(void* const* d_in, const int* in_sizes, int n_in,
                              void* d_out, int out_size, void* d_ws, size_t ws_size,
                              hipStream_t stream)
{
    (void)in_sizes; (void)n_in; (void)out_size; (void)ws_size;
    const float* x_a = (const float*)d_in[0];
    const float* x_b = (const float*)d_in[1];
    const float* h_a = (const float*)d_in[2];
    const float* h_b = (const float*)d_in[3];
    const float* Wx  = (const float*)d_in[4];
    const float* bx  = (const float*)d_in[5];
    const float* gws = (const float*)d_in[6];
    const float* gwd = (const float*)d_in[7];
    const float* gas = (const float*)d_in[8];
    const float* gad = (const float*)d_in[9];
    const float* gb  = (const float*)d_in[10];
    const int* ea2a_s = (const int*)d_in[11];
    const int* ea2a_d = (const int*)d_in[12];
    const int* ea2b_s = (const int*)d_in[13];
    const int* ea2b_d = (const int*)d_in[14];
    const int* eb2a_s = (const int*)d_in[15];
    const int* eb2a_d = (const int*)d_in[16];
    float* out = (float*)d_out;

    char* w = (char*)d_ws;
    auto alloc = [&](size_t bytes) -> char* {
        char* p = w;
        w += (bytes + 255) & ~(size_t)255;
        return p;
    };
    char* xsblk = alloc((size_t)(NA + NA + NB) * 64 * 4);
    u32* xs_zr0 = (u32*)xsblk;
    u32* xs_zr1 = (u32*)(xsblk + (size_t)NA * 64 * 4);
    u32* xs_zr2 = (u32*)(xsblk + (size_t)(NA + NA) * 64 * 4);
    u16* xs_n0 = (u16*)xsblk;
    u16* xs_n1 = (u16*)(xsblk + (size_t)NA * 64 * 2);
    u16* xs_n2 = (u16*)(xsblk + (size_t)(NA + NA) * 64 * 2);
    char* alblk = alloc((size_t)(4 * NA + 2 * NB) * 2 * 4);
    float* als_zr0 = (float*)alblk;
    float* als_zr1 = als_zr0 + (size_t)NA * 2;
    float* als_zr2 = als_zr1 + (size_t)NA * 2;
    float* ald_zr0 = als_zr2 + (size_t)NB * 2;
    float* ald_zr1 = ald_zr0 + (size_t)NA * 2;
    float* ald_zr2 = ald_zr1 + (size_t)NB * 2;
    float* als_n0 = (float*)alblk;
    float* als_n1 = als_n0 + NA;
    float* als_n2 = als_n1 + NA;
    float* ald_n0 = als_n2 + NB;
    float* ald_n1 = ald_n0 + NA;
    float* ald_n2 = ald_n1 + NB;
    float* zbuf  = (float*)alloc((size_t)(NA + NB) * 64 * 4);
    float* rhbuf = (float*)alloc((size_t)(NA + NB) * 64 * 4);
    u32* dzrA = (u32*)alloc((size_t)NA * 64 * 4);
    u32* dzrB = (u32*)alloc((size_t)NB * 64 * 4);
    u16* dnA = (u16*)alloc((size_t)NA * 64 * 2);
    u16* dnB = (u16*)alloc((size_t)NB * 64 * 2);
    int* partial = (int*)alloc((size_t)NSLICE * NCAT * 4);
    int* cnt = (int*)alloc((size_t)NCAT * 4);
    int* rp  = (int*)alloc((size_t)NCAT * 4);
    u16* csr = (u16*)alloc((size_t)ETOT * 2);
    int* bsum = (int*)alloc(512 * 4);

    const int nbC = (NCAT + 255) / 256;

    // ---- CSR build (no global atomics, no memset) ----
    hist_k<<<NXCD * NSLICE, 256, 0, stream>>>(ea2a_d, ea2b_d, eb2a_d, partial);
    scan_partial<<<nbC, 256, 0, stream>>>(partial, bsum, NCAT);
    scan_tops<<<1, 64, 0, stream>>>(bsum, nbC);
    scan_final<<<nbC, 256, 0, stream>>>(partial, bsum, rp, cnt, NCAT);
    soff_k<<<nbC, 256, 0, stream>>>(rp, partial);
    fill_k<<<NXCD * NSLICE, 256, 0, stream>>>(ea2a_s, ea2a_d, ea2b_s, ea2b_d, eb2a_s, eb2a_d,
                                              partial, csr);

    // ---- dense precompute (all 3 gates, both node types) ----
    gemm_x_k<<<(NA + NB) / 8, 256, 0, stream>>>(x_a, x_b, Wx, bx, gb, dzrA, dzrB, dnA, dnB);

    float* rh_a = rhbuf;
    float* rh_b = rhbuf + (size_t)NA * 64;
    float* z_a = zbuf;
    float* z_b = zbuf + (size_t)NA * 64;

    // ---- z+r MFMA GEMMs ----
    {
        MmArgs a{};
        a.H = h_a; a.ntiles = NA / 16;
        a.W0 = gws + 0 * 4096; a.W1 = gws + 3 * 4096;
        a.XS = xs_zr0;
        a.SW[0] = gws + 0 * 4096; a.SA[0] = gas + 0 * 64; a.SOUT[0] = als_zr0;
        a.SW[1] = gws + 3 * 4096; a.SA[1] = gas + 3 * 64; a.SOUT[1] = als_zr0 + 1;
        a.SW[2] = gws + 1 * 4096; a.SA[2] = gas + 1 * 64; a.SOUT[2] = als_zr1;
        a.SW[3] = gws + 4 * 4096; a.SA[3] = gas + 4 * 64; a.SOUT[3] = als_zr1 + 1;
        a.SW[4] = gwd + 0 * 4096; a.SA[4] = gad + 0 * 64; a.SOUT[4] = ald_zr0;
        a.SW[5] = gwd + 3 * 4096; a.SA[5] = gad + 3 * 64; a.SOUT[5] = ald_zr0 + 1;
        a.SW[6] = gwd + 2 * 4096; a.SA[6] = gad + 2 * 64; a.SOUT[6] = ald_zr2;
        a.SW[7] = gwd + 5 * 4096; a.SA[7] = gad + 5 * 64; a.SOUT[7] = ald_zr2 + 1;
        a.sstride = 2; a.nsc = 8;
        gemm_mfma<2><<<320, 256, 0, stream>>>(a);
    }
    {
        MmArgs a{};
        a.H = h_a; a.ntiles = NA / 16;
        a.W0 = gws + 1 * 4096; a.W1 = gws + 4 * 4096;
        a.XS = xs_zr1;
        a.sstride = 1; a.nsc = 0;
        gemm_mfma<2><<<320, 256, 0, stream>>>(a);
    }
    {
        MmArgs a{};
        a.H = h_b; a.ntiles = NB / 16;
        a.W0 = gws + 2 * 4096; a.W1 = gws + 5 * 4096;
        a.XS = xs_zr2;
        a.SW[0] = gws + 2 * 4096; a.SA[0] = gas + 2 * 64; a.SOUT[0] = als_zr2;
        a.SW[1] = gws + 5 * 4096; a.SA[1] = gas + 5 * 64; a.SOUT[1] = als_zr2 + 1;
        a.SW[2] = gwd + 1 * 4096; a.SA[2] = gad + 1 * 64; a.SOUT[2] = ald_zr1;
        a.SW[3] = gwd + 4 * 4096; a.SA[3] = gad + 4 * 64; a.SOUT[3] = ald_zr1 + 1;
        a.sstride = 2; a.nsc = 4;
        gemm_mfma<2><<<80, 256, 0, stream>>>(a);
    }

    // ---- z+r aggregation ----
    {
        ZrArgs P{};
        P.rp = rp; P.cnt = cnt; P.csr = csr;
        P.als0 = (const float2*)als_zr0; P.ald0 = (const float2*)ald_zr0;
        P.als1 = (const float2*)als_zr1; P.ald1 = (const float2*)ald_zr1;
        P.als2 = (const float2*)als_zr2; P.ald2 = (const float2*)ald_zr2;
        P.xs0 = (const uint4*)xs_zr0; P.xs1 = (const uint4*)xs_zr1; P.xs2 = (const uint4*)xs_zr2;
        P.dzrA = dzrA; P.dzrB = dzrB;
        P.hA = h_a; P.hB = h_b;
        P.zA = z_a; P.rhA = rh_a; P.zB = z_b; P.rhB = rh_b;
        aggregate_zr_k<<<(NA + NB) / 4, 256, 0, stream>>>(P);
    }

    // ---- n MFMA GEMMs (input rh) ----
    {
        MmArgs a{};
        a.H = rh_a; a.ntiles = NA / 16;
        a.W0 = gws + 6 * 4096; a.W1 = nullptr;
        a.XS = xs_n0;
        a.SW[0] = gws + 6 * 4096; a.SA[0] = gas + 6 * 64; a.SOUT[0] = als_n0;
        a.SW[1] = gws + 7 * 4096; a.SA[1] = gas + 7 * 64; a.SOUT[1] = als_n1;
        a.SW[2] = gwd + 6 * 4096; a.SA[2] = gad + 6 * 64; a.SOUT[2] = ald_n0;
        a.SW[3] = gwd + 8 * 4096; a.SA[3] = gad + 8 * 64; a.SOUT[3] = ald_n2;
        a.sstride = 1; a.nsc = 4;
        gemm_mfma<1><<<320, 256, 0, stream>>>(a);
    }
    {
        MmArgs a{};
        a.H = rh_a; a.ntiles = NA / 16;
        a.W0 = gws + 7 * 4096; a.W1 = nullptr;
        a.XS = xs_n1;
        a.sstride = 1; a.nsc = 0;
        gemm_mfma<1><<<320, 256, 0, stream>>>(a);
    }
    {
        MmArgs a{};
        a.H = rh_b; a.ntiles = NB / 16;
        a.W0 = gws + 8 * 4096; a.W1 = nullptr;
        a.XS = xs_n2;
        a.SW[0] = gws + 8 * 4096; a.SA[0] = gas + 8 * 64; a.SOUT[0] = als_n2;
        a.SW[1] = gwd + 7 * 4096; a.SA[1] = gad + 7 * 64; a.SOUT[1] = ald_n1;
        a.sstride = 1; a.nsc = 2;
        gemm_mfma<1><<<80, 256, 0, stream>>>(a);
    }

    // ---- n aggregation + GRU combine ----
    {
        NArgs P{};
        P.rp = rp; P.cnt = cnt; P.csr = csr;
        P.als0 = als_n0; P.ald0 = ald_n0;
        P.als1 = als_n1; P.ald1 = ald_n1;
        P.als2 = als_n2; P.ald2 = ald_n2;
        P.xs0 = (const uint2*)xs_n0; P.xs1 = (const uint2*)xs_n1; P.xs2 = (const uint2*)xs_n2;
        P.dnA = dnA; P.dnB = dnB;
        P.hA = h_a; P.hB = h_b; P.zA = z_a; P.zB = z_b;
        P.outA = out; P.outB = out + (size_t)NA * 64;
        aggregate_n_k<<<(NA + NB) / 4, 256, 0, stream>>>(P);
    }
}

// Round 9
// 327.634 us; speedup vs baseline: 2.0903x; 2.0903x over previous
//
#include <hip/hip_runtime.h>
#include <hip/hip_bf16.h>
#include <cstddef>
#include <cstdint>

#define NA 50000
#define NB 10000
#define D_IN 32
#define D_OUT 64
#define EA2A 800000
#define EA2B 400000
#define EB2A 400000
#define NCAT (NA + NB + NA)
#define ETOT (EA2A + EA2B + EB2A)
#define NCHUNK 8
#define CHUNK (NCAT / NCHUNK)          // 13750 nodes per chunk (55KB LDS)
#define NSLICE 64
#define ESLICE (ETOT / NSLICE)         // 25000 edges per slice

typedef unsigned int u32;
typedef unsigned short u16;
typedef __attribute__((ext_vector_type(8))) short short8_t;
typedef __attribute__((ext_vector_type(4))) float f32x4;

// ---------------- helpers ----------------
__device__ __forceinline__ u32 bf16r(float x) {          // round-to-nearest-even bf16 bits
    u32 u = __float_as_uint(x);
    u += 0x7fffu + ((u >> 16) & 1u);
    return u >> 16;
}
__device__ __forceinline__ float ubf(u32 bits) { return __uint_as_float(bits); }
__device__ __forceinline__ float sigm(float x) { return 1.f / (1.f + __expf(-x)); }
__device__ __forceinline__ u32 cvtpk(float lo, float hi) {   // bf16(lo) | bf16(hi)<<16
    u32 r;
    asm("v_cvt_pk_bf16_f32 %0, %1, %2" : "=v"(r) : "v"(lo), "v"(hi));
    return r;
}

template <int CTRL, int RM>
__device__ __forceinline__ float dppf(float v) {
    return __int_as_float(__builtin_amdgcn_update_dpp(0, __float_as_int(v), CTRL, RM, 0xf, true));
}
__device__ __forceinline__ float wsum64(float v) {
    v += dppf<0x111, 0xf>(v);
    v += dppf<0x112, 0xf>(v);
    v += dppf<0x114, 0xf>(v);
    v += dppf<0x118, 0xf>(v);
    v += dppf<0x142, 0xa>(v);
    v += dppf<0x143, 0xc>(v);
    return __int_as_float(__builtin_amdgcn_readlane(__float_as_int(v), 63));
}
// max clamped at >= 0 (bound_ctrl injects 0) — safe: m only needs >= true max
__device__ __forceinline__ float wmax64(float v) {
    v = fmaxf(v, dppf<0x111, 0xf>(v));
    v = fmaxf(v, dppf<0x112, 0xf>(v));
    v = fmaxf(v, dppf<0x114, 0xf>(v));
    v = fmaxf(v, dppf<0x118, 0xf>(v));
    v = fmaxf(v, dppf<0x142, 0xa>(v));
    v = fmaxf(v, dppf<0x143, 0xc>(v));
    return __int_as_float(__builtin_amdgcn_readlane(__float_as_int(v), 63));
}

// ---------------- MFMA staging GEMM ----------------
struct MmArgs {
    const float* H; int ntiles;
    const float* W0; const float* W1;
    void* XS;
    const float* SW[8]; const float* SA[8]; float* SOUT[8];
    int sstride; int nsc;
};

template <int NMAT>
__global__ void __launch_bounds__(256) gemm_mfma(MmArgs a)
{
    __shared__ float wvec[8][64];
    __shared__ short8_t bfr[NMAT * 8 + 2][64];
    int t = threadIdx.x;
    for (int idx = t; idx < a.nsc * 64; idx += 256) {
        int c = idx >> 6, k = idx & 63;
        const float* w = a.SW[c] + k * 64;
        const float* av = a.SA[c];
        float s = 0.f;
#pragma unroll 16
        for (int e = 0; e < 64; ++e) s = fmaf(w[e], av[e], s);
        wvec[c][k] = s;
    }
    __syncthreads();
    for (int idx = t; idx < NMAT * 8 * 64; idx += 256) {
        int fid = idx >> 6, l = idx & 63;
        int m = fid >> 3, r3 = fid & 7, tn = r3 >> 1, q = r3 & 1;
        const float* W = (NMAT == 2 && m == 1) ? a.W1 : a.W0;
        int kbase = 32 * q + ((l >> 4) << 3);
        int d = 16 * tn + (l & 15);
        short8_t v;
#pragma unroll
        for (int e = 0; e < 8; ++e) v[e] = (short)bf16r(W[(size_t)(kbase + e) * 64 + d]);
        bfr[fid][l] = v;
    }
    for (int idx = t; idx < 128; idx += 256) {
        int q = idx >> 6, l = idx & 63;
        int c = l & 15;
        int kbase = 32 * q + ((l >> 4) << 3);
        short8_t v;
#pragma unroll
        for (int e = 0; e < 8; ++e) v[e] = (c < a.nsc) ? (short)bf16r(wvec[c][kbase + e]) : (short)0;
        bfr[NMAT * 8 + q][l] = v;
    }
    __syncthreads();
    int lane = t & 63, wid = t >> 6;
    short8_t bw[NMAT][4][2], bs0, bs1;
#pragma unroll
    for (int m = 0; m < NMAT; ++m)
#pragma unroll
        for (int tn = 0; tn < 4; ++tn)
#pragma unroll
            for (int q = 0; q < 2; ++q) bw[m][tn][q] = bfr[m * 8 + tn * 2 + q][lane];
    bs0 = bfr[NMAT * 8][lane];
    bs1 = bfr[NMAT * 8 + 1][lane];

    int rl = lane & 15, kg = lane >> 4;
    f32x4 zero = {0.f, 0.f, 0.f, 0.f};
    for (int tile = blockIdx.x * 4 + wid; tile < a.ntiles; tile += gridDim.x * 4) {
        const float4* hp = (const float4*)(a.H + (size_t)(tile * 16 + rl) * 64) + kg * 2;
        float4 a0 = hp[0], a1 = hp[1];
        float4 b0 = hp[8], b1 = hp[9];
        union { short8_t s; u32 w[4]; } A0, A1;
        A0.w[0] = cvtpk(a0.x, a0.y); A0.w[1] = cvtpk(a0.z, a0.w);
        A0.w[2] = cvtpk(a1.x, a1.y); A0.w[3] = cvtpk(a1.z, a1.w);
        A1.w[0] = cvtpk(b0.x, b0.y); A1.w[1] = cvtpk(b0.z, b0.w);
        A1.w[2] = cvtpk(b1.x, b1.y); A1.w[3] = cvtpk(b1.z, b1.w);

        f32x4 acc[NMAT][4];
#pragma unroll
        for (int m = 0; m < NMAT; ++m)
#pragma unroll
            for (int tn = 0; tn < 4; ++tn) {
                f32x4 c0 = __builtin_amdgcn_mfma_f32_16x16x32_bf16(A0.s, bw[m][tn][0], zero, 0, 0, 0);
                acc[m][tn] = __builtin_amdgcn_mfma_f32_16x16x32_bf16(A1.s, bw[m][tn][1], c0, 0, 0, 0);
            }
        f32x4 accs = __builtin_amdgcn_mfma_f32_16x16x32_bf16(A0.s, bs0, zero, 0, 0, 0);
        accs = __builtin_amdgcn_mfma_f32_16x16x32_bf16(A1.s, bs1, accs, 0, 0, 0);

        int rbase = tile * 16 + kg * 4;
        if (NMAT == 2) {
            u32* xo = (u32*)a.XS;
#pragma unroll
            for (int tn = 0; tn < 4; ++tn) {
                int d = tn * 16 + rl;
#pragma unroll
                for (int j = 0; j < 4; ++j)
                    xo[(size_t)(rbase + j) * 64 + d] = cvtpk(acc[0][tn][j], acc[1][tn][j]);
            }
        } else {
            u16* xo = (u16*)a.XS;
#pragma unroll
            for (int tn = 0; tn < 4; ++tn) {
                int d = tn * 16 + rl;
#pragma unroll
                for (int j = 0; j < 4; ++j)
                    xo[(size_t)(rbase + j) * 64 + d] = (u16)bf16r(acc[0][tn][j]);
            }
        }
        if (rl < a.nsc) {
            float* so = a.SOUT[rl];
#pragma unroll
            for (int j = 0; j < 4; ++j) so[(size_t)(rbase + j) * a.sstride] = accs[j];
        }
    }
}

// ---------------- dense precompute: d*(node,dim) = x @ Wx[g] + bx + sum(gat_b) ----
__global__ void __launch_bounds__(256) gemm_x_k(
    const float* __restrict__ xA, const float* __restrict__ xB,
    const float* __restrict__ Wx, const float* __restrict__ bx, const float* __restrict__ gb,
    u32* __restrict__ dzrA, u32* __restrict__ dzrB,
    u16* __restrict__ dnA, u16* __restrict__ dnB)
{
    __shared__ float Wsh[3 * 2048];
    __shared__ float cb[3 * 64];
    int t = threadIdx.x;
    int blk = blockIdx.x;
    bool isA = blk < (NA / 8);
    int ty = isA ? 0 : 1;
#pragma unroll
    for (int g = 0; g < 3; ++g) {
        const float4* s = (const float4*)(Wx + (size_t)(g * 2 + ty) * 2048);
        float4* d = (float4*)&Wsh[g * 2048];
        for (int i = t; i < 512; i += 256) d[i] = s[i];
    }
    if (t < 192) {
        int g = t >> 6, d = t & 63;
        float c = bx[(g * 2 + ty) * 64 + d];
        if (isA) c += gb[(g * 3 + 0) * 64 + d] + gb[(g * 3 + 2) * 64 + d];
        else     c += gb[(g * 3 + 1) * 64 + d];
        cb[t] = c;
    }
    __syncthreads();
    int lane = t & 63, wid = t >> 6;
    const float* X = isA ? xA : xB;
    int N = isA ? NA : NB;
    int rbase = (isA ? blk : blk - NA / 8) * 8 + wid * 2;
    float cz = cb[lane], cr = cb[64 + lane], cn = cb[128 + lane];
#pragma unroll
    for (int rr = 0; rr < 2; ++rr) {
        int r = rbase + rr;
        if (r >= N) break;
        float xv = (lane < 32) ? X[(size_t)r * 32 + lane] : 0.f;
        float az = cz, ar = cr, an = cn;
#pragma unroll
        for (int k = 0; k < 32; ++k) {
            float xk = __shfl(xv, k, 64);
            az = fmaf(xk, Wsh[k * 64 + lane], az);
            ar = fmaf(xk, Wsh[2048 + k * 64 + lane], ar);
            an = fmaf(xk, Wsh[4096 + k * 64 + lane], an);
        }
        u32 zr = bf16r(az) | (bf16r(ar) << 16);
        u16 nn = (u16)bf16r(an);
        if (isA) { dzrA[(size_t)r * 64 + lane] = zr; dnA[(size_t)r * 64 + lane] = nn; }
        else     { dzrB[(size_t)r * 64 + lane] = zr; dnB[(size_t)r * 64 + lane] = nn; }
    }
}

// ---------------- CSR build: no global atomics, 512 blocks x 512 threads ----------------
__global__ void __launch_bounds__(512) hist_k(
    const int* __restrict__ d0, const int* __restrict__ d1, const int* __restrict__ d2,
    u16* __restrict__ partial)
{
    __shared__ int hcnt[CHUNK];
    int k = blockIdx.x & (NCHUNK - 1);
    int s = blockIdx.x / NCHUNK;
    int lo = k * CHUNK;
    for (int i = threadIdx.x; i < CHUNK; i += 512) hcnt[i] = 0;
    __syncthreads();
    int e0 = s * ESLICE, e1 = e0 + ESLICE;
    for (int e = e0 + threadIdx.x; e < e1; e += 512) {
        int g;
        if (e < EA2A) g = d0[e];
        else if (e < EA2A + EA2B) g = NA + d1[e - EA2A];
        else g = NA + NB + d2[e - EA2A - EA2B];
        u32 rel = (u32)(g - lo);
        if (rel < CHUNK) atomicAdd(&hcnt[rel], 1);
    }
    __syncthreads();
    u16* po = partial + (size_t)s * NCAT + lo;
    for (int i = threadIdx.x; i < CHUNK; i += 512) po[i] = (u16)hcnt[i];
}

__global__ void scan_partial(const u16* __restrict__ partial, int* __restrict__ bsum, int N)
{
    __shared__ int sd[256];
    int t = threadIdx.x;
    int i = blockIdx.x * 256 + t;
    int v = 0;
    if (i < N) {
#pragma unroll 16
        for (int s = 0; s < NSLICE; ++s) v += partial[(size_t)s * NCAT + i];
    }
    sd[t] = v;
    __syncthreads();
    for (int off = 128; off; off >>= 1) {
        if (t < off) sd[t] += sd[t + off];
        __syncthreads();
    }
    if (t == 0) bsum[blockIdx.x] = sd[0];
}

__global__ void __launch_bounds__(512) scan_tops(int* bsum, int nb)
{
    __shared__ int sd[512];
    int t = threadIdx.x;
    int v = (t < nb) ? bsum[t] : 0;
    sd[t] = v;
    __syncthreads();
    for (int off = 1; off < 512; off <<= 1) {
        int add = (t >= off) ? sd[t - off] : 0;
        __syncthreads();
        sd[t] += add;
        __syncthreads();
    }
    if (t < nb) bsum[t] = sd[t] - v;   // exclusive
}

__global__ void scan_final(const u16* __restrict__ partial, const int* __restrict__ bsum,
                           int* __restrict__ rowptr, int* __restrict__ cnt, int N)
{
    __shared__ int sd[256];
    int t = threadIdx.x;
    int i = blockIdx.x * 256 + t;
    int v = 0;
    if (i < N) {
#pragma unroll 16
        for (int s = 0; s < NSLICE; ++s) v += partial[(size_t)s * NCAT + i];
    }
    sd[t] = v;
    __syncthreads();
    for (int off = 1; off < 256; off <<= 1) {
        int add = (t >= off) ? sd[t - off] : 0;
        __syncthreads();
        sd[t] += add;
        __syncthreads();
    }
    if (i < N) {
        rowptr[i] = bsum[blockIdx.x] + sd[t] - v;
        cnt[i] = v;
    }
}

// soff[s][g] = rp[g] + sum_{s'<s} partial[s'][g]
__global__ void soff_k(const int* __restrict__ rp, const u16* __restrict__ partial,
                       u32* __restrict__ soff)
{
    int g = blockIdx.x * 256 + threadIdx.x;
    if (g >= NCAT) return;
    int run = rp[g];
#pragma unroll 16
    for (int s = 0; s < NSLICE; ++s) {
        soff[(size_t)s * NCAT + g] = (u32)run;
        run += partial[(size_t)s * NCAT + g];
    }
}

__global__ void __launch_bounds__(512) fill_k(
    const int* __restrict__ s0, const int* __restrict__ d0,
    const int* __restrict__ s1, const int* __restrict__ d1,
    const int* __restrict__ s2, const int* __restrict__ d2,
    const u32* __restrict__ soff, u16* __restrict__ csr)
{
    __shared__ int fpos[CHUNK];
    int k = blockIdx.x & (NCHUNK - 1);
    int s = blockIdx.x / NCHUNK;
    int lo = k * CHUNK;
    const u32* po = soff + (size_t)s * NCAT + lo;
    for (int i = threadIdx.x; i < CHUNK; i += 512) fpos[i] = (int)po[i];
    __syncthreads();
    int e0 = s * ESLICE, e1 = e0 + ESLICE;
    for (int e = e0 + threadIdx.x; e < e1; e += 512) {
        int g, sidx;
        const int* sp;
        if (e < EA2A) { g = d0[e]; sp = s0; sidx = e; }
        else if (e < EA2A + EA2B) { sidx = e - EA2A; g = NA + d1[sidx]; sp = s1; }
        else { sidx = e - EA2A - EA2B; g = NA + NB + d2[sidx]; sp = s2; }
        u32 rel = (u32)(g - lo);
        if (rel < CHUNK) {
            int src = sp[sidx];
            int p = atomicAdd(&fpos[rel], 1);   // LDS atomic only
            csr[p] = (u16)src;
        }
    }
}

// ---------------- GAT per-edge-type contributions ----------------
__device__ __forceinline__ void zr_fma(float az[4], float ar[4], uint4 v, float pz, float pr) {
    az[0] = fmaf(pz, ubf(v.x << 16), az[0]); ar[0] = fmaf(pr, ubf(v.x & 0xffff0000u), ar[0]);
    az[1] = fmaf(pz, ubf(v.y << 16), az[1]); ar[1] = fmaf(pr, ubf(v.y & 0xffff0000u), ar[1]);
    az[2] = fmaf(pz, ubf(v.z << 16), az[2]); ar[2] = fmaf(pr, ubf(v.z & 0xffff0000u), ar[2]);
    az[3] = fmaf(pz, ubf(v.w << 16), az[3]); ar[3] = fmaf(pr, ubf(v.w & 0xffff0000u), ar[3]);
}

__device__ __forceinline__ void gat_zr_et(
    int gnode, int inode, int lane, int sub, int grp,
    const int* __restrict__ rp, const int* __restrict__ cnt, const u16* __restrict__ csr,
    const float2* __restrict__ als, const float2* __restrict__ ald,
    const uint4* __restrict__ xs,
    float oz[4], float orr[4])
{
    int deg = cnt[gnode];
    if (deg <= 0) return;
    int beg = rp[gnode];
    float2 ad = ald[inode];
    float mz = 0.f, mr = 0.f, sz = 0.f, sr = 0.f;
    float az[4] = {0.f, 0.f, 0.f, 0.f}, ar[4] = {0.f, 0.f, 0.f, 0.f};
    for (int base = 0; base < deg; base += 64) {
        int j = base + lane;
        int sj = 0; float ez = -1e30f, er = -1e30f;
        if (j < deg) {
            sj = csr[beg + j];
            float2 al = als[sj];
            float tz = al.x + ad.x; ez = tz > 0.f ? tz : 0.2f * tz;
            float tr = al.y + ad.y; er = tr > 0.f ? tr : 0.2f * tr;
        }
        float cmz = wmax64(ez), cmr = wmax64(er);
        if (base == 0) { mz = cmz; mr = cmr; }
        else {
            if (cmz > mz) { float s = __expf(mz - cmz);
                az[0] *= s; az[1] *= s; az[2] *= s; az[3] *= s; sz *= s; mz = cmz; }
            if (cmr > mr) { float s = __expf(mr - cmr);
                ar[0] *= s; ar[1] *= s; ar[2] *= s; ar[3] *= s; sr *= s; mr = cmr; }
        }
        float pz = (j < deg) ? __expf(ez - mz) : 0.f;
        float pr = (j < deg) ? __expf(er - mr) : 0.f;
        sz += wsum64(pz);
        sr += wsum64(pr);
        u32 pk = (u32)sj | (bf16r(pz) << 16);   // invalid lanes: pk=0 -> contributes 0
        int c = deg - base; if (c > 64) c = 64;
        int b = 0;
        for (; b + 16 <= c; b += 16) {
            u32 k0 = (u32)__shfl((int)pk, b + grp, 64);
            u32 k1 = (u32)__shfl((int)pk, b + 4 + grp, 64);
            u32 k2 = (u32)__shfl((int)pk, b + 8 + grp, 64);
            u32 k3 = (u32)__shfl((int)pk, b + 12 + grp, 64);
            float q0 = __shfl(pr, b + grp, 64);
            float q1 = __shfl(pr, b + 4 + grp, 64);
            float q2 = __shfl(pr, b + 8 + grp, 64);
            float q3 = __shfl(pr, b + 12 + grp, 64);
            uint4 v0 = xs[(size_t)(k0 & 0xffffu) * 16 + sub];
            uint4 v1 = xs[(size_t)(k1 & 0xffffu) * 16 + sub];
            uint4 v2 = xs[(size_t)(k2 & 0xffffu) * 16 + sub];
            uint4 v3 = xs[(size_t)(k3 & 0xffffu) * 16 + sub];
            zr_fma(az, ar, v0, ubf(k0 & 0xffff0000u), q0);
            zr_fma(az, ar, v1, ubf(k1 & 0xffff0000u), q1);
            zr_fma(az, ar, v2, ubf(k2 & 0xffff0000u), q2);
            zr_fma(az, ar, v3, ubf(k3 & 0xffff0000u), q3);
        }
        for (; b < c; b += 4) {
            u32 k0 = (u32)__shfl((int)pk, b + grp, 64);
            float q0 = __shfl(pr, b + grp, 64);
            uint4 v0 = xs[(size_t)(k0 & 0xffffu) * 16 + sub];
            zr_fma(az, ar, v0, ubf(k0 & 0xffff0000u), q0);
        }
    }
    float rz = 1.f / (sz + 1e-16f), rr = 1.f / (sr + 1e-16f);
    oz[0] = fmaf(az[0], rz, oz[0]); orr[0] = fmaf(ar[0], rr, orr[0]);
    oz[1] = fmaf(az[1], rz, oz[1]); orr[1] = fmaf(ar[1], rr, orr[1]);
    oz[2] = fmaf(az[2], rz, oz[2]); orr[2] = fmaf(ar[2], rr, orr[2]);
    oz[3] = fmaf(az[3], rz, oz[3]); orr[3] = fmaf(ar[3], rr, orr[3]);
}

__device__ __forceinline__ void n_fma(float a[4], uint2 v, float p) {
    a[0] = fmaf(p, ubf(v.x << 16), a[0]);
    a[1] = fmaf(p, ubf(v.x & 0xffff0000u), a[1]);
    a[2] = fmaf(p, ubf(v.y << 16), a[2]);
    a[3] = fmaf(p, ubf(v.y & 0xffff0000u), a[3]);
}

__device__ __forceinline__ void gat_n_et(
    int gnode, int inode, int lane, int sub, int grp,
    const int* __restrict__ rp, const int* __restrict__ cnt, const u16* __restrict__ csr,
    const float* __restrict__ als, const float* __restrict__ ald,
    const uint2* __restrict__ xs,
    float oa[4])
{
    int deg = cnt[gnode];
    if (deg <= 0) return;
    int beg = rp[gnode];
    float ad = ald[inode];
    float m = 0.f, ss = 0.f;
    float ac[4] = {0.f, 0.f, 0.f, 0.f};
    for (int base = 0; base < deg; base += 64) {
        int j = base + lane;
        int sj = 0; float e = -1e30f;
        if (j < deg) {
            sj = csr[beg + j];
            float tv = als[sj] + ad;
            e = tv > 0.f ? tv : 0.2f * tv;
        }
        float cm = wmax64(e);
        if (base == 0) m = cm;
        else if (cm > m) {
            float s = __expf(m - cm);
            ac[0] *= s; ac[1] *= s; ac[2] *= s; ac[3] *= s; ss *= s; m = cm;
        }
        float p = (j < deg) ? __expf(e - m) : 0.f;
        ss += wsum64(p);
        u32 pk = (u32)sj | (bf16r(p) << 16);
        int c = deg - base; if (c > 64) c = 64;
        int b = 0;
        for (; b + 16 <= c; b += 16) {
            u32 k0 = (u32)__shfl((int)pk, b + grp, 64);
            u32 k1 = (u32)__shfl((int)pk, b + 4 + grp, 64);
            u32 k2 = (u32)__shfl((int)pk, b + 8 + grp, 64);
            u32 k3 = (u32)__shfl((int)pk, b + 12 + grp, 64);
            uint2 v0 = xs[(size_t)(k0 & 0xffffu) * 16 + sub];
            uint2 v1 = xs[(size_t)(k1 & 0xffffu) * 16 + sub];
            uint2 v2 = xs[(size_t)(k2 & 0xffffu) * 16 + sub];
            uint2 v3 = xs[(size_t)(k3 & 0xffffu) * 16 + sub];
            n_fma(ac, v0, ubf(k0 & 0xffff0000u));
            n_fma(ac, v1, ubf(k1 & 0xffff0000u));
            n_fma(ac, v2, ubf(k2 & 0xffff0000u));
            n_fma(ac, v3, ubf(k3 & 0xffff0000u));
        }
        for (; b < c; b += 4) {
            u32 k0 = (u32)__shfl((int)pk, b + grp, 64);
            uint2 v0 = xs[(size_t)(k0 & 0xffffu) * 16 + sub];
            n_fma(ac, v0, ubf(k0 & 0xffff0000u));
        }
    }
    float rs = 1.f / (ss + 1e-16f);
    oa[0] = fmaf(ac[0], rs, oa[0]);
    oa[1] = fmaf(ac[1], rs, oa[1]);
    oa[2] = fmaf(ac[2], rs, oa[2]);
    oa[3] = fmaf(ac[3], rs, oa[3]);
}

// ---------------- aggregate kernels (A and B merged) ----------------
struct ZrArgs {
    const int *rp, *cnt;
    const u16 *csr;
    const float2 *als0, *ald0, *als1, *ald1, *als2, *ald2;
    const uint4 *xs0, *xs1, *xs2;
    const u32 *dzrA, *dzrB;
    const float *hA, *hB;
    float *zA, *rhA, *zB, *rhB;
};

__global__ void __launch_bounds__(256) aggregate_zr_k(ZrArgs P)
{
    int t = threadIdx.x, lane = t & 63, wid = t >> 6;
    int sub = lane & 15, grp = lane >> 4;
    float oz[4] = {0.f, 0.f, 0.f, 0.f}, orr[4] = {0.f, 0.f, 0.f, 0.f};
    int blk = blockIdx.x;
    const u32* dzr; const float* Hp; float *Zp, *RHp;
    if (blk < NA / 4) {
        int i = blk * 4 + wid;
        gat_zr_et(i, i, lane, sub, grp, P.rp, P.cnt, P.csr, P.als0, P.ald0, P.xs0, oz, orr);
        gat_zr_et(NA + NB + i, i, lane, sub, grp, P.rp, P.cnt, P.csr, P.als2, P.ald2, P.xs2, oz, orr);
        dzr = P.dzrA + (size_t)i * 64; Hp = P.hA + (size_t)i * 64;
        Zp = P.zA + (size_t)i * 64; RHp = P.rhA + (size_t)i * 64;
    } else {
        int i = (blk - NA / 4) * 4 + wid;
        gat_zr_et(NA + i, i, lane, sub, grp, P.rp, P.cnt, P.csr, P.als1, P.ald1, P.xs1, oz, orr);
        dzr = P.dzrB + (size_t)i * 64; Hp = P.hB + (size_t)i * 64;
        Zp = P.zB + (size_t)i * 64; RHp = P.rhB + (size_t)i * 64;
    }
#pragma unroll
    for (int q = 0; q < 4; ++q) {
        oz[q] += __shfl_xor(oz[q], 16, 64); oz[q] += __shfl_xor(oz[q], 32, 64);
        orr[q] += __shfl_xor(orr[q], 16, 64); orr[q] += __shfl_xor(orr[q], 32, 64);
    }
    if (grp == 0) {
        uint4 d = *(const uint4*)(dzr + sub * 4);
        float4 h = *(const float4*)(Hp + sub * 4);
        float z0 = sigm(oz[0] + ubf(d.x << 16)), r0 = sigm(orr[0] + ubf(d.x & 0xffff0000u)) * h.x;
        float z1 = sigm(oz[1] + ubf(d.y << 16)), r1 = sigm(orr[1] + ubf(d.y & 0xffff0000u)) * h.y;
        float z2 = sigm(oz[2] + ubf(d.z << 16)), r2 = sigm(orr[2] + ubf(d.z & 0xffff0000u)) * h.z;
        float z3 = sigm(oz[3] + ubf(d.w << 16)), r3 = sigm(orr[3] + ubf(d.w & 0xffff0000u)) * h.w;
        *(float4*)(Zp + sub * 4) = make_float4(z0, z1, z2, z3);
        *(float4*)(RHp + sub * 4) = make_float4(r0, r1, r2, r3);
    }
}

struct NArgs {
    const int *rp, *cnt;
    const u16 *csr;
    const float *als0, *ald0, *als1, *ald1, *als2, *ald2;
    const uint2 *xs0, *xs1, *xs2;
    const u16 *dnA, *dnB;
    const float *hA, *hB, *zA, *zB;
    float *outA, *outB;
};

__global__ void __launch_bounds__(256) aggregate_n_k(NArgs P)
{
    int t = threadIdx.x, lane = t & 63, wid = t >> 6;
    int sub = lane & 15, grp = lane >> 4;
    float oa[4] = {0.f, 0.f, 0.f, 0.f};
    int blk = blockIdx.x;
    const u16* dn; const float *Hp, *Zp; float* Op;
    if (blk < NA / 4) {
        int i = blk * 4 + wid;
        gat_n_et(i, i, lane, sub, grp, P.rp, P.cnt, P.csr, P.als0, P.ald0, P.xs0, oa);
        gat_n_et(NA + NB + i, i, lane, sub, grp, P.rp, P.cnt, P.csr, P.als2, P.ald2, P.xs2, oa);
        dn = P.dnA + (size_t)i * 64; Hp = P.hA + (size_t)i * 64;
        Zp = P.zA + (size_t)i * 64; Op = P.outA + (size_t)i * 64;
    } else {
        int i = (blk - NA / 4) * 4 + wid;
        gat_n_et(NA + i, i, lane, sub, grp, P.rp, P.cnt, P.csr, P.als1, P.ald1, P.xs1, oa);
        dn = P.dnB + (size_t)i * 64; Hp = P.hB + (size_t)i * 64;
        Zp = P.zB + (size_t)i * 64; Op = P.outB + (size_t)i * 64;
    }
#pragma unroll
    for (int q = 0; q < 4; ++q) {
        oa[q] += __shfl_xor(oa[q], 16, 64); oa[q] += __shfl_xor(oa[q], 32, 64);
    }
    if (grp == 0) {
        uint2 d = *(const uint2*)(dn + sub * 4);
        float4 h = *(const float4*)(Hp + sub * 4);
        float4 zv = *(const float4*)(Zp + sub * 4);
        float pre[4];
        pre[0] = oa[0] + ubf(d.x << 16);
        pre[1] = oa[1] + ubf(d.x & 0xffff0000u);
        pre[2] = oa[2] + ubf(d.y << 16);
        pre[3] = oa[3] + ubf(d.y & 0xffff0000u);
        float o[4];
        float hh[4] = {h.x, h.y, h.z, h.w};
        float zz[4] = {zv.x, zv.y, zv.z, zv.w};
#pragma unroll
        for (int q = 0; q < 4; ++q) {
            float x2 = fminf(fmaxf(pre[q] * 2.f, -30.f), 30.f);
            float ex = __expf(x2);
            float nv = (ex - 1.f) / (ex + 1.f);
            o[q] = (1.f - zz[q]) * nv + zz[q] * hh[q];
        }
        *(float4*)(Op + sub * 4) = make_float4(o[0], o[1], o[2], o[3]);
    }
}

// ---------------- host side ----------------
extern "C" void kernel_launch(void* const* d_in, const int* in_sizes, int n_in,
                              void* d_out, int out_size, void* d_ws, size_t ws_size,
                              hipStream_t stream)
{
    (void)in_sizes; (void)n_in; (void)out_size; (void)ws_size;
    const float* x_a = (const float*)d_in[0];
    const float* x_b = (const float*)d_in[1];
    const float* h_a = (const float*)d_in[2];
    const float* h_b = (const float*)d_in[3];
    const float* Wx  = (const float*)d_in[4];
    const float* bx  = (const float*)d_in[5];
    const float* gws = (const float*)d_in[6];
    const float* gwd = (const float*)d_in[7];
    const float* gas = (const float*)d_in[8];
    const float* gad = (const float*)d_in[9];
    const float* gb  = (const float*)d_in[10];
    const int* ea2a_s = (const int*)d_in[11];
    const int* ea2a_d = (const int*)d_in[12];
    const int* ea2b_s = (const int*)d_in[13];
    const int* ea2b_d = (const int*)d_in[14];
    const int* eb2a_s = (const int*)d_in[15];
    const int* eb2a_d = (const int*)d_in[16];
    float* out = (float*)d_out;

    char* w = (char*)d_ws;
    auto alloc = [&](size_t bytes) -> char* {
        char* p = w;
        w += (bytes + 255) & ~(size_t)255;
        return p;
    };
    char* xsblk = alloc((size_t)(NA + NA + NB) * 64 * 4);
    u32* xs_zr0 = (u32*)xsblk;
    u32* xs_zr1 = (u32*)(xsblk + (size_t)NA * 64 * 4);
    u32* xs_zr2 = (u32*)(xsblk + (size_t)(NA + NA) * 64 * 4);
    u16* xs_n0 = (u16*)xsblk;
    u16* xs_n1 = (u16*)(xsblk + (size_t)NA * 64 * 2);
    u16* xs_n2 = (u16*)(xsblk + (size_t)(NA + NA) * 64 * 2);
    char* alblk = alloc((size_t)(4 * NA + 2 * NB) * 2 * 4);
    float* als_zr0 = (float*)alblk;
    float* als_zr1 = als_zr0 + (size_t)NA * 2;
    float* als_zr2 = als_zr1 + (size_t)NA * 2;
    float* ald_zr0 = als_zr2 + (size_t)NB * 2;
    float* ald_zr1 = ald_zr0 + (size_t)NA * 2;
    float* ald_zr2 = ald_zr1 + (size_t)NB * 2;
    float* als_n0 = (float*)alblk;
    float* als_n1 = als_n0 + NA;
    float* als_n2 = als_n1 + NA;
    float* ald_n0 = als_n2 + NB;
    float* ald_n1 = ald_n0 + NA;
    float* ald_n2 = ald_n1 + NB;
    float* zbuf  = (float*)alloc((size_t)(NA + NB) * 64 * 4);
    float* rhbuf = (float*)alloc((size_t)(NA + NB) * 64 * 4);
    u32* dzrA = (u32*)alloc((size_t)NA * 64 * 4);
    u32* dzrB = (u32*)alloc((size_t)NB * 64 * 4);
    u16* dnA = (u16*)alloc((size_t)NA * 64 * 2);
    u16* dnB = (u16*)alloc((size_t)NB * 64 * 2);
    u16* partial = (u16*)alloc((size_t)NSLICE * NCAT * 2);
    u32* soff    = (u32*)alloc((size_t)NSLICE * NCAT * 4);
    int* cnt = (int*)alloc((size_t)NCAT * 4);
    int* rp  = (int*)alloc((size_t)NCAT * 4);
    u16* csr = (u16*)alloc((size_t)ETOT * 2);
    int* bsum = (int*)alloc(512 * 4);

    const int nbC = (NCAT + 255) / 256;

    // ---- CSR build (no global atomics, no memset) ----
    hist_k<<<NCHUNK * NSLICE, 512, 0, stream>>>(ea2a_d, ea2b_d, eb2a_d, partial);
    scan_partial<<<nbC, 256, 0, stream>>>(partial, bsum, NCAT);
    scan_tops<<<1, 512, 0, stream>>>(bsum, nbC);
    scan_final<<<nbC, 256, 0, stream>>>(partial, bsum, rp, cnt, NCAT);
    soff_k<<<nbC, 256, 0, stream>>>(rp, partial, soff);
    fill_k<<<NCHUNK * NSLICE, 512, 0, stream>>>(ea2a_s, ea2a_d, ea2b_s, ea2b_d, eb2a_s, eb2a_d,
                                                soff, csr);

    // ---- dense precompute (all 3 gates, both node types) ----
    gemm_x_k<<<(NA + NB) / 8, 256, 0, stream>>>(x_a, x_b, Wx, bx, gb, dzrA, dzrB, dnA, dnB);

    float* rh_a = rhbuf;
    float* rh_b = rhbuf + (size_t)NA * 64;
    float* z_a = zbuf;
    float* z_b = zbuf + (size_t)NA * 64;

    // ---- z+r MFMA GEMMs ----
    {
        MmArgs a{};
        a.H = h_a; a.ntiles = NA / 16;
        a.W0 = gws + 0 * 4096; a.W1 = gws + 3 * 4096;
        a.XS = xs_zr0;
        a.SW[0] = gws + 0 * 4096; a.SA[0] = gas + 0 * 64; a.SOUT[0] = als_zr0;
        a.SW[1] = gws + 3 * 4096; a.SA[1] = gas + 3 * 64; a.SOUT[1] = als_zr0 + 1;
        a.SW[2] = gws + 1 * 4096; a.SA[2] = gas + 1 * 64; a.SOUT[2] = als_zr1;
        a.SW[3] = gws + 4 * 4096; a.SA[3] = gas + 4 * 64; a.SOUT[3] = als_zr1 + 1;
        a.SW[4] = gwd + 0 * 4096; a.SA[4] = gad + 0 * 64; a.SOUT[4] = ald_zr0;
        a.SW[5] = gwd + 3 * 4096; a.SA[5] = gad + 3 * 64; a.SOUT[5] = ald_zr0 + 1;
        a.SW[6] = gwd + 2 * 4096; a.SA[6] = gad + 2 * 64; a.SOUT[6] = ald_zr2;
        a.SW[7] = gwd + 5 * 4096; a.SA[7] = gad + 5 * 64; a.SOUT[7] = ald_zr2 + 1;
        a.sstride = 2; a.nsc = 8;
        gemm_mfma<2><<<320, 256, 0, stream>>>(a);
    }
    {
        MmArgs a{};
        a.H = h_a; a.ntiles = NA / 16;
        a.W0 = gws + 1 * 4096; a.W1 = gws + 4 * 4096;
        a.XS = xs_zr1;
        a.sstride = 1; a.nsc = 0;
        gemm_mfma<2><<<320, 256, 0, stream>>>(a);
    }
    {
        MmArgs a{};
        a.H = h_b; a.ntiles = NB / 16;
        a.W0 = gws + 2 * 4096; a.W1 = gws + 5 * 4096;
        a.XS = xs_zr2;
        a.SW[0] = gws + 2 * 4096; a.SA[0] = gas + 2 * 64; a.SOUT[0] = als_zr2;
        a.SW[1] = gws + 5 * 4096; a.SA[1] = gas + 5 * 64; a.SOUT[1] = als_zr2 + 1;
        a.SW[2] = gwd + 1 * 4096; a.SA[2] = gad + 1 * 64; a.SOUT[2] = ald_zr1;
        a.SW[3] = gwd + 4 * 4096; a.SA[3] = gad + 4 * 64; a.SOUT[3] = ald_zr1 + 1;
        a.sstride = 2; a.nsc = 4;
        gemm_mfma<2><<<80, 256, 0, stream>>>(a);
    }

    // ---- z+r aggregation ----
    {
        ZrArgs P{};
        P.rp = rp; P.cnt = cnt; P.csr = csr;
        P.als0 = (const float2*)als_zr0; P.ald0 = (const float2*)ald_zr0;
        P.als1 = (const float2*)als_zr1; P.ald1 = (const float2*)ald_zr1;
        P.als2 = (const float2*)als_zr2; P.ald2 = (const float2*)ald_zr2;
        P.xs0 = (const uint4*)xs_zr0; P.xs1 = (const uint4*)xs_zr1; P.xs2 = (const uint4*)xs_zr2;
        P.dzrA = dzrA; P.dzrB = dzrB;
        P.hA = h_a; P.hB = h_b;
        P.zA = z_a; P.rhA = rh_a; P.zB = z_b; P.rhB = rh_b;
        aggregate_zr_k<<<(NA + NB) / 4, 256, 0, stream>>>(P);
    }

    // ---- n MFMA GEMMs (input rh) ----
    {
        MmArgs a{};
        a.H = rh_a; a.ntiles = NA / 16;
        a.W0 = gws + 6 * 4096; a.W1 = nullptr;
        a.XS = xs_n0;
        a.SW[0] = gws + 6 * 4096; a.SA[0] = gas + 6 * 64; a.SOUT[0] = als_n0;
        a.SW[1] = gws + 7 * 4096; a.SA[1] = gas + 7 * 64; a.SOUT[1] = als_n1;
        a.SW[2] = gwd + 6 * 4096; a.SA[2] = gad + 6 * 64; a.SOUT[2] = ald_n0;
        a.SW[3] = gwd + 8 * 4096; a.SA[3] = gad + 8 * 64; a.SOUT[3] = ald_n2;
        a.sstride = 1; a.nsc = 4;
        gemm_mfma<1><<<320, 256, 0, stream>>>(a);
    }
    {
        MmArgs a{};
        a.H = rh_a; a.ntiles = NA / 16;
        a.W0 = gws + 7 * 4096; a.W1 = nullptr;
        a.XS = xs_n1;
        a.sstride = 1; a.nsc = 0;
        gemm_mfma<1><<<320, 256, 0, stream>>>(a);
    }
    {
        MmArgs a{};
        a.H = rh_b; a.ntiles = NB / 16;
        a.W0 = gws + 8 * 4096; a.W1 = nullptr;
        a.XS = xs_n2;
        a.SW[0] = gws + 8 * 4096; a.SA[0] = gas + 8 * 64; a.SOUT[0] = als_n2;
        a.SW[1] = gwd + 7 * 4096; a.SA[1] = gad + 7 * 64; a.SOUT[1] = ald_n1;
        a.sstride = 1; a.nsc = 2;
        gemm_mfma<1><<<80, 256, 0, stream>>>(a);
    }

    // ---- n aggregation + GRU combine ----
    {
        NArgs P{};
        P.rp = rp; P.cnt = cnt; P.csr = csr;
        P.als0 = als_n0; P.ald0 = ald_n0;
        P.als1 = als_n1; P.ald1 = ald_n1;
        P.als2 = als_n2; P.ald2 = ald_n2;
        P.xs0 = (const uint2*)xs_n0; P.xs1 = (const uint2*)xs_n1; P.xs2 = (const uint2*)xs_n2;
        P.dnA = dnA; P.dnB = dnB;
        P.hA = h_a; P.hB = h_b; P.zA = z_a; P.zB = z_b;
        P.outA = out; P.outB = out + (size_t)NA * 64;
        aggregate_n_k<<<(NA + NB) / 4, 256, 0, stream>>>(P);
    }
}

// Round 10
// 316.544 us; speedup vs baseline: 2.1635x; 1.0350x over previous
//
#include <hip/hip_runtime.h>
#include <hip/hip_bf16.h>
#include <cstddef>
#include <cstdint>

#define NA 50000
#define NB 10000
#define D_IN 32
#define D_OUT 64
#define EA2A 800000
#define EA2B 400000
#define EB2A 400000
#define NCAT (NA + NB + NA)
#define ETOT (EA2A + EA2B + EB2A)
#define NCHUNK 8
#define CHUNK (NCAT / NCHUNK)          // 13750 nodes per chunk (55KB LDS)
#define NSLICE 64
#define ESLICE (ETOT / NSLICE)         // 25000 edges per slice

typedef unsigned int u32;
typedef unsigned short u16;
typedef __attribute__((ext_vector_type(8))) short short8_t;
typedef __attribute__((ext_vector_type(4))) float f32x4;
typedef __attribute__((ext_vector_type(2))) float f32x2;

// ---------------- helpers ----------------
__device__ __forceinline__ u32 bf16r(float x) {          // round-to-nearest-even bf16 bits
    u32 u = __float_as_uint(x);
    u += 0x7fffu + ((u >> 16) & 1u);
    return u >> 16;
}
__device__ __forceinline__ float ubf(u32 bits) { return __uint_as_float(bits); }
__device__ __forceinline__ float sigm(float x) { return 1.f / (1.f + __expf(-x)); }
__device__ __forceinline__ u32 cvtpk(float lo, float hi) {   // bf16(lo) | bf16(hi)<<16
    u32 r;
    asm("v_cvt_pk_bf16_f32 %0, %1, %2" : "=v"(r) : "v"(lo), "v"(hi));
    return r;
}
// packed dual-f32 fma: acc.lo += x.lo*p.lo ; acc.hi += x.hi*p.hi
__device__ __forceinline__ void pkfma(f32x2& acc, f32x2 x, f32x2 p) {
    asm("v_pk_fma_f32 %0, %1, %2, %0" : "+v"(acc) : "v"(x), "v"(p));
}

template <int CTRL, int RM>
__device__ __forceinline__ float dppf(float v) {
    return __int_as_float(__builtin_amdgcn_update_dpp(0, __float_as_int(v), CTRL, RM, 0xf, true));
}
__device__ __forceinline__ float wsum64(float v) {
    v += dppf<0x111, 0xf>(v);
    v += dppf<0x112, 0xf>(v);
    v += dppf<0x114, 0xf>(v);
    v += dppf<0x118, 0xf>(v);
    v += dppf<0x142, 0xa>(v);
    v += dppf<0x143, 0xc>(v);
    return __int_as_float(__builtin_amdgcn_readlane(__float_as_int(v), 63));
}

// ---------------- MFMA staging GEMM ----------------
struct MmArgs {
    const float* H; int ntiles;
    const float* W0; const float* W1;
    void* XS;
    const float* SW[8]; const float* SA[8]; float* SOUT[8];
    int sstride; int nsc;
};

template <int NMAT>
__global__ void __launch_bounds__(256) gemm_mfma(MmArgs a)
{
    __shared__ float wvec[8][64];
    __shared__ short8_t bfr[NMAT * 8 + 2][64];
    int t = threadIdx.x;
    for (int idx = t; idx < a.nsc * 64; idx += 256) {
        int c = idx >> 6, k = idx & 63;
        const float* w = a.SW[c] + k * 64;
        const float* av = a.SA[c];
        float s = 0.f;
#pragma unroll 16
        for (int e = 0; e < 64; ++e) s = fmaf(w[e], av[e], s);
        wvec[c][k] = s;
    }
    __syncthreads();
    for (int idx = t; idx < NMAT * 8 * 64; idx += 256) {
        int fid = idx >> 6, l = idx & 63;
        int m = fid >> 3, r3 = fid & 7, tn = r3 >> 1, q = r3 & 1;
        const float* W = (NMAT == 2 && m == 1) ? a.W1 : a.W0;
        int kbase = 32 * q + ((l >> 4) << 3);
        int d = 16 * tn + (l & 15);
        short8_t v;
#pragma unroll
        for (int e = 0; e < 8; ++e) v[e] = (short)bf16r(W[(size_t)(kbase + e) * 64 + d]);
        bfr[fid][l] = v;
    }
    for (int idx = t; idx < 128; idx += 256) {
        int q = idx >> 6, l = idx & 63;
        int c = l & 15;
        int kbase = 32 * q + ((l >> 4) << 3);
        short8_t v;
#pragma unroll
        for (int e = 0; e < 8; ++e) v[e] = (c < a.nsc) ? (short)bf16r(wvec[c][kbase + e]) : (short)0;
        bfr[NMAT * 8 + q][l] = v;
    }
    __syncthreads();
    int lane = t & 63, wid = t >> 6;
    short8_t bw[NMAT][4][2], bs0, bs1;
#pragma unroll
    for (int m = 0; m < NMAT; ++m)
#pragma unroll
        for (int tn = 0; tn < 4; ++tn)
#pragma unroll
            for (int q = 0; q < 2; ++q) bw[m][tn][q] = bfr[m * 8 + tn * 2 + q][lane];
    bs0 = bfr[NMAT * 8][lane];
    bs1 = bfr[NMAT * 8 + 1][lane];

    int rl = lane & 15, kg = lane >> 4;
    f32x4 zero = {0.f, 0.f, 0.f, 0.f};
    for (int tile = blockIdx.x * 4 + wid; tile < a.ntiles; tile += gridDim.x * 4) {
        const float4* hp = (const float4*)(a.H + (size_t)(tile * 16 + rl) * 64) + kg * 2;
        float4 a0 = hp[0], a1 = hp[1];
        float4 b0 = hp[8], b1 = hp[9];
        union { short8_t s; u32 w[4]; } A0, A1;
        A0.w[0] = cvtpk(a0.x, a0.y); A0.w[1] = cvtpk(a0.z, a0.w);
        A0.w[2] = cvtpk(a1.x, a1.y); A0.w[3] = cvtpk(a1.z, a1.w);
        A1.w[0] = cvtpk(b0.x, b0.y); A1.w[1] = cvtpk(b0.z, b0.w);
        A1.w[2] = cvtpk(b1.x, b1.y); A1.w[3] = cvtpk(b1.z, b1.w);

        f32x4 acc[NMAT][4];
#pragma unroll
        for (int m = 0; m < NMAT; ++m)
#pragma unroll
            for (int tn = 0; tn < 4; ++tn) {
                f32x4 c0 = __builtin_amdgcn_mfma_f32_16x16x32_bf16(A0.s, bw[m][tn][0], zero, 0, 0, 0);
                acc[m][tn] = __builtin_amdgcn_mfma_f32_16x16x32_bf16(A1.s, bw[m][tn][1], c0, 0, 0, 0);
            }
        f32x4 accs = __builtin_amdgcn_mfma_f32_16x16x32_bf16(A0.s, bs0, zero, 0, 0, 0);
        accs = __builtin_amdgcn_mfma_f32_16x16x32_bf16(A1.s, bs1, accs, 0, 0, 0);

        int rbase = tile * 16 + kg * 4;
        if (NMAT == 2) {
            u32* xo = (u32*)a.XS;
#pragma unroll
            for (int tn = 0; tn < 4; ++tn) {
                int d = tn * 16 + rl;
#pragma unroll
                for (int j = 0; j < 4; ++j)
                    xo[(size_t)(rbase + j) * 64 + d] = cvtpk(acc[0][tn][j], acc[1][tn][j]);
            }
        } else {
            u16* xo = (u16*)a.XS;
#pragma unroll
            for (int tn = 0; tn < 4; ++tn) {
                int d = tn * 16 + rl;
#pragma unroll
                for (int j = 0; j < 4; ++j)
                    xo[(size_t)(rbase + j) * 64 + d] = (u16)bf16r(acc[0][tn][j]);
            }
        }
        if (rl < a.nsc) {
            float* so = a.SOUT[rl];
#pragma unroll
            for (int j = 0; j < 4; ++j) so[(size_t)(rbase + j) * a.sstride] = accs[j];
        }
    }
}

// ---------------- dense precompute: d*(node,dim) = x @ Wx[g] + bx + sum(gat_b) ----
__global__ void __launch_bounds__(256) gemm_x_k(
    const float* __restrict__ xA, const float* __restrict__ xB,
    const float* __restrict__ Wx, const float* __restrict__ bx, const float* __restrict__ gb,
    u32* __restrict__ dzrA, u32* __restrict__ dzrB,
    u16* __restrict__ dnA, u16* __restrict__ dnB)
{
    __shared__ float Wsh[3 * 2048];
    __shared__ float cb[3 * 64];
    int t = threadIdx.x;
    int blk = blockIdx.x;
    bool isA = blk < (NA / 8);
    int ty = isA ? 0 : 1;
#pragma unroll
    for (int g = 0; g < 3; ++g) {
        const float4* s = (const float4*)(Wx + (size_t)(g * 2 + ty) * 2048);
        float4* d = (float4*)&Wsh[g * 2048];
        for (int i = t; i < 512; i += 256) d[i] = s[i];
    }
    if (t < 192) {
        int g = t >> 6, d = t & 63;
        float c = bx[(g * 2 + ty) * 64 + d];
        if (isA) c += gb[(g * 3 + 0) * 64 + d] + gb[(g * 3 + 2) * 64 + d];
        else     c += gb[(g * 3 + 1) * 64 + d];
        cb[t] = c;
    }
    __syncthreads();
    int lane = t & 63, wid = t >> 6;
    const float* X = isA ? xA : xB;
    int N = isA ? NA : NB;
    int rbase = (isA ? blk : blk - NA / 8) * 8 + wid * 2;
    float cz = cb[lane], cr = cb[64 + lane], cn = cb[128 + lane];
#pragma unroll
    for (int rr = 0; rr < 2; ++rr) {
        int r = rbase + rr;
        if (r >= N) break;
        float xv = (lane < 32) ? X[(size_t)r * 32 + lane] : 0.f;
        float az = cz, ar = cr, an = cn;
#pragma unroll
        for (int k = 0; k < 32; ++k) {
            float xk = __shfl(xv, k, 64);
            az = fmaf(xk, Wsh[k * 64 + lane], az);
            ar = fmaf(xk, Wsh[2048 + k * 64 + lane], ar);
            an = fmaf(xk, Wsh[4096 + k * 64 + lane], an);
        }
        u32 zr = bf16r(az) | (bf16r(ar) << 16);
        u16 nn = (u16)bf16r(an);
        if (isA) { dzrA[(size_t)r * 64 + lane] = zr; dnA[(size_t)r * 64 + lane] = nn; }
        else     { dzrB[(size_t)r * 64 + lane] = zr; dnB[(size_t)r * 64 + lane] = nn; }
    }
}

// ---------------- CSR build: no global atomics ----------------
__global__ void __launch_bounds__(512) hist_k(
    const int* __restrict__ d0, const int* __restrict__ d1, const int* __restrict__ d2,
    u16* __restrict__ partial)
{
    __shared__ int hcnt[CHUNK];
    int k = blockIdx.x & (NCHUNK - 1);
    int s = blockIdx.x / NCHUNK;
    int lo = k * CHUNK;
    for (int i = threadIdx.x; i < CHUNK; i += 512) hcnt[i] = 0;
    __syncthreads();
    int e0 = s * ESLICE, e1 = e0 + ESLICE;
    for (int e = e0 + threadIdx.x; e < e1; e += 512) {
        int g;
        if (e < EA2A) g = d0[e];
        else if (e < EA2A + EA2B) g = NA + d1[e - EA2A];
        else g = NA + NB + d2[e - EA2A - EA2B];
        u32 rel = (u32)(g - lo);
        if (rel < CHUNK) atomicAdd(&hcnt[rel], 1);
    }
    __syncthreads();
    u16* po = partial + (size_t)s * NCAT + lo;
    for (int i = threadIdx.x; i < CHUNK; i += 512) po[i] = (u16)hcnt[i];
}

__global__ void scan_partial(const u16* __restrict__ partial, int* __restrict__ bsum, int N)
{
    __shared__ int sd[256];
    int t = threadIdx.x;
    int i = blockIdx.x * 256 + t;
    int v = 0;
    if (i < N) {
#pragma unroll 16
        for (int s = 0; s < NSLICE; ++s) v += partial[(size_t)s * NCAT + i];
    }
    sd[t] = v;
    __syncthreads();
    for (int off = 128; off; off >>= 1) {
        if (t < off) sd[t] += sd[t + off];
        __syncthreads();
    }
    if (t == 0) bsum[blockIdx.x] = sd[0];
}

__global__ void __launch_bounds__(512) scan_tops(int* bsum, int nb)
{
    __shared__ int sd[512];
    int t = threadIdx.x;
    int v = (t < nb) ? bsum[t] : 0;
    sd[t] = v;
    __syncthreads();
    for (int off = 1; off < 512; off <<= 1) {
        int add = (t >= off) ? sd[t - off] : 0;
        __syncthreads();
        sd[t] += add;
        __syncthreads();
    }
    if (t < nb) bsum[t] = sd[t] - v;   // exclusive
}

// merged: rowptr + cnt + per-slice start offsets (soff)
__global__ void scan_final(const u16* __restrict__ partial, const int* __restrict__ bsum,
                           int* __restrict__ rowptr, int* __restrict__ cnt,
                           u32* __restrict__ soff, int N)
{
    __shared__ int sd[256];
    int t = threadIdx.x;
    int i = blockIdx.x * 256 + t;
    int v = 0;
    if (i < N) {
#pragma unroll 16
        for (int s = 0; s < NSLICE; ++s) v += partial[(size_t)s * NCAT + i];
    }
    sd[t] = v;
    __syncthreads();
    for (int off = 1; off < 256; off <<= 1) {
        int add = (t >= off) ? sd[t - off] : 0;
        __syncthreads();
        sd[t] += add;
        __syncthreads();
    }
    if (i < N) {
        int rpi = bsum[blockIdx.x] + sd[t] - v;
        rowptr[i] = rpi;
        cnt[i] = v;
        int run = rpi;
#pragma unroll 16
        for (int s = 0; s < NSLICE; ++s) {
            soff[(size_t)s * NCAT + i] = (u32)run;
            run += partial[(size_t)s * NCAT + i];
        }
    }
}

__global__ void __launch_bounds__(512) fill_k(
    const int* __restrict__ s0, const int* __restrict__ d0,
    const int* __restrict__ s1, const int* __restrict__ d1,
    const int* __restrict__ s2, const int* __restrict__ d2,
    const u32* __restrict__ soff, u16* __restrict__ csr)
{
    __shared__ int fpos[CHUNK];
    int k = blockIdx.x & (NCHUNK - 1);
    int s = blockIdx.x / NCHUNK;
    int lo = k * CHUNK;
    const u32* po = soff + (size_t)s * NCAT + lo;
    for (int i = threadIdx.x; i < CHUNK; i += 512) fpos[i] = (int)po[i];
    __syncthreads();
    int e0 = s * ESLICE, e1 = e0 + ESLICE;
    for (int e = e0 + threadIdx.x; e < e1; e += 512) {
        int g, sidx;
        const int* sp;
        if (e < EA2A) { g = d0[e]; sp = s0; sidx = e; }
        else if (e < EA2A + EA2B) { sidx = e - EA2A; g = NA + d1[sidx]; sp = s1; }
        else { sidx = e - EA2A - EA2B; g = NA + NB + d2[sidx]; sp = s2; }
        u32 rel = (u32)(g - lo);
        if (rel < CHUNK) {
            int src = sp[sidx];
            int p = atomicAdd(&fpos[rel], 1);   // LDS atomic only
            csr[p] = (u16)src;
        }
    }
}

// ---------------- GAT per-edge-type contributions ----------------
// m=0 softmax: logits are O(+-2) (weights*0.05), exp is range-safe; softmax is
// shift-invariant so this matches the reference's max-subtracted form exactly.
__device__ __forceinline__ void zr_pk(f32x2 azr[4], uint4 v, f32x2 p) {
    f32x2 x;
    x[0] = ubf(v.x << 16); x[1] = ubf(v.x & 0xffff0000u); pkfma(azr[0], x, p);
    x[0] = ubf(v.y << 16); x[1] = ubf(v.y & 0xffff0000u); pkfma(azr[1], x, p);
    x[0] = ubf(v.z << 16); x[1] = ubf(v.z & 0xffff0000u); pkfma(azr[2], x, p);
    x[0] = ubf(v.w << 16); x[1] = ubf(v.w & 0xffff0000u); pkfma(azr[3], x, p);
}

__device__ __forceinline__ void gat_zr_et(
    int gnode, int inode, int lane, int sub, int grp,
    const int* __restrict__ rp, const int* __restrict__ cnt, const u16* __restrict__ csr,
    const float2* __restrict__ als, const float2* __restrict__ ald,
    const uint4* __restrict__ xs,
    float oz[4], float orr[4])
{
    int deg = cnt[gnode];
    if (deg <= 0) return;
    int beg = rp[gnode];
    float2 ad = ald[inode];
    f32x2 azr[4];
#pragma unroll
    for (int q = 0; q < 4; ++q) { azr[q][0] = 0.f; azr[q][1] = 0.f; }
    float szl = 0.f, srl = 0.f;
    for (int base = 0; base < deg; base += 64) {
        int j = base + lane;
        int sj = 0; float pz = 0.f, pr = 0.f;
        if (j < deg) {
            sj = csr[beg + j];
            float2 al = als[sj];
            float tz = al.x + ad.x;
            float tr = al.y + ad.y;
            pz = __expf(fmaxf(tz, 0.2f * tz));
            pr = __expf(fmaxf(tr, 0.2f * tr));
        }
        szl += pz; srl += pr;
        u32 pk = (u32)sj | (bf16r(pz) << 16);   // invalid lanes: pk=0 -> contributes 0
        int c = deg - base; if (c > 64) c = 64;
        int b = 0;
        for (; b + 16 <= c; b += 16) {
            u32 k0 = (u32)__shfl((int)pk, b + grp, 64);
            u32 k1 = (u32)__shfl((int)pk, b + 4 + grp, 64);
            u32 k2 = (u32)__shfl((int)pk, b + 8 + grp, 64);
            u32 k3 = (u32)__shfl((int)pk, b + 12 + grp, 64);
            float q0 = __shfl(pr, b + grp, 64);
            float q1 = __shfl(pr, b + 4 + grp, 64);
            float q2 = __shfl(pr, b + 8 + grp, 64);
            float q3 = __shfl(pr, b + 12 + grp, 64);
            uint4 v0 = xs[(size_t)(k0 & 0xffffu) * 16 + sub];
            uint4 v1 = xs[(size_t)(k1 & 0xffffu) * 16 + sub];
            uint4 v2 = xs[(size_t)(k2 & 0xffffu) * 16 + sub];
            uint4 v3 = xs[(size_t)(k3 & 0xffffu) * 16 + sub];
            f32x2 p;
            p[0] = ubf(k0 & 0xffff0000u); p[1] = q0; zr_pk(azr, v0, p);
            p[0] = ubf(k1 & 0xffff0000u); p[1] = q1; zr_pk(azr, v1, p);
            p[0] = ubf(k2 & 0xffff0000u); p[1] = q2; zr_pk(azr, v2, p);
            p[0] = ubf(k3 & 0xffff0000u); p[1] = q3; zr_pk(azr, v3, p);
        }
        for (; b < c; b += 4) {
            u32 k0 = (u32)__shfl((int)pk, b + grp, 64);
            float q0 = __shfl(pr, b + grp, 64);
            uint4 v0 = xs[(size_t)(k0 & 0xffffu) * 16 + sub];
            f32x2 p;
            p[0] = ubf(k0 & 0xffff0000u); p[1] = q0;
            zr_pk(azr, v0, p);
        }
    }
    float sz = wsum64(szl), sr = wsum64(srl);
    float rz = 1.f / (sz + 1e-16f), rr = 1.f / (sr + 1e-16f);
#pragma unroll
    for (int q = 0; q < 4; ++q) {
        oz[q] = fmaf(azr[q][0], rz, oz[q]);
        orr[q] = fmaf(azr[q][1], rr, orr[q]);
    }
}

__device__ __forceinline__ void n_pk(f32x2 ac[2], uint2 v, f32x2 p) {
    f32x2 x;
    x[0] = ubf(v.x << 16); x[1] = ubf(v.x & 0xffff0000u); pkfma(ac[0], x, p);
    x[0] = ubf(v.y << 16); x[1] = ubf(v.y & 0xffff0000u); pkfma(ac[1], x, p);
}

__device__ __forceinline__ void gat_n_et(
    int gnode, int inode, int lane, int sub, int grp,
    const int* __restrict__ rp, const int* __restrict__ cnt, const u16* __restrict__ csr,
    const float* __restrict__ als, const float* __restrict__ ald,
    const uint2* __restrict__ xs,
    float oa[4])
{
    int deg = cnt[gnode];
    if (deg <= 0) return;
    int beg = rp[gnode];
    float ad = ald[inode];
    f32x2 ac[2];
    ac[0][0] = 0.f; ac[0][1] = 0.f; ac[1][0] = 0.f; ac[1][1] = 0.f;
    float ssl = 0.f;
    for (int base = 0; base < deg; base += 64) {
        int j = base + lane;
        int sj = 0; float pv = 0.f;
        if (j < deg) {
            sj = csr[beg + j];
            float tv = als[sj] + ad;
            pv = __expf(fmaxf(tv, 0.2f * tv));
        }
        ssl += pv;
        u32 pk = (u32)sj | (bf16r(pv) << 16);
        int c = deg - base; if (c > 64) c = 64;
        int b = 0;
        for (; b + 16 <= c; b += 16) {
            u32 k0 = (u32)__shfl((int)pk, b + grp, 64);
            u32 k1 = (u32)__shfl((int)pk, b + 4 + grp, 64);
            u32 k2 = (u32)__shfl((int)pk, b + 8 + grp, 64);
            u32 k3 = (u32)__shfl((int)pk, b + 12 + grp, 64);
            uint2 v0 = xs[(size_t)(k0 & 0xffffu) * 16 + sub];
            uint2 v1 = xs[(size_t)(k1 & 0xffffu) * 16 + sub];
            uint2 v2 = xs[(size_t)(k2 & 0xffffu) * 16 + sub];
            uint2 v3 = xs[(size_t)(k3 & 0xffffu) * 16 + sub];
            f32x2 p;
            p[0] = ubf(k0 & 0xffff0000u); p[1] = p[0]; n_pk(ac, v0, p);
            p[0] = ubf(k1 & 0xffff0000u); p[1] = p[0]; n_pk(ac, v1, p);
            p[0] = ubf(k2 & 0xffff0000u); p[1] = p[0]; n_pk(ac, v2, p);
            p[0] = ubf(k3 & 0xffff0000u); p[1] = p[0]; n_pk(ac, v3, p);
        }
        for (; b < c; b += 4) {
            u32 k0 = (u32)__shfl((int)pk, b + grp, 64);
            uint2 v0 = xs[(size_t)(k0 & 0xffffu) * 16 + sub];
            f32x2 p;
            p[0] = ubf(k0 & 0xffff0000u); p[1] = p[0];
            n_pk(ac, v0, p);
        }
    }
    float ss = wsum64(ssl);
    float rs = 1.f / (ss + 1e-16f);
    oa[0] = fmaf(ac[0][0], rs, oa[0]);
    oa[1] = fmaf(ac[0][1], rs, oa[1]);
    oa[2] = fmaf(ac[1][0], rs, oa[2]);
    oa[3] = fmaf(ac[1][1], rs, oa[3]);
}

// ---------------- aggregate kernels (A and B merged) ----------------
struct ZrArgs {
    const int *rp, *cnt;
    const u16 *csr;
    const float2 *als0, *ald0, *als1, *ald1, *als2, *ald2;
    const uint4 *xs0, *xs1, *xs2;
    const u32 *dzrA, *dzrB;
    const float *hA, *hB;
    float *zA, *rhA, *zB, *rhB;
};

__global__ void __launch_bounds__(256) aggregate_zr_k(ZrArgs P)
{
    int t = threadIdx.x, lane = t & 63, wid = t >> 6;
    int sub = lane & 15, grp = lane >> 4;
    float oz[4] = {0.f, 0.f, 0.f, 0.f}, orr[4] = {0.f, 0.f, 0.f, 0.f};
    int blk = blockIdx.x;
    const u32* dzr; const float* Hp; float *Zp, *RHp;
    if (blk < NA / 4) {
        int i = blk * 4 + wid;
        gat_zr_et(i, i, lane, sub, grp, P.rp, P.cnt, P.csr, P.als0, P.ald0, P.xs0, oz, orr);
        gat_zr_et(NA + NB + i, i, lane, sub, grp, P.rp, P.cnt, P.csr, P.als2, P.ald2, P.xs2, oz, orr);
        dzr = P.dzrA + (size_t)i * 64; Hp = P.hA + (size_t)i * 64;
        Zp = P.zA + (size_t)i * 64; RHp = P.rhA + (size_t)i * 64;
    } else {
        int i = (blk - NA / 4) * 4 + wid;
        gat_zr_et(NA + i, i, lane, sub, grp, P.rp, P.cnt, P.csr, P.als1, P.ald1, P.xs1, oz, orr);
        dzr = P.dzrB + (size_t)i * 64; Hp = P.hB + (size_t)i * 64;
        Zp = P.zB + (size_t)i * 64; RHp = P.rhB + (size_t)i * 64;
    }
#pragma unroll
    for (int q = 0; q < 4; ++q) {
        oz[q] += __shfl_xor(oz[q], 16, 64); oz[q] += __shfl_xor(oz[q], 32, 64);
        orr[q] += __shfl_xor(orr[q], 16, 64); orr[q] += __shfl_xor(orr[q], 32, 64);
    }
    if (grp == 0) {
        uint4 d = *(const uint4*)(dzr + sub * 4);
        float4 h = *(const float4*)(Hp + sub * 4);
        float z0 = sigm(oz[0] + ubf(d.x << 16)), r0 = sigm(orr[0] + ubf(d.x & 0xffff0000u)) * h.x;
        float z1 = sigm(oz[1] + ubf(d.y << 16)), r1 = sigm(orr[1] + ubf(d.y & 0xffff0000u)) * h.y;
        float z2 = sigm(oz[2] + ubf(d.z << 16)), r2 = sigm(orr[2] + ubf(d.z & 0xffff0000u)) * h.z;
        float z3 = sigm(oz[3] + ubf(d.w << 16)), r3 = sigm(orr[3] + ubf(d.w & 0xffff0000u)) * h.w;
        *(float4*)(Zp + sub * 4) = make_float4(z0, z1, z2, z3);
        *(float4*)(RHp + sub * 4) = make_float4(r0, r1, r2, r3);
    }
}

struct NArgs {
    const int *rp, *cnt;
    const u16 *csr;
    const float *als0, *ald0, *als1, *ald1, *als2, *ald2;
    const uint2 *xs0, *xs1, *xs2;
    const u16 *dnA, *dnB;
    const float *hA, *hB, *zA, *zB;
    float *outA, *outB;
};

__global__ void __launch_bounds__(256) aggregate_n_k(NArgs P)
{
    int t = threadIdx.x, lane = t & 63, wid = t >> 6;
    int sub = lane & 15, grp = lane >> 4;
    float oa[4] = {0.f, 0.f, 0.f, 0.f};
    int blk = blockIdx.x;
    const u16* dn; const float *Hp, *Zp; float* Op;
    if (blk < NA / 4) {
        int i = blk * 4 + wid;
        gat_n_et(i, i, lane, sub, grp, P.rp, P.cnt, P.csr, P.als0, P.ald0, P.xs0, oa);
        gat_n_et(NA + NB + i, i, lane, sub, grp, P.rp, P.cnt, P.csr, P.als2, P.ald2, P.xs2, oa);
        dn = P.dnA + (size_t)i * 64; Hp = P.hA + (size_t)i * 64;
        Zp = P.zA + (size_t)i * 64; Op = P.outA + (size_t)i * 64;
    } else {
        int i = (blk - NA / 4) * 4 + wid;
        gat_n_et(NA + i, i, lane, sub, grp, P.rp, P.cnt, P.csr, P.als1, P.ald1, P.xs1, oa);
        dn = P.dnB + (size_t)i * 64; Hp = P.hB + (size_t)i * 64;
        Zp = P.zB + (size_t)i * 64; Op = P.outB + (size_t)i * 64;
    }
#pragma unroll
    for (int q = 0; q < 4; ++q) {
        oa[q] += __shfl_xor(oa[q], 16, 64); oa[q] += __shfl_xor(oa[q], 32, 64);
    }
    if (grp == 0) {
        uint2 d = *(const uint2*)(dn + sub * 4);
        float4 h = *(const float4*)(Hp + sub * 4);
        float4 zv = *(const float4*)(Zp + sub * 4);
        float pre[4];
        pre[0] = oa[0] + ubf(d.x << 16);
        pre[1] = oa[1] + ubf(d.x & 0xffff0000u);
        pre[2] = oa[2] + ubf(d.y << 16);
        pre[3] = oa[3] + ubf(d.y & 0xffff0000u);
        float o[4];
        float hh[4] = {h.x, h.y, h.z, h.w};
        float zz[4] = {zv.x, zv.y, zv.z, zv.w};
#pragma unroll
        for (int q = 0; q < 4; ++q) {
            float x2 = fminf(fmaxf(pre[q] * 2.f, -30.f), 30.f);
            float ex = __expf(x2);
            float nv = (ex - 1.f) / (ex + 1.f);
            o[q] = (1.f - zz[q]) * nv + zz[q] * hh[q];
        }
        *(float4*)(Op + sub * 4) = make_float4(o[0], o[1], o[2], o[3]);
    }
}

// ---------------- host side ----------------
extern "C" void kernel_launch(void* const* d_in, const int* in_sizes, int n_in,
                              void* d_out, int out_size, void* d_ws, size_t ws_size,
                              hipStream_t stream)
{
    (void)in_sizes; (void)n_in; (void)out_size; (void)ws_size;
    const float* x_a = (const float*)d_in[0];
    const float* x_b = (const float*)d_in[1];
    const float* h_a = (const float*)d_in[2];
    const float* h_b = (const float*)d_in[3];
    const float* Wx  = (const float*)d_in[4];
    const float* bx  = (const float*)d_in[5];
    const float* gws = (const float*)d_in[6];
    const float* gwd = (const float*)d_in[7];
    const float* gas = (const float*)d_in[8];
    const float* gad = (const float*)d_in[9];
    const float* gb  = (const float*)d_in[10];
    const int* ea2a_s = (const int*)d_in[11];
    const int* ea2a_d = (const int*)d_in[12];
    const int* ea2b_s = (const int*)d_in[13];
    const int* ea2b_d = (const int*)d_in[14];
    const int* eb2a_s = (const int*)d_in[15];
    const int* eb2a_d = (const int*)d_in[16];
    float* out = (float*)d_out;

    char* w = (char*)d_ws;
    auto alloc = [&](size_t bytes) -> char* {
        char* p = w;
        w += (bytes + 255) & ~(size_t)255;
        return p;
    };
    char* xsblk = alloc((size_t)(NA + NA + NB) * 64 * 4);
    u32* xs_zr0 = (u32*)xsblk;
    u32* xs_zr1 = (u32*)(xsblk + (size_t)NA * 64 * 4);
    u32* xs_zr2 = (u32*)(xsblk + (size_t)(NA + NA) * 64 * 4);
    u16* xs_n0 = (u16*)xsblk;
    u16* xs_n1 = (u16*)(xsblk + (size_t)NA * 64 * 2);
    u16* xs_n2 = (u16*)(xsblk + (size_t)(NA + NA) * 64 * 2);
    char* alblk = alloc((size_t)(4 * NA + 2 * NB) * 2 * 4);
    float* als_zr0 = (float*)alblk;
    float* als_zr1 = als_zr0 + (size_t)NA * 2;
    float* als_zr2 = als_zr1 + (size_t)NA * 2;
    float* ald_zr0 = als_zr2 + (size_t)NB * 2;
    float* ald_zr1 = ald_zr0 + (size_t)NA * 2;
    float* ald_zr2 = ald_zr1 + (size_t)NB * 2;
    float* als_n0 = (float*)alblk;
    float* als_n1 = als_n0 + NA;
    float* als_n2 = als_n1 + NA;
    float* ald_n0 = als_n2 + NB;
    float* ald_n1 = ald_n0 + NA;
    float* ald_n2 = ald_n1 + NB;
    float* zbuf  = (float*)alloc((size_t)(NA + NB) * 64 * 4);
    float* rhbuf = (float*)alloc((size_t)(NA + NB) * 64 * 4);
    u32* dzrA = (u32*)alloc((size_t)NA * 64 * 4);
    u32* dzrB = (u32*)alloc((size_t)NB * 64 * 4);
    u16* dnA = (u16*)alloc((size_t)NA * 64 * 2);
    u16* dnB = (u16*)alloc((size_t)NB * 64 * 2);
    u16* partial = (u16*)alloc((size_t)NSLICE * NCAT * 2);
    u32* soff    = (u32*)alloc((size_t)NSLICE * NCAT * 4);
    int* cnt = (int*)alloc((size_t)NCAT * 4);
    int* rp  = (int*)alloc((size_t)NCAT * 4);
    u16* csr = (u16*)alloc((size_t)ETOT * 2);
    int* bsum = (int*)alloc(512 * 4);

    const int nbC = (NCAT + 255) / 256;

    // ---- CSR build (no global atomics, no memset) ----
    hist_k<<<NCHUNK * NSLICE, 512, 0, stream>>>(ea2a_d, ea2b_d, eb2a_d, partial);
    scan_partial<<<nbC, 256, 0, stream>>>(partial, bsum, NCAT);
    scan_tops<<<1, 512, 0, stream>>>(bsum, nbC);
    scan_final<<<nbC, 256, 0, stream>>>(partial, bsum, rp, cnt, soff, NCAT);
    fill_k<<<NCHUNK * NSLICE, 512, 0, stream>>>(ea2a_s, ea2a_d, ea2b_s, ea2b_d, eb2a_s, eb2a_d,
                                                soff, csr);

    // ---- dense precompute (all 3 gates, both node types) ----
    gemm_x_k<<<(NA + NB) / 8, 256, 0, stream>>>(x_a, x_b, Wx, bx, gb, dzrA, dzrB, dnA, dnB);

    float* rh_a = rhbuf;
    float* rh_b = rhbuf + (size_t)NA * 64;
    float* z_a = zbuf;
    float* z_b = zbuf + (size_t)NA * 64;

    // ---- z+r MFMA GEMMs ----
    {
        MmArgs a{};
        a.H = h_a; a.ntiles = NA / 16;
        a.W0 = gws + 0 * 4096; a.W1 = gws + 3 * 4096;
        a.XS = xs_zr0;
        a.SW[0] = gws + 0 * 4096; a.SA[0] = gas + 0 * 64; a.SOUT[0] = als_zr0;
        a.SW[1] = gws + 3 * 4096; a.SA[1] = gas + 3 * 64; a.SOUT[1] = als_zr0 + 1;
        a.SW[2] = gws + 1 * 4096; a.SA[2] = gas + 1 * 64; a.SOUT[2] = als_zr1;
        a.SW[3] = gws + 4 * 4096; a.SA[3] = gas + 4 * 64; a.SOUT[3] = als_zr1 + 1;
        a.SW[4] = gwd + 0 * 4096; a.SA[4] = gad + 0 * 64; a.SOUT[4] = ald_zr0;
        a.SW[5] = gwd + 3 * 4096; a.SA[5] = gad + 3 * 64; a.SOUT[5] = ald_zr0 + 1;
        a.SW[6] = gwd + 2 * 4096; a.SA[6] = gad + 2 * 64; a.SOUT[6] = ald_zr2;
        a.SW[7] = gwd + 5 * 4096; a.SA[7] = gad + 5 * 64; a.SOUT[7] = ald_zr2 + 1;
        a.sstride = 2; a.nsc = 8;
        gemm_mfma<2><<<320, 256, 0, stream>>>(a);
    }
    {
        MmArgs a{};
        a.H = h_a; a.ntiles = NA / 16;
        a.W0 = gws + 1 * 4096; a.W1 = gws + 4 * 4096;
        a.XS = xs_zr1;
        a.sstride = 1; a.nsc = 0;
        gemm_mfma<2><<<320, 256, 0, stream>>>(a);
    }
    {
        MmArgs a{};
        a.H = h_b; a.ntiles = NB / 16;
        a.W0 = gws + 2 * 4096; a.W1 = gws + 5 * 4096;
        a.XS = xs_zr2;
        a.SW[0] = gws + 2 * 4096; a.SA[0] = gas + 2 * 64; a.SOUT[0] = als_zr2;
        a.SW[1] = gws + 5 * 4096; a.SA[1] = gas + 5 * 64; a.SOUT[1] = als_zr2 + 1;
        a.SW[2] = gwd + 1 * 4096; a.SA[2] = gad + 1 * 64; a.SOUT[2] = ald_zr1;
        a.SW[3] = gwd + 4 * 4096; a.SA[3] = gad + 4 * 64; a.SOUT[3] = ald_zr1 + 1;
        a.sstride = 2; a.nsc = 4;
        gemm_mfma<2><<<80, 256, 0, stream>>>(a);
    }

    // ---- z+r aggregation ----
    {
        ZrArgs P{};
        P.rp = rp; P.cnt = cnt; P.csr = csr;
        P.als0 = (const float2*)als_zr0; P.ald0 = (const float2*)ald_zr0;
        P.als1 = (const float2*)als_zr1; P.ald1 = (const float2*)ald_zr1;
        P.als2 = (const float2*)als_zr2; P.ald2 = (const float2*)ald_zr2;
        P.xs0 = (const uint4*)xs_zr0; P.xs1 = (const uint4*)xs_zr1; P.xs2 = (const uint4*)xs_zr2;
        P.dzrA = dzrA; P.dzrB = dzrB;
        P.hA = h_a; P.hB = h_b;
        P.zA = z_a; P.rhA = rh_a; P.zB = z_b; P.rhB = rh_b;
        aggregate_zr_k<<<(NA + NB) / 4, 256, 0, stream>>>(P);
    }

    // ---- n MFMA GEMMs (input rh) ----
    {
        MmArgs a{};
        a.H = rh_a; a.ntiles = NA / 16;
        a.W0 = gws + 6 * 4096; a.W1 = nullptr;
        a.XS = xs_n0;
        a.SW[0] = gws + 6 * 4096; a.SA[0] = gas + 6 * 64; a.SOUT[0] = als_n0;
        a.SW[1] = gws + 7 * 4096; a.SA[1] = gas + 7 * 64; a.SOUT[1] = als_n1;
        a.SW[2] = gwd + 6 * 4096; a.SA[2] = gad + 6 * 64; a.SOUT[2] = ald_n0;
        a.SW[3] = gwd + 8 * 4096; a.SA[3] = gad + 8 * 64; a.SOUT[3] = ald_n2;
        a.sstride = 1; a.nsc = 4;
        gemm_mfma<1><<<320, 256, 0, stream>>>(a);
    }
    {
        MmArgs a{};
        a.H = rh_a; a.ntiles = NA / 16;
        a.W0 = gws + 7 * 4096; a.W1 = nullptr;
        a.XS = xs_n1;
        a.sstride = 1; a.nsc = 0;
        gemm_mfma<1><<<320, 256, 0, stream>>>(a);
    }
    {
        MmArgs a{};
        a.H = rh_b; a.ntiles = NB / 16;
        a.W0 = gws + 8 * 4096; a.W1 = nullptr;
        a.XS = xs_n2;
        a.SW[0] = gws + 8 * 4096; a.SA[0] = gas + 8 * 64; a.SOUT[0] = als_n2;
        a.SW[1] = gwd + 7 * 4096; a.SA[1] = gad + 7 * 64; a.SOUT[1] = ald_n1;
        a.sstride = 1; a.nsc = 2;
        gemm_mfma<1><<<80, 256, 0, stream>>>(a);
    }

    // ---- n aggregation + GRU combine ----
    {
        NArgs P{};
        P.rp = rp; P.cnt = cnt; P.csr = csr;
        P.als0 = als_n0; P.ald0 = ald_n0;
        P.als1 = als_n1; P.ald1 = ald_n1;
        P.als2 = als_n2; P.ald2 = ald_n2;
        P.xs0 = (const uint2*)xs_n0; P.xs1 = (const uint2*)xs_n1; P.xs2 = (const uint2*)xs_n2;
        P.dnA = dnA; P.dnB = dnB;
        P.hA = h_a; P.hB = h_b; P.zA = z_a; P.zB = z_b;
        P.outA = out; P.outB = out + (size_t)NA * 64;
        aggregate_n_k<<<(NA + NB) / 4, 256, 0, stream>>>(P);
    }
}

// Round 11
// 316.520 us; speedup vs baseline: 2.1637x; 1.0001x over previous
//
#include <hip/hip_runtime.h>
#include <hip/hip_bf16.h>
#include <cstddef>
#include <cstdint>

#define NA 50000
#define NB 10000
#define D_IN 32
#define D_OUT 64
#define EA2A 800000
#define EA2B 400000
#define EB2A 400000
#define NCAT (NA + NB + NA)
#define ETOT (EA2A + EA2B + EB2A)
#define NCHUNK 8
#define CHUNK (NCAT / NCHUNK)          // 13750 nodes per chunk (55KB LDS)
#define NSLICE 64
#define ESLICE (ETOT / NSLICE)         // 25000 edges per slice

typedef unsigned int u32;
typedef unsigned short u16;
typedef __attribute__((ext_vector_type(8))) short short8_t;
typedef __attribute__((ext_vector_type(4))) float f32x4;
typedef __attribute__((ext_vector_type(2))) float f32x2;

// ---------------- helpers ----------------
__device__ __forceinline__ u32 bf16r(float x) {          // round-to-nearest-even bf16 bits
    u32 u = __float_as_uint(x);
    u += 0x7fffu + ((u >> 16) & 1u);
    return u >> 16;
}
__device__ __forceinline__ float ubf(u32 bits) { return __uint_as_float(bits); }
__device__ __forceinline__ float sigm(float x) { return 1.f / (1.f + __expf(-x)); }
__device__ __forceinline__ u32 cvtpk(float lo, float hi) {   // bf16(lo) | bf16(hi)<<16
    u32 r;
    asm("v_cvt_pk_bf16_f32 %0, %1, %2" : "=v"(r) : "v"(lo), "v"(hi));
    return r;
}
// packed dual-f32 fma: acc.lo += x.lo*p.lo ; acc.hi += x.hi*p.hi
__device__ __forceinline__ void pkfma(f32x2& acc, f32x2 x, f32x2 p) {
    asm("v_pk_fma_f32 %0, %1, %2, %0" : "+v"(acc) : "v"(x), "v"(p));
}

template <int CTRL, int RM>
__device__ __forceinline__ float dppf(float v) {
    return __int_as_float(__builtin_amdgcn_update_dpp(0, __float_as_int(v), CTRL, RM, 0xf, true));
}
__device__ __forceinline__ float wsum64(float v) {
    v += dppf<0x111, 0xf>(v);
    v += dppf<0x112, 0xf>(v);
    v += dppf<0x114, 0xf>(v);
    v += dppf<0x118, 0xf>(v);
    v += dppf<0x142, 0xa>(v);
    v += dppf<0x143, 0xc>(v);
    return __int_as_float(__builtin_amdgcn_readlane(__float_as_int(v), 63));
}

// ---------------- MFMA staging GEMM ----------------
// PACKED=1: NMAT==2 -> u32 zr-pair output; NMAT==1 -> u16 output.
// PACKED=0 (NMAT==2): two separate u16 outputs XS, XS1.
struct MmArgs {
    const float* H; int ntiles;
    const float* W0; const float* W1;
    void* XS; void* XS1;
    const float* SW[8]; const float* SA[8]; float* SOUT[8];
    int sstride; int nsc;
};

template <int NMAT, int PACKED>
__global__ void __launch_bounds__(256) gemm_mfma(MmArgs a)
{
    __shared__ float wvec[8][64];
    __shared__ short8_t bfr[NMAT * 8 + 2][64];
    int t = threadIdx.x;
    for (int idx = t; idx < a.nsc * 64; idx += 256) {
        int c = idx >> 6, k = idx & 63;
        const float* w = a.SW[c] + k * 64;
        const float* av = a.SA[c];
        float s = 0.f;
#pragma unroll 16
        for (int e = 0; e < 64; ++e) s = fmaf(w[e], av[e], s);
        wvec[c][k] = s;
    }
    __syncthreads();
    for (int idx = t; idx < NMAT * 8 * 64; idx += 256) {
        int fid = idx >> 6, l = idx & 63;
        int m = fid >> 3, r3 = fid & 7, tn = r3 >> 1, q = r3 & 1;
        const float* W = (NMAT == 2 && m == 1) ? a.W1 : a.W0;
        int kbase = 32 * q + ((l >> 4) << 3);
        int d = 16 * tn + (l & 15);
        short8_t v;
#pragma unroll
        for (int e = 0; e < 8; ++e) v[e] = (short)bf16r(W[(size_t)(kbase + e) * 64 + d]);
        bfr[fid][l] = v;
    }
    for (int idx = t; idx < 128; idx += 256) {
        int q = idx >> 6, l = idx & 63;
        int c = l & 15;
        int kbase = 32 * q + ((l >> 4) << 3);
        short8_t v;
#pragma unroll
        for (int e = 0; e < 8; ++e) v[e] = (c < a.nsc) ? (short)bf16r(wvec[c][kbase + e]) : (short)0;
        bfr[NMAT * 8 + q][l] = v;
    }
    __syncthreads();
    int lane = t & 63, wid = t >> 6;
    short8_t bw[NMAT][4][2], bs0, bs1;
#pragma unroll
    for (int m = 0; m < NMAT; ++m)
#pragma unroll
        for (int tn = 0; tn < 4; ++tn)
#pragma unroll
            for (int q = 0; q < 2; ++q) bw[m][tn][q] = bfr[m * 8 + tn * 2 + q][lane];
    bs0 = bfr[NMAT * 8][lane];
    bs1 = bfr[NMAT * 8 + 1][lane];

    int rl = lane & 15, kg = lane >> 4;
    f32x4 zero = {0.f, 0.f, 0.f, 0.f};
    for (int tile = blockIdx.x * 4 + wid; tile < a.ntiles; tile += gridDim.x * 4) {
        const float4* hp = (const float4*)(a.H + (size_t)(tile * 16 + rl) * 64) + kg * 2;
        float4 a0 = hp[0], a1 = hp[1];
        float4 b0 = hp[8], b1 = hp[9];
        union { short8_t s; u32 w[4]; } A0, A1;
        A0.w[0] = cvtpk(a0.x, a0.y); A0.w[1] = cvtpk(a0.z, a0.w);
        A0.w[2] = cvtpk(a1.x, a1.y); A0.w[3] = cvtpk(a1.z, a1.w);
        A1.w[0] = cvtpk(b0.x, b0.y); A1.w[1] = cvtpk(b0.z, b0.w);
        A1.w[2] = cvtpk(b1.x, b1.y); A1.w[3] = cvtpk(b1.z, b1.w);

        f32x4 acc[NMAT][4];
#pragma unroll
        for (int m = 0; m < NMAT; ++m)
#pragma unroll
            for (int tn = 0; tn < 4; ++tn) {
                f32x4 c0 = __builtin_amdgcn_mfma_f32_16x16x32_bf16(A0.s, bw[m][tn][0], zero, 0, 0, 0);
                acc[m][tn] = __builtin_amdgcn_mfma_f32_16x16x32_bf16(A1.s, bw[m][tn][1], c0, 0, 0, 0);
            }
        f32x4 accs = __builtin_amdgcn_mfma_f32_16x16x32_bf16(A0.s, bs0, zero, 0, 0, 0);
        accs = __builtin_amdgcn_mfma_f32_16x16x32_bf16(A1.s, bs1, accs, 0, 0, 0);

        int rbase = tile * 16 + kg * 4;
        if (NMAT == 2 && PACKED == 1) {
            u32* xo = (u32*)a.XS;
#pragma unroll
            for (int tn = 0; tn < 4; ++tn) {
                int d = tn * 16 + rl;
#pragma unroll
                for (int j = 0; j < 4; ++j)
                    xo[(size_t)(rbase + j) * 64 + d] = cvtpk(acc[0][tn][j], acc[1][tn][j]);
            }
        } else if (NMAT == 2 && PACKED == 0) {
            u16* xo0 = (u16*)a.XS;
            u16* xo1 = (u16*)a.XS1;
#pragma unroll
            for (int tn = 0; tn < 4; ++tn) {
                int d = tn * 16 + rl;
#pragma unroll
                for (int j = 0; j < 4; ++j) {
                    xo0[(size_t)(rbase + j) * 64 + d] = (u16)bf16r(acc[0][tn][j]);
                    xo1[(size_t)(rbase + j) * 64 + d] = (u16)bf16r(acc[1][tn][j]);
                }
            }
        } else {
            u16* xo = (u16*)a.XS;
#pragma unroll
            for (int tn = 0; tn < 4; ++tn) {
                int d = tn * 16 + rl;
#pragma unroll
                for (int j = 0; j < 4; ++j)
                    xo[(size_t)(rbase + j) * 64 + d] = (u16)bf16r(acc[0][tn][j]);
            }
        }
        if (rl < a.nsc) {
            float* so = a.SOUT[rl];
#pragma unroll
            for (int j = 0; j < 4; ++j) so[(size_t)(rbase + j) * a.sstride] = accs[j];
        }
    }
}

// ---------------- dense precompute: d*(node,dim) = x @ Wx[g] + bx + sum(gat_b) ----
__global__ void __launch_bounds__(256) gemm_x_k(
    const float* __restrict__ xA, const float* __restrict__ xB,
    const float* __restrict__ Wx, const float* __restrict__ bx, const float* __restrict__ gb,
    u32* __restrict__ dzrA, u32* __restrict__ dzrB,
    u16* __restrict__ dnA, u16* __restrict__ dnB)
{
    __shared__ float Wsh[3 * 2048];
    __shared__ float cb[3 * 64];
    int t = threadIdx.x;
    int blk = blockIdx.x;
    bool isA = blk < (NA / 8);
    int ty = isA ? 0 : 1;
#pragma unroll
    for (int g = 0; g < 3; ++g) {
        const float4* s = (const float4*)(Wx + (size_t)(g * 2 + ty) * 2048);
        float4* d = (float4*)&Wsh[g * 2048];
        for (int i = t; i < 512; i += 256) d[i] = s[i];
    }
    if (t < 192) {
        int g = t >> 6, d = t & 63;
        float c = bx[(g * 2 + ty) * 64 + d];
        if (isA) c += gb[(g * 3 + 0) * 64 + d] + gb[(g * 3 + 2) * 64 + d];
        else     c += gb[(g * 3 + 1) * 64 + d];
        cb[t] = c;
    }
    __syncthreads();
    int lane = t & 63, wid = t >> 6;
    const float* X = isA ? xA : xB;
    int N = isA ? NA : NB;
    int rbase = (isA ? blk : blk - NA / 8) * 8 + wid * 2;
    float cz = cb[lane], cr = cb[64 + lane], cn = cb[128 + lane];
#pragma unroll
    for (int rr = 0; rr < 2; ++rr) {
        int r = rbase + rr;
        if (r >= N) break;
        float xv = (lane < 32) ? X[(size_t)r * 32 + lane] : 0.f;
        float az = cz, ar = cr, an = cn;
#pragma unroll
        for (int k = 0; k < 32; ++k) {
            float xk = __shfl(xv, k, 64);
            az = fmaf(xk, Wsh[k * 64 + lane], az);
            ar = fmaf(xk, Wsh[2048 + k * 64 + lane], ar);
            an = fmaf(xk, Wsh[4096 + k * 64 + lane], an);
        }
        u32 zr = bf16r(az) | (bf16r(ar) << 16);
        u16 nn = (u16)bf16r(an);
        if (isA) { dzrA[(size_t)r * 64 + lane] = zr; dnA[(size_t)r * 64 + lane] = nn; }
        else     { dzrB[(size_t)r * 64 + lane] = zr; dnB[(size_t)r * 64 + lane] = nn; }
    }
}

// ---------------- CSR build: no global atomics ----------------
__global__ void __launch_bounds__(512) hist_k(
    const int* __restrict__ d0, const int* __restrict__ d1, const int* __restrict__ d2,
    u16* __restrict__ partial)
{
    __shared__ int hcnt[CHUNK];
    int k = blockIdx.x & (NCHUNK - 1);
    int s = blockIdx.x / NCHUNK;
    int lo = k * CHUNK;
    for (int i = threadIdx.x; i < CHUNK; i += 512) hcnt[i] = 0;
    __syncthreads();
    int e0 = s * ESLICE, e1 = e0 + ESLICE;
    for (int e = e0 + threadIdx.x; e < e1; e += 512) {
        int g;
        if (e < EA2A) g = d0[e];
        else if (e < EA2A + EA2B) g = NA + d1[e - EA2A];
        else g = NA + NB + d2[e - EA2A - EA2B];
        u32 rel = (u32)(g - lo);
        if (rel < CHUNK) atomicAdd(&hcnt[rel], 1);
    }
    __syncthreads();
    u16* po = partial + (size_t)s * NCAT + lo;
    for (int i = threadIdx.x; i < CHUNK; i += 512) po[i] = (u16)hcnt[i];
}

__global__ void scan_partial(const u16* __restrict__ partial, int* __restrict__ bsum, int N)
{
    __shared__ int sd[256];
    int t = threadIdx.x;
    int i = blockIdx.x * 256 + t;
    int v = 0;
    if (i < N) {
#pragma unroll 16
        for (int s = 0; s < NSLICE; ++s) v += partial[(size_t)s * NCAT + i];
    }
    sd[t] = v;
    __syncthreads();
    for (int off = 128; off; off >>= 1) {
        if (t < off) sd[t] += sd[t + off];
        __syncthreads();
    }
    if (t == 0) bsum[blockIdx.x] = sd[0];
}

__global__ void __launch_bounds__(512) scan_tops(int* bsum, int nb)
{
    __shared__ int sd[512];
    int t = threadIdx.x;
    int v = (t < nb) ? bsum[t] : 0;
    sd[t] = v;
    __syncthreads();
    for (int off = 1; off < 512; off <<= 1) {
        int add = (t >= off) ? sd[t - off] : 0;
        __syncthreads();
        sd[t] += add;
        __syncthreads();
    }
    if (t < nb) bsum[t] = sd[t] - v;   // exclusive
}

// merged: rowptr + cnt + per-slice RELATIVE start offsets (u16, rel to rp[g])
__global__ void scan_final(const u16* __restrict__ partial, const int* __restrict__ bsum,
                           int* __restrict__ rowptr, int* __restrict__ cnt,
                           u16* __restrict__ soff, int N)
{
    __shared__ int sd[256];
    int t = threadIdx.x;
    int i = blockIdx.x * 256 + t;
    int v = 0;
    if (i < N) {
#pragma unroll 16
        for (int s = 0; s < NSLICE; ++s) v += partial[(size_t)s * NCAT + i];
    }
    sd[t] = v;
    __syncthreads();
    for (int off = 1; off < 256; off <<= 1) {
        int add = (t >= off) ? sd[t - off] : 0;
        __syncthreads();
        sd[t] += add;
        __syncthreads();
    }
    if (i < N) {
        int rpi = bsum[blockIdx.x] + sd[t] - v;
        rowptr[i] = rpi;
        cnt[i] = v;
        int run = 0;   // relative to rp[i]; max = node degree << 65535
#pragma unroll 16
        for (int s = 0; s < NSLICE; ++s) {
            soff[(size_t)s * NCAT + i] = (u16)run;
            run += partial[(size_t)s * NCAT + i];
        }
    }
}

__global__ void __launch_bounds__(512) fill_k(
    const int* __restrict__ s0, const int* __restrict__ d0,
    const int* __restrict__ s1, const int* __restrict__ d1,
    const int* __restrict__ s2, const int* __restrict__ d2,
    const int* __restrict__ rp, const u16* __restrict__ soff, u16* __restrict__ csr)
{
    __shared__ int fpos[CHUNK];
    int k = blockIdx.x & (NCHUNK - 1);
    int s = blockIdx.x / NCHUNK;
    int lo = k * CHUNK;
    const u16* po = soff + (size_t)s * NCAT + lo;
    const int* rpo = rp + lo;
    for (int i = threadIdx.x; i < CHUNK; i += 512) fpos[i] = rpo[i] + (int)po[i];
    __syncthreads();
    int e0 = s * ESLICE, e1 = e0 + ESLICE;
    for (int e = e0 + threadIdx.x; e < e1; e += 512) {
        int g, sidx;
        const int* sp;
        if (e < EA2A) { g = d0[e]; sp = s0; sidx = e; }
        else if (e < EA2A + EA2B) { sidx = e - EA2A; g = NA + d1[sidx]; sp = s1; }
        else { sidx = e - EA2A - EA2B; g = NA + NB + d2[sidx]; sp = s2; }
        u32 rel = (u32)(g - lo);
        if (rel < CHUNK) {
            int src = sp[sidx];
            int p = atomicAdd(&fpos[rel], 1);   // LDS atomic only
            csr[p] = (u16)src;
        }
    }
}

// ---------------- GAT per-edge-type contributions ----------------
// m=0 softmax: logits are O(+-2) (weights*0.05), exp is range-safe; softmax is
// shift-invariant so this matches the reference's max-subtracted form exactly.
__device__ __forceinline__ void zr_pk(f32x2 azr[4], uint4 v, f32x2 p) {
    f32x2 x;
    x[0] = ubf(v.x << 16); x[1] = ubf(v.x & 0xffff0000u); pkfma(azr[0], x, p);
    x[0] = ubf(v.y << 16); x[1] = ubf(v.y & 0xffff0000u); pkfma(azr[1], x, p);
    x[0] = ubf(v.z << 16); x[1] = ubf(v.z & 0xffff0000u); pkfma(azr[2], x, p);
    x[0] = ubf(v.w << 16); x[1] = ubf(v.w & 0xffff0000u); pkfma(azr[3], x, p);
}

__device__ __forceinline__ void gat_zr_et(
    int gnode, int inode, int lane, int sub, int grp,
    const int* __restrict__ rp, const int* __restrict__ cnt, const u16* __restrict__ csr,
    const float2* __restrict__ als, const float2* __restrict__ ald,
    const uint4* __restrict__ xs,
    float oz[4], float orr[4])
{
    int deg = cnt[gnode];
    if (deg <= 0) return;
    int beg = rp[gnode];
    float2 ad = ald[inode];
    f32x2 azr[4];
#pragma unroll
    for (int q = 0; q < 4; ++q) { azr[q][0] = 0.f; azr[q][1] = 0.f; }
    float szl = 0.f, srl = 0.f;
    for (int base = 0; base < deg; base += 64) {
        int j = base + lane;
        int sj = 0; float pz = 0.f, pr = 0.f;
        if (j < deg) {
            sj = csr[beg + j];
            float2 al = als[sj];
            float tz = al.x + ad.x;
            float tr = al.y + ad.y;
            pz = __expf(fmaxf(tz, 0.2f * tz));
            pr = __expf(fmaxf(tr, 0.2f * tr));
        }
        szl += pz; srl += pr;
        u32 pk = (u32)sj | (bf16r(pz) << 16);   // invalid lanes: pk=0 -> contributes 0
        int c = deg - base; if (c > 64) c = 64;
        int b = 0;
        for (; b + 16 <= c; b += 16) {
            u32 k0 = (u32)__shfl((int)pk, b + grp, 64);
            u32 k1 = (u32)__shfl((int)pk, b + 4 + grp, 64);
            u32 k2 = (u32)__shfl((int)pk, b + 8 + grp, 64);
            u32 k3 = (u32)__shfl((int)pk, b + 12 + grp, 64);
            float q0 = __shfl(pr, b + grp, 64);
            float q1 = __shfl(pr, b + 4 + grp, 64);
            float q2 = __shfl(pr, b + 8 + grp, 64);
            float q3 = __shfl(pr, b + 12 + grp, 64);
            uint4 v0 = xs[(size_t)(k0 & 0xffffu) * 16 + sub];
            uint4 v1 = xs[(size_t)(k1 & 0xffffu) * 16 + sub];
            uint4 v2 = xs[(size_t)(k2 & 0xffffu) * 16 + sub];
            uint4 v3 = xs[(size_t)(k3 & 0xffffu) * 16 + sub];
            f32x2 p;
            p[0] = ubf(k0 & 0xffff0000u); p[1] = q0; zr_pk(azr, v0, p);
            p[0] = ubf(k1 & 0xffff0000u); p[1] = q1; zr_pk(azr, v1, p);
            p[0] = ubf(k2 & 0xffff0000u); p[1] = q2; zr_pk(azr, v2, p);
            p[0] = ubf(k3 & 0xffff0000u); p[1] = q3; zr_pk(azr, v3, p);
        }
        for (; b < c; b += 4) {
            u32 k0 = (u32)__shfl((int)pk, b + grp, 64);
            float q0 = __shfl(pr, b + grp, 64);
            uint4 v0 = xs[(size_t)(k0 & 0xffffu) * 16 + sub];
            f32x2 p;
            p[0] = ubf(k0 & 0xffff0000u); p[1] = q0;
            zr_pk(azr, v0, p);
        }
    }
    float sz = wsum64(szl), sr = wsum64(srl);
    float rz = 1.f / (sz + 1e-16f), rr = 1.f / (sr + 1e-16f);
#pragma unroll
    for (int q = 0; q < 4; ++q) {
        oz[q] = fmaf(azr[q][0], rz, oz[q]);
        orr[q] = fmaf(azr[q][1], rr, orr[q]);
    }
}

// n: 8-lane groups, full 128B row per group as one uint4 (8 bf16 dims/lane)
__device__ __forceinline__ void n_pk4(f32x2 ac[4], uint4 v, f32x2 p) {
    f32x2 x;
    x[0] = ubf(v.x << 16); x[1] = ubf(v.x & 0xffff0000u); pkfma(ac[0], x, p);
    x[0] = ubf(v.y << 16); x[1] = ubf(v.y & 0xffff0000u); pkfma(ac[1], x, p);
    x[0] = ubf(v.z << 16); x[1] = ubf(v.z & 0xffff0000u); pkfma(ac[2], x, p);
    x[0] = ubf(v.w << 16); x[1] = ubf(v.w & 0xffff0000u); pkfma(ac[3], x, p);
}

__device__ __forceinline__ void gat_n_et(
    int gnode, int inode, int lane, int sub8, int grp8,
    const int* __restrict__ rp, const int* __restrict__ cnt, const u16* __restrict__ csr,
    const float* __restrict__ als, const float* __restrict__ ald,
    const uint4* __restrict__ xs,        // row = 8 uint4
    f32x2 oa[4])
{
    int deg = cnt[gnode];
    if (deg <= 0) return;
    int beg = rp[gnode];
    float ad = ald[inode];
    f32x2 ac[4];
#pragma unroll
    for (int q = 0; q < 4; ++q) { ac[q][0] = 0.f; ac[q][1] = 0.f; }
    float ssl = 0.f;
    for (int base = 0; base < deg; base += 64) {
        int j = base + lane;
        int sj = 0; float pv = 0.f;
        if (j < deg) {
            sj = csr[beg + j];
            float tv = als[sj] + ad;
            pv = __expf(fmaxf(tv, 0.2f * tv));
        }
        ssl += pv;
        u32 pk = (u32)sj | (bf16r(pv) << 16);
        int c = deg - base; if (c > 64) c = 64;
        int b = 0;
        for (; b + 32 <= c; b += 32) {
            u32 kk[4];
#pragma unroll
            for (int u = 0; u < 4; ++u) kk[u] = (u32)__shfl((int)pk, b + 8 * u + grp8, 64);
            uint4 vv[4];
#pragma unroll
            for (int u = 0; u < 4; ++u) vv[u] = xs[(size_t)(kk[u] & 0xffffu) * 8 + sub8];
#pragma unroll
            for (int u = 0; u < 4; ++u) {
                f32x2 p; p[0] = ubf(kk[u] & 0xffff0000u); p[1] = p[0];
                n_pk4(ac, vv[u], p);
            }
        }
        for (; b < c; b += 8) {
            u32 k0 = (u32)__shfl((int)pk, b + grp8, 64);
            uint4 v0 = xs[(size_t)(k0 & 0xffffu) * 8 + sub8];
            f32x2 p; p[0] = ubf(k0 & 0xffff0000u); p[1] = p[0];
            n_pk4(ac, v0, p);
        }
    }
    float ss = wsum64(ssl);
    float rs = 1.f / (ss + 1e-16f);
#pragma unroll
    for (int q = 0; q < 4; ++q) {
        oa[q][0] = fmaf(ac[q][0], rs, oa[q][0]);
        oa[q][1] = fmaf(ac[q][1], rs, oa[q][1]);
    }
}

// ---------------- aggregate kernels (A and B merged) ----------------
struct ZrArgs {
    const int *rp, *cnt;
    const u16 *csr;
    const float2 *als0, *ald0, *als1, *ald1, *als2, *ald2;
    const uint4 *xs0, *xs1, *xs2;
    const u32 *dzrA, *dzrB;
    const float *hA, *hB;
    float *zA, *rhA, *zB, *rhB;
};

__global__ void __launch_bounds__(256) aggregate_zr_k(ZrArgs P)
{
    int t = threadIdx.x, lane = t & 63, wid = t >> 6;
    int sub = lane & 15, grp = lane >> 4;
    float oz[4] = {0.f, 0.f, 0.f, 0.f}, orr[4] = {0.f, 0.f, 0.f, 0.f};
    int blk = blockIdx.x;
    const u32* dzr; const float* Hp; float *Zp, *RHp;
    if (blk < NA / 4) {
        int i = blk * 4 + wid;
        gat_zr_et(i, i, lane, sub, grp, P.rp, P.cnt, P.csr, P.als0, P.ald0, P.xs0, oz, orr);
        gat_zr_et(NA + NB + i, i, lane, sub, grp, P.rp, P.cnt, P.csr, P.als2, P.ald2, P.xs2, oz, orr);
        dzr = P.dzrA + (size_t)i * 64; Hp = P.hA + (size_t)i * 64;
        Zp = P.zA + (size_t)i * 64; RHp = P.rhA + (size_t)i * 64;
    } else {
        int i = (blk - NA / 4) * 4 + wid;
        gat_zr_et(NA + i, i, lane, sub, grp, P.rp, P.cnt, P.csr, P.als1, P.ald1, P.xs1, oz, orr);
        dzr = P.dzrB + (size_t)i * 64; Hp = P.hB + (size_t)i * 64;
        Zp = P.zB + (size_t)i * 64; RHp = P.rhB + (size_t)i * 64;
    }
#pragma unroll
    for (int q = 0; q < 4; ++q) {
        oz[q] += __shfl_xor(oz[q], 16, 64); oz[q] += __shfl_xor(oz[q], 32, 64);
        orr[q] += __shfl_xor(orr[q], 16, 64); orr[q] += __shfl_xor(orr[q], 32, 64);
    }
    if (grp == 0) {
        uint4 d = *(const uint4*)(dzr + sub * 4);
        float4 h = *(const float4*)(Hp + sub * 4);
        float z0 = sigm(oz[0] + ubf(d.x << 16)), r0 = sigm(orr[0] + ubf(d.x & 0xffff0000u)) * h.x;
        float z1 = sigm(oz[1] + ubf(d.y << 16)), r1 = sigm(orr[1] + ubf(d.y & 0xffff0000u)) * h.y;
        float z2 = sigm(oz[2] + ubf(d.z << 16)), r2 = sigm(orr[2] + ubf(d.z & 0xffff0000u)) * h.z;
        float z3 = sigm(oz[3] + ubf(d.w << 16)), r3 = sigm(orr[3] + ubf(d.w & 0xffff0000u)) * h.w;
        *(float4*)(Zp + sub * 4) = make_float4(z0, z1, z2, z3);
        *(float4*)(RHp + sub * 4) = make_float4(r0, r1, r2, r3);
    }
}

struct NArgs {
    const int *rp, *cnt;
    const u16 *csr;
    const float *als0, *ald0, *als1, *ald1, *als2, *ald2;
    const uint4 *xs0, *xs1, *xs2;
    const u16 *dnA, *dnB;
    const float *hA, *hB, *zA, *zB;
    float *outA, *outB;
};

__global__ void __launch_bounds__(256) aggregate_n_k(NArgs P)
{
    int t = threadIdx.x, lane = t & 63, wid = t >> 6;
    int sub8 = lane & 7, grp8 = lane >> 3;
    f32x2 oa[4];
#pragma unroll
    for (int q = 0; q < 4; ++q) { oa[q][0] = 0.f; oa[q][1] = 0.f; }
    int blk = blockIdx.x;
    const u16* dn; const float *Hp, *Zp; float* Op;
    if (blk < NA / 4) {
        int i = blk * 4 + wid;
        gat_n_et(i, i, lane, sub8, grp8, P.rp, P.cnt, P.csr, P.als0, P.ald0, P.xs0, oa);
        gat_n_et(NA + NB + i, i, lane, sub8, grp8, P.rp, P.cnt, P.csr, P.als2, P.ald2, P.xs2, oa);
        dn = P.dnA + (size_t)i * 64; Hp = P.hA + (size_t)i * 64;
        Zp = P.zA + (size_t)i * 64; Op = P.outA + (size_t)i * 64;
    } else {
        int i = (blk - NA / 4) * 4 + wid;
        gat_n_et(NA + i, i, lane, sub8, grp8, P.rp, P.cnt, P.csr, P.als1, P.ald1, P.xs1, oa);
        dn = P.dnB + (size_t)i * 64; Hp = P.hB + (size_t)i * 64;
        Zp = P.zB + (size_t)i * 64; Op = P.outB + (size_t)i * 64;
    }
#pragma unroll
    for (int q = 0; q < 4; ++q) {
#pragma unroll
        for (int e = 0; e < 2; ++e) {
            oa[q][e] += __shfl_xor(oa[q][e], 8, 64);
            oa[q][e] += __shfl_xor(oa[q][e], 16, 64);
            oa[q][e] += __shfl_xor(oa[q][e], 32, 64);
        }
    }
    if (grp8 == 0) {
        // lane sub8 owns dims [sub8*8, sub8*8+8)
        uint4 d = *(const uint4*)(dn + sub8 * 8);
        float4 h0 = *(const float4*)(Hp + sub8 * 8);
        float4 h1 = *(const float4*)(Hp + sub8 * 8 + 4);
        float4 zv0 = *(const float4*)(Zp + sub8 * 8);
        float4 zv1 = *(const float4*)(Zp + sub8 * 8 + 4);
        float pre[8];
        pre[0] = oa[0][0] + ubf(d.x << 16); pre[1] = oa[0][1] + ubf(d.x & 0xffff0000u);
        pre[2] = oa[1][0] + ubf(d.y << 16); pre[3] = oa[1][1] + ubf(d.y & 0xffff0000u);
        pre[4] = oa[2][0] + ubf(d.z << 16); pre[5] = oa[2][1] + ubf(d.z & 0xffff0000u);
        pre[6] = oa[3][0] + ubf(d.w << 16); pre[7] = oa[3][1] + ubf(d.w & 0xffff0000u);
        float hh[8] = {h0.x, h0.y, h0.z, h0.w, h1.x, h1.y, h1.z, h1.w};
        float zz[8] = {zv0.x, zv0.y, zv0.z, zv0.w, zv1.x, zv1.y, zv1.z, zv1.w};
        float o[8];
#pragma unroll
        for (int q = 0; q < 8; ++q) {
            float x2 = fminf(fmaxf(pre[q] * 2.f, -30.f), 30.f);
            float ex = __expf(x2);
            float nv = (ex - 1.f) / (ex + 1.f);
            o[q] = (1.f - zz[q]) * nv + zz[q] * hh[q];
        }
        *(float4*)(Op + sub8 * 8) = make_float4(o[0], o[1], o[2], o[3]);
        *(float4*)(Op + sub8 * 8 + 4) = make_float4(o[4], o[5], o[6], o[7]);
    }
}

// ---------------- host side ----------------
extern "C" void kernel_launch(void* const* d_in, const int* in_sizes, int n_in,
                              void* d_out, int out_size, void* d_ws, size_t ws_size,
                              hipStream_t stream)
{
    (void)in_sizes; (void)n_in; (void)out_size; (void)ws_size;
    const float* x_a = (const float*)d_in[0];
    const float* x_b = (const float*)d_in[1];
    const float* h_a = (const float*)d_in[2];
    const float* h_b = (const float*)d_in[3];
    const float* Wx  = (const float*)d_in[4];
    const float* bx  = (const float*)d_in[5];
    const float* gws = (const float*)d_in[6];
    const float* gwd = (const float*)d_in[7];
    const float* gas = (const float*)d_in[8];
    const float* gad = (const float*)d_in[9];
    const float* gb  = (const float*)d_in[10];
    const int* ea2a_s = (const int*)d_in[11];
    const int* ea2a_d = (const int*)d_in[12];
    const int* ea2b_s = (const int*)d_in[13];
    const int* ea2b_d = (const int*)d_in[14];
    const int* eb2a_s = (const int*)d_in[15];
    const int* eb2a_d = (const int*)d_in[16];
    float* out = (float*)d_out;

    char* w = (char*)d_ws;
    auto alloc = [&](size_t bytes) -> char* {
        char* p = w;
        w += (bytes + 255) & ~(size_t)255;
        return p;
    };
    char* xsblk = alloc((size_t)(NA + NA + NB) * 64 * 4);
    u32* xs_zr0 = (u32*)xsblk;
    u32* xs_zr1 = (u32*)(xsblk + (size_t)NA * 64 * 4);
    u32* xs_zr2 = (u32*)(xsblk + (size_t)(NA + NA) * 64 * 4);
    u16* xs_n0 = (u16*)xsblk;
    u16* xs_n1 = (u16*)(xsblk + (size_t)NA * 64 * 2);
    u16* xs_n2 = (u16*)(xsblk + (size_t)(NA + NA) * 64 * 2);
    char* alblk = alloc((size_t)(4 * NA + 2 * NB) * 2 * 4);
    float* als_zr0 = (float*)alblk;
    float* als_zr1 = als_zr0 + (size_t)NA * 2;
    float* als_zr2 = als_zr1 + (size_t)NA * 2;
    float* ald_zr0 = als_zr2 + (size_t)NB * 2;
    float* ald_zr1 = ald_zr0 + (size_t)NA * 2;
    float* ald_zr2 = ald_zr1 + (size_t)NB * 2;
    float* als_n0 = (float*)alblk;
    float* als_n1 = als_n0 + NA;
    float* als_n2 = als_n1 + NA;
    float* ald_n0 = als_n2 + NB;
    float* ald_n1 = ald_n0 + NA;
    float* ald_n2 = ald_n1 + NB;
    float* zbuf  = (float*)alloc((size_t)(NA + NB) * 64 * 4);
    float* rhbuf = (float*)alloc((size_t)(NA + NB) * 64 * 4);
    u32* dzrA = (u32*)alloc((size_t)NA * 64 * 4);
    u32* dzrB = (u32*)alloc((size_t)NB * 64 * 4);
    u16* dnA = (u16*)alloc((size_t)NA * 64 * 2);
    u16* dnB = (u16*)alloc((size_t)NB * 64 * 2);
    u16* partial = (u16*)alloc((size_t)NSLICE * NCAT * 2);
    u16* soff    = (u16*)alloc((size_t)NSLICE * NCAT * 2);
    int* cnt = (int*)alloc((size_t)NCAT * 4);
    int* rp  = (int*)alloc((size_t)NCAT * 4);
    u16* csr = (u16*)alloc((size_t)ETOT * 2);
    int* bsum = (int*)alloc(512 * 4);

    const int nbC = (NCAT + 255) / 256;

    // ---- CSR build (no global atomics, no memset) ----
    hist_k<<<NCHUNK * NSLICE, 512, 0, stream>>>(ea2a_d, ea2b_d, eb2a_d, partial);
    scan_partial<<<nbC, 256, 0, stream>>>(partial, bsum, NCAT);
    scan_tops<<<1, 512, 0, stream>>>(bsum, nbC);
    scan_final<<<nbC, 256, 0, stream>>>(partial, bsum, rp, cnt, soff, NCAT);
    fill_k<<<NCHUNK * NSLICE, 512, 0, stream>>>(ea2a_s, ea2a_d, ea2b_s, ea2b_d, eb2a_s, eb2a_d,
                                                rp, soff, csr);

    // ---- dense precompute (all 3 gates, both node types) ----
    gemm_x_k<<<(NA + NB) / 8, 256, 0, stream>>>(x_a, x_b, Wx, bx, gb, dzrA, dzrB, dnA, dnB);

    float* rh_a = rhbuf;
    float* rh_b = rhbuf + (size_t)NA * 64;
    float* z_a = zbuf;
    float* z_b = zbuf + (size_t)NA * 64;

    // ---- z+r MFMA GEMMs ----
    {
        MmArgs a{};
        a.H = h_a; a.ntiles = NA / 16;
        a.W0 = gws + 0 * 4096; a.W1 = gws + 3 * 4096;
        a.XS = xs_zr0;
        a.SW[0] = gws + 0 * 4096; a.SA[0] = gas + 0 * 64; a.SOUT[0] = als_zr0;
        a.SW[1] = gws + 3 * 4096; a.SA[1] = gas + 3 * 64; a.SOUT[1] = als_zr0 + 1;
        a.SW[2] = gws + 1 * 4096; a.SA[2] = gas + 1 * 64; a.SOUT[2] = als_zr1;
        a.SW[3] = gws + 4 * 4096; a.SA[3] = gas + 4 * 64; a.SOUT[3] = als_zr1 + 1;
        a.SW[4] = gwd + 0 * 4096; a.SA[4] = gad + 0 * 64; a.SOUT[4] = ald_zr0;
        a.SW[5] = gwd + 3 * 4096; a.SA[5] = gad + 3 * 64; a.SOUT[5] = ald_zr0 + 1;
        a.SW[6] = gwd + 2 * 4096; a.SA[6] = gad + 2 * 64; a.SOUT[6] = ald_zr2;
        a.SW[7] = gwd + 5 * 4096; a.SA[7] = gad + 5 * 64; a.SOUT[7] = ald_zr2 + 1;
        a.sstride = 2; a.nsc = 8;
        gemm_mfma<2, 1><<<320, 256, 0, stream>>>(a);
    }
    {
        MmArgs a{};
        a.H = h_a; a.ntiles = NA / 16;
        a.W0 = gws + 1 * 4096; a.W1 = gws + 4 * 4096;
        a.XS = xs_zr1;
        a.sstride = 1; a.nsc = 0;
        gemm_mfma<2, 1><<<320, 256, 0, stream>>>(a);
    }
    {
        MmArgs a{};
        a.H = h_b; a.ntiles = NB / 16;
        a.W0 = gws + 2 * 4096; a.W1 = gws + 5 * 4096;
        a.XS = xs_zr2;
        a.SW[0] = gws + 2 * 4096; a.SA[0] = gas + 2 * 64; a.SOUT[0] = als_zr2;
        a.SW[1] = gws + 5 * 4096; a.SA[1] = gas + 5 * 64; a.SOUT[1] = als_zr2 + 1;
        a.SW[2] = gwd + 1 * 4096; a.SA[2] = gad + 1 * 64; a.SOUT[2] = ald_zr1;
        a.SW[3] = gwd + 4 * 4096; a.SA[3] = gad + 4 * 64; a.SOUT[3] = ald_zr1 + 1;
        a.sstride = 2; a.nsc = 4;
        gemm_mfma<2, 1><<<80, 256, 0, stream>>>(a);
    }

    // ---- z+r aggregation ----
    {
        ZrArgs P{};
        P.rp = rp; P.cnt = cnt; P.csr = csr;
        P.als0 = (const float2*)als_zr0; P.ald0 = (const float2*)ald_zr0;
        P.als1 = (const float2*)als_zr1; P.ald1 = (const float2*)ald_zr1;
        P.als2 = (const float2*)als_zr2; P.ald2 = (const float2*)ald_zr2;
        P.xs0 = (const uint4*)xs_zr0; P.xs1 = (const uint4*)xs_zr1; P.xs2 = (const uint4*)xs_zr2;
        P.dzrA = dzrA; P.dzrB = dzrB;
        P.hA = h_a; P.hB = h_b;
        P.zA = z_a; P.rhA = rh_a; P.zB = z_b; P.rhB = rh_b;
        aggregate_zr_k<<<(NA + NB) / 4, 256, 0, stream>>>(P);
    }

    // ---- n MFMA GEMMs (input rh) ----
    {   // fused: (n,a2a) -> xs_n0 and (n,a2b) -> xs_n1, one rh_a read
        MmArgs a{};
        a.H = rh_a; a.ntiles = NA / 16;
        a.W0 = gws + 6 * 4096; a.W1 = gws + 7 * 4096;
        a.XS = xs_n0; a.XS1 = xs_n1;
        a.SW[0] = gws + 6 * 4096; a.SA[0] = gas + 6 * 64; a.SOUT[0] = als_n0;
        a.SW[1] = gws + 7 * 4096; a.SA[1] = gas + 7 * 64; a.SOUT[1] = als_n1;
        a.SW[2] = gwd + 6 * 4096; a.SA[2] = gad + 6 * 64; a.SOUT[2] = ald_n0;
        a.SW[3] = gwd + 8 * 4096; a.SA[3] = gad + 8 * 64; a.SOUT[3] = ald_n2;
        a.sstride = 1; a.nsc = 4;
        gemm_mfma<2, 0><<<320, 256, 0, stream>>>(a);
    }
    {
        MmArgs a{};
        a.H = rh_b; a.ntiles = NB / 16;
        a.W0 = gws + 8 * 4096; a.W1 = nullptr;
        a.XS = xs_n2;
        a.SW[0] = gws + 8 * 4096; a.SA[0] = gas + 8 * 64; a.SOUT[0] = als_n2;
        a.SW[1] = gwd + 7 * 4096; a.SA[1] = gad + 7 * 64; a.SOUT[1] = ald_n1;
        a.sstride = 1; a.nsc = 2;
        gemm_mfma<1, 1><<<80, 256, 0, stream>>>(a);
    }

    // ---- n aggregation + GRU combine ----
    {
        NArgs P{};
        P.rp = rp; P.cnt = cnt; P.csr = csr;
        P.als0 = als_n0; P.ald0 = ald_n0;
        P.als1 = als_n1; P.ald1 = ald_n1;
        P.als2 = als_n2; P.ald2 = ald_n2;
        P.xs0 = (const uint4*)xs_n0; P.xs1 = (const uint4*)xs_n1; P.xs2 = (const uint4*)xs_n2;
        P.dnA = dnA; P.dnB = dnB;
        P.hA = h_a; P.hB = h_b; P.zA = z_a; P.zB = z_b;
        P.outA = out; P.outB = out + (size_t)NA * 64;
        aggregate_n_k<<<(NA + NB) / 4, 256, 0, stream>>>(P);
    }
}

// Round 12
// 314.944 us; speedup vs baseline: 2.1745x; 1.0050x over previous
//
#include <hip/hip_runtime.h>
#include <hip/hip_bf16.h>
#include <cstddef>
#include <cstdint>

#define NA 50000
#define NB 10000
#define D_IN 32
#define D_OUT 64
#define EA2A 800000
#define EA2B 400000
#define EB2A 400000
#define NCAT (NA + NB + NA)
#define ETOT (EA2A + EA2B + EB2A)
#define NCHUNK 8
#define CHUNK (NCAT / NCHUNK)          // 13750 nodes per chunk (55KB LDS)
#define NSLICE 64
#define ESLICE (ETOT / NSLICE)         // 25000 edges per slice

typedef unsigned int u32;
typedef unsigned short u16;
typedef __attribute__((ext_vector_type(8))) short short8_t;
typedef __attribute__((ext_vector_type(4))) float f32x4;
typedef __attribute__((ext_vector_type(2))) float f32x2;

// ---------------- helpers ----------------
__device__ __forceinline__ u32 bf16r(float x) {          // round-to-nearest-even bf16 bits
    u32 u = __float_as_uint(x);
    u += 0x7fffu + ((u >> 16) & 1u);
    return u >> 16;
}
__device__ __forceinline__ float ubf(u32 bits) { return __uint_as_float(bits); }
__device__ __forceinline__ float sigm(float x) { return 1.f / (1.f + __expf(-x)); }
__device__ __forceinline__ u32 cvtpk(float lo, float hi) {   // bf16(lo) | bf16(hi)<<16
    u32 r;
    asm("v_cvt_pk_bf16_f32 %0, %1, %2" : "=v"(r) : "v"(lo), "v"(hi));
    return r;
}
// packed dual-f32 fma: acc.lo += x.lo*p.lo ; acc.hi += x.hi*p.hi
__device__ __forceinline__ void pkfma(f32x2& acc, f32x2 x, f32x2 p) {
    asm("v_pk_fma_f32 %0, %1, %2, %0" : "+v"(acc) : "v"(x), "v"(p));
}

template <int CTRL, int RM>
__device__ __forceinline__ float dppf(float v) {
    return __int_as_float(__builtin_amdgcn_update_dpp(0, __float_as_int(v), CTRL, RM, 0xf, true));
}
__device__ __forceinline__ float wsum64(float v) {
    v += dppf<0x111, 0xf>(v);
    v += dppf<0x112, 0xf>(v);
    v += dppf<0x114, 0xf>(v);
    v += dppf<0x118, 0xf>(v);
    v += dppf<0x142, 0xa>(v);
    v += dppf<0x143, 0xc>(v);
    return __int_as_float(__builtin_amdgcn_readlane(__float_as_int(v), 63));
}

// ---------------- MFMA staging GEMM (multi-region) ----------------
// PACKED=1 (NMAT==2): u32 zr-pair output in XS.
// PACKED=0 (NMAT==2): two separate u16 outputs XS, XS1.
// HB16: H rows are bf16 (u16[64]); else f32 rows (cvtpk on load).
struct MmArgs {
    const void* H; int ntiles;
    const float* W0; const float* W1;
    void* XS; void* XS1;
    const float* SW[8]; const float* SA[8]; float* SOUT[8];
    int sstride; int nsc;
};
struct MmMulti {
    MmArgs r[3];
    int n0, n1;   // blocks in region 0, 1 (region 2 = rest)
};

template <int NMAT, int PACKED, int HB16>
__global__ void __launch_bounds__(256) gemm_mfma(MmMulti m)
{
    __shared__ float wvec[8][64];
    __shared__ short8_t bfr[NMAT * 8 + 2][64];
    int b = blockIdx.x;
    const MmArgs* Rp; int lb, nb;
    if (b < m.n0) { Rp = &m.r[0]; lb = b; nb = m.n0; }
    else if (b < m.n0 + m.n1) { Rp = &m.r[1]; lb = b - m.n0; nb = m.n1; }
    else { Rp = &m.r[2]; lb = b - m.n0 - m.n1; nb = gridDim.x - m.n0 - m.n1; }
    const MmArgs a = *Rp;
    int t = threadIdx.x;
    for (int idx = t; idx < a.nsc * 64; idx += 256) {
        int c = idx >> 6, k = idx & 63;
        const float* w = a.SW[c] + k * 64;
        const float* av = a.SA[c];
        float s = 0.f;
#pragma unroll 16
        for (int e = 0; e < 64; ++e) s = fmaf(w[e], av[e], s);
        wvec[c][k] = s;
    }
    __syncthreads();
    for (int idx = t; idx < NMAT * 8 * 64; idx += 256) {
        int fid = idx >> 6, l = idx & 63;
        int mm = fid >> 3, r3 = fid & 7, tn = r3 >> 1, q = r3 & 1;
        const float* W = (NMAT == 2 && mm == 1) ? a.W1 : a.W0;
        int kbase = 32 * q + ((l >> 4) << 3);
        int d = 16 * tn + (l & 15);
        short8_t v;
#pragma unroll
        for (int e = 0; e < 8; ++e) v[e] = (short)bf16r(W[(size_t)(kbase + e) * 64 + d]);
        bfr[fid][l] = v;
    }
    for (int idx = t; idx < 128; idx += 256) {
        int q = idx >> 6, l = idx & 63;
        int c = l & 15;
        int kbase = 32 * q + ((l >> 4) << 3);
        short8_t v;
#pragma unroll
        for (int e = 0; e < 8; ++e) v[e] = (c < a.nsc) ? (short)bf16r(wvec[c][kbase + e]) : (short)0;
        bfr[NMAT * 8 + q][l] = v;
    }
    __syncthreads();
    int lane = t & 63, wid = t >> 6;
    short8_t bw[NMAT][4][2], bs0, bs1;
#pragma unroll
    for (int mm = 0; mm < NMAT; ++mm)
#pragma unroll
        for (int tn = 0; tn < 4; ++tn)
#pragma unroll
            for (int q = 0; q < 2; ++q) bw[mm][tn][q] = bfr[mm * 8 + tn * 2 + q][lane];
    bs0 = bfr[NMAT * 8][lane];
    bs1 = bfr[NMAT * 8 + 1][lane];

    int rl = lane & 15, kg = lane >> 4;
    f32x4 zero = {0.f, 0.f, 0.f, 0.f};
    for (int tile = lb * 4 + wid; tile < a.ntiles; tile += nb * 4) {
        union { uint4 u; short8_t s; } A0, A1;
        if (HB16) {
            const uint4* hp = (const uint4*)((const u16*)a.H + (size_t)(tile * 16 + rl) * 64);
            A0.u = hp[kg];
            A1.u = hp[4 + kg];
        } else {
            const float4* hp = (const float4*)((const float*)a.H + (size_t)(tile * 16 + rl) * 64) + kg * 2;
            float4 a0 = hp[0], a1 = hp[1];
            float4 b0 = hp[8], b1 = hp[9];
            A0.u.x = cvtpk(a0.x, a0.y); A0.u.y = cvtpk(a0.z, a0.w);
            A0.u.z = cvtpk(a1.x, a1.y); A0.u.w = cvtpk(a1.z, a1.w);
            A1.u.x = cvtpk(b0.x, b0.y); A1.u.y = cvtpk(b0.z, b0.w);
            A1.u.z = cvtpk(b1.x, b1.y); A1.u.w = cvtpk(b1.z, b1.w);
        }

        f32x4 acc[NMAT][4];
#pragma unroll
        for (int mm = 0; mm < NMAT; ++mm)
#pragma unroll
            for (int tn = 0; tn < 4; ++tn) {
                f32x4 c0 = __builtin_amdgcn_mfma_f32_16x16x32_bf16(A0.s, bw[mm][tn][0], zero, 0, 0, 0);
                acc[mm][tn] = __builtin_amdgcn_mfma_f32_16x16x32_bf16(A1.s, bw[mm][tn][1], c0, 0, 0, 0);
            }
        f32x4 accs = __builtin_amdgcn_mfma_f32_16x16x32_bf16(A0.s, bs0, zero, 0, 0, 0);
        accs = __builtin_amdgcn_mfma_f32_16x16x32_bf16(A1.s, bs1, accs, 0, 0, 0);

        int rbase = tile * 16 + kg * 4;
        if (NMAT == 2 && PACKED == 1) {
            u32* xo = (u32*)a.XS;
#pragma unroll
            for (int tn = 0; tn < 4; ++tn) {
                int d = tn * 16 + rl;
#pragma unroll
                for (int j = 0; j < 4; ++j)
                    xo[(size_t)(rbase + j) * 64 + d] = cvtpk(acc[0][tn][j], acc[1][tn][j]);
            }
        } else if (NMAT == 2 && PACKED == 0) {
            u16* xo0 = (u16*)a.XS;
            u16* xo1 = (u16*)a.XS1;
#pragma unroll
            for (int tn = 0; tn < 4; ++tn) {
                int d = tn * 16 + rl;
#pragma unroll
                for (int j = 0; j < 4; ++j) {
                    xo0[(size_t)(rbase + j) * 64 + d] = (u16)bf16r(acc[0][tn][j]);
                    xo1[(size_t)(rbase + j) * 64 + d] = (u16)bf16r(acc[1][tn][j]);
                }
            }
        } else {
            u16* xo = (u16*)a.XS;
#pragma unroll
            for (int tn = 0; tn < 4; ++tn) {
                int d = tn * 16 + rl;
#pragma unroll
                for (int j = 0; j < 4; ++j)
                    xo[(size_t)(rbase + j) * 64 + d] = (u16)bf16r(acc[0][tn][j]);
            }
        }
        if (rl < a.nsc) {
            float* so = a.SOUT[rl];
#pragma unroll
            for (int j = 0; j < 4; ++j) so[(size_t)(rbase + j) * a.sstride] = accs[j];
        }
    }
}

// ---------------- dense precompute: d*(node,dim) = x @ Wx[g] + bx + sum(gat_b) ----
// 512 blocks grid-stride (448 A / 64 B); W staged once per block.
__global__ void __launch_bounds__(256) gemm_x_k(
    const float* __restrict__ xA, const float* __restrict__ xB,
    const float* __restrict__ Wx, const float* __restrict__ bx, const float* __restrict__ gb,
    u32* __restrict__ dzrA, u32* __restrict__ dzrB,
    u16* __restrict__ dnA, u16* __restrict__ dnB)
{
    __shared__ float Wsh[3 * 2048];
    __shared__ float cb[3 * 64];
    int t = threadIdx.x;
    int blk = blockIdx.x;
    bool isA = blk < 448;
    int ty = isA ? 0 : 1;
#pragma unroll
    for (int g = 0; g < 3; ++g) {
        const float4* s = (const float4*)(Wx + (size_t)(g * 2 + ty) * 2048);
        float4* d = (float4*)&Wsh[g * 2048];
        for (int i = t; i < 512; i += 256) d[i] = s[i];
    }
    if (t < 192) {
        int g = t >> 6, d = t & 63;
        float c = bx[(g * 2 + ty) * 64 + d];
        if (isA) c += gb[(g * 3 + 0) * 64 + d] + gb[(g * 3 + 2) * 64 + d];
        else     c += gb[(g * 3 + 1) * 64 + d];
        cb[t] = c;
    }
    __syncthreads();
    int lane = t & 63, wid = t >> 6;
    const float* X = isA ? xA : xB;
    int N = isA ? NA : NB;
    int nblk = isA ? 448 : 64;
    int lb = isA ? blk : blk - 448;
    float cz = cb[lane], cr = cb[64 + lane], cn = cb[128 + lane];
    for (int r0 = (lb * 4 + wid) * 2; r0 < N; r0 += nblk * 8) {
#pragma unroll
        for (int rr = 0; rr < 2; ++rr) {
            int r = r0 + rr;
            if (r >= N) break;
            float xv = (lane < 32) ? X[(size_t)r * 32 + lane] : 0.f;
            float az = cz, ar = cr, an = cn;
#pragma unroll
            for (int k = 0; k < 32; ++k) {
                float xk = __shfl(xv, k, 64);
                az = fmaf(xk, Wsh[k * 64 + lane], az);
                ar = fmaf(xk, Wsh[2048 + k * 64 + lane], ar);
                an = fmaf(xk, Wsh[4096 + k * 64 + lane], an);
            }
            u32 zr = bf16r(az) | (bf16r(ar) << 16);
            u16 nn = (u16)bf16r(an);
            if (isA) { dzrA[(size_t)r * 64 + lane] = zr; dnA[(size_t)r * 64 + lane] = nn; }
            else     { dzrB[(size_t)r * 64 + lane] = zr; dnB[(size_t)r * 64 + lane] = nn; }
        }
    }
}

// ---------------- CSR build: no global atomics ----------------
__global__ void __launch_bounds__(512) hist_k(
    const int* __restrict__ d0, const int* __restrict__ d1, const int* __restrict__ d2,
    u16* __restrict__ partial)
{
    __shared__ int hcnt[CHUNK];
    int k = blockIdx.x & (NCHUNK - 1);
    int s = blockIdx.x / NCHUNK;
    int lo = k * CHUNK;
    for (int i = threadIdx.x; i < CHUNK; i += 512) hcnt[i] = 0;
    __syncthreads();
    int e0 = s * ESLICE, e1 = e0 + ESLICE;
    for (int e = e0 + threadIdx.x; e < e1; e += 512) {
        int g;
        if (e < EA2A) g = d0[e];
        else if (e < EA2A + EA2B) g = NA + d1[e - EA2A];
        else g = NA + NB + d2[e - EA2A - EA2B];
        u32 rel = (u32)(g - lo);
        if (rel < CHUNK) atomicAdd(&hcnt[rel], 1);
    }
    __syncthreads();
    u16* po = partial + (size_t)s * NCAT + lo;
    for (int i = threadIdx.x; i < CHUNK; i += 512) po[i] = (u16)hcnt[i];
}

__global__ void scan_partial(const u16* __restrict__ partial, int* __restrict__ bsum, int N)
{
    __shared__ int sd[256];
    int t = threadIdx.x;
    int i = blockIdx.x * 256 + t;
    int v = 0;
    if (i < N) {
#pragma unroll 16
        for (int s = 0; s < NSLICE; ++s) v += partial[(size_t)s * NCAT + i];
    }
    sd[t] = v;
    __syncthreads();
    for (int off = 128; off; off >>= 1) {
        if (t < off) sd[t] += sd[t + off];
        __syncthreads();
    }
    if (t == 0) bsum[blockIdx.x] = sd[0];
}

// merged: (self-scan of bsum) + rowptr + cnt + per-slice RELATIVE offsets (u16)
__global__ void scan_final(const u16* __restrict__ partial, const int* __restrict__ bsum,
                           int* __restrict__ rowptr, int* __restrict__ cnt,
                           u16* __restrict__ soff, int N)
{
    __shared__ int sd[256];
    __shared__ int rbuf[256];
    int t = threadIdx.x;
    // base = sum of bsum[j] for j < blockIdx.x
    int acc = 0;
    for (int j = t; j < blockIdx.x; j += 256) acc += bsum[j];
    rbuf[t] = acc;
    __syncthreads();
    for (int off = 128; off; off >>= 1) {
        if (t < off) rbuf[t] += rbuf[t + off];
        __syncthreads();
    }
    int base = rbuf[0];
    __syncthreads();
    int i = blockIdx.x * 256 + t;
    int v = 0;
    if (i < N) {
#pragma unroll 16
        for (int s = 0; s < NSLICE; ++s) v += partial[(size_t)s * NCAT + i];
    }
    sd[t] = v;
    __syncthreads();
    for (int off = 1; off < 256; off <<= 1) {
        int add = (t >= off) ? sd[t - off] : 0;
        __syncthreads();
        sd[t] += add;
        __syncthreads();
    }
    if (i < N) {
        int rpi = base + sd[t] - v;
        rowptr[i] = rpi;
        cnt[i] = v;
        int run = 0;   // relative to rp[i]
#pragma unroll 16
        for (int s = 0; s < NSLICE; ++s) {
            soff[(size_t)s * NCAT + i] = (u16)run;
            run += partial[(size_t)s * NCAT + i];
        }
    }
}

__global__ void __launch_bounds__(512) fill_k(
    const int* __restrict__ s0, const int* __restrict__ d0,
    const int* __restrict__ s1, const int* __restrict__ d1,
    const int* __restrict__ s2, const int* __restrict__ d2,
    const int* __restrict__ rp, const u16* __restrict__ soff, u16* __restrict__ csr)
{
    __shared__ int fpos[CHUNK];
    int k = blockIdx.x & (NCHUNK - 1);
    int s = blockIdx.x / NCHUNK;
    int lo = k * CHUNK;
    const u16* po = soff + (size_t)s * NCAT + lo;
    const int* rpo = rp + lo;
    for (int i = threadIdx.x; i < CHUNK; i += 512) fpos[i] = rpo[i] + (int)po[i];
    __syncthreads();
    int e0 = s * ESLICE, e1 = e0 + ESLICE;
    for (int e = e0 + threadIdx.x; e < e1; e += 512) {
        int g, sidx;
        const int* sp;
        if (e < EA2A) { g = d0[e]; sp = s0; sidx = e; }
        else if (e < EA2A + EA2B) { sidx = e - EA2A; g = NA + d1[sidx]; sp = s1; }
        else { sidx = e - EA2A - EA2B; g = NA + NB + d2[sidx]; sp = s2; }
        u32 rel = (u32)(g - lo);
        if (rel < CHUNK) {
            int src = sp[sidx];
            int p = atomicAdd(&fpos[rel], 1);   // LDS atomic only
            csr[p] = (u16)src;
        }
    }
}

// ---------------- GAT per-edge-type contributions ----------------
// m=0 softmax: logits are O(+-2) (weights*0.05), exp is range-safe; softmax is
// shift-invariant so this matches the reference's max-subtracted form exactly.
__device__ __forceinline__ void zr_pk(f32x2 azr[4], uint4 v, f32x2 p) {
    f32x2 x;
    x[0] = ubf(v.x << 16); x[1] = ubf(v.x & 0xffff0000u); pkfma(azr[0], x, p);
    x[0] = ubf(v.y << 16); x[1] = ubf(v.y & 0xffff0000u); pkfma(azr[1], x, p);
    x[0] = ubf(v.z << 16); x[1] = ubf(v.z & 0xffff0000u); pkfma(azr[2], x, p);
    x[0] = ubf(v.w << 16); x[1] = ubf(v.w & 0xffff0000u); pkfma(azr[3], x, p);
}

__device__ __forceinline__ void gat_zr_et(
    int gnode, int inode, int lane, int sub, int grp,
    const int* __restrict__ rp, const int* __restrict__ cnt, const u16* __restrict__ csr,
    const float2* __restrict__ als, const float2* __restrict__ ald,
    const uint4* __restrict__ xs,
    float oz[4], float orr[4])
{
    int deg = cnt[gnode];
    if (deg <= 0) return;
    int beg = rp[gnode];
    float2 ad = ald[inode];
    f32x2 azr[4];
#pragma unroll
    for (int q = 0; q < 4; ++q) { azr[q][0] = 0.f; azr[q][1] = 0.f; }
    float szl = 0.f, srl = 0.f;
    for (int base = 0; base < deg; base += 64) {
        int j = base + lane;
        int sj = 0; float pz = 0.f, pr = 0.f;
        if (j < deg) {
            sj = csr[beg + j];
            float2 al = als[sj];
            float tz = al.x + ad.x;
            float tr = al.y + ad.y;
            pz = __expf(fmaxf(tz, 0.2f * tz));
            pr = __expf(fmaxf(tr, 0.2f * tr));
        }
        szl += pz; srl += pr;
        u32 pk = (u32)sj | (bf16r(pz) << 16);   // invalid lanes: pk=0 -> contributes 0
        int c = deg - base; if (c > 64) c = 64;
        int b = 0;
        for (; b + 16 <= c; b += 16) {
            u32 k0 = (u32)__shfl((int)pk, b + grp, 64);
            u32 k1 = (u32)__shfl((int)pk, b + 4 + grp, 64);
            u32 k2 = (u32)__shfl((int)pk, b + 8 + grp, 64);
            u32 k3 = (u32)__shfl((int)pk, b + 12 + grp, 64);
            float q0 = __shfl(pr, b + grp, 64);
            float q1 = __shfl(pr, b + 4 + grp, 64);
            float q2 = __shfl(pr, b + 8 + grp, 64);
            float q3 = __shfl(pr, b + 12 + grp, 64);
            uint4 v0 = xs[(size_t)(k0 & 0xffffu) * 16 + sub];
            uint4 v1 = xs[(size_t)(k1 & 0xffffu) * 16 + sub];
            uint4 v2 = xs[(size_t)(k2 & 0xffffu) * 16 + sub];
            uint4 v3 = xs[(size_t)(k3 & 0xffffu) * 16 + sub];
            f32x2 p;
            p[0] = ubf(k0 & 0xffff0000u); p[1] = q0; zr_pk(azr, v0, p);
            p[0] = ubf(k1 & 0xffff0000u); p[1] = q1; zr_pk(azr, v1, p);
            p[0] = ubf(k2 & 0xffff0000u); p[1] = q2; zr_pk(azr, v2, p);
            p[0] = ubf(k3 & 0xffff0000u); p[1] = q3; zr_pk(azr, v3, p);
        }
        for (; b < c; b += 4) {
            u32 k0 = (u32)__shfl((int)pk, b + grp, 64);
            float q0 = __shfl(pr, b + grp, 64);
            uint4 v0 = xs[(size_t)(k0 & 0xffffu) * 16 + sub];
            f32x2 p;
            p[0] = ubf(k0 & 0xffff0000u); p[1] = q0;
            zr_pk(azr, v0, p);
        }
    }
    float sz = wsum64(szl), sr = wsum64(srl);
    float rz = 1.f / (sz + 1e-16f), rr = 1.f / (sr + 1e-16f);
#pragma unroll
    for (int q = 0; q < 4; ++q) {
        oz[q] = fmaf(azr[q][0], rz, oz[q]);
        orr[q] = fmaf(azr[q][1], rr, orr[q]);
    }
}

// n: 8-lane groups, full 128B row per group as one uint4 (8 bf16 dims/lane)
__device__ __forceinline__ void n_pk4(f32x2 ac[4], uint4 v, f32x2 p) {
    f32x2 x;
    x[0] = ubf(v.x << 16); x[1] = ubf(v.x & 0xffff0000u); pkfma(ac[0], x, p);
    x[0] = ubf(v.y << 16); x[1] = ubf(v.y & 0xffff0000u); pkfma(ac[1], x, p);
    x[0] = ubf(v.z << 16); x[1] = ubf(v.z & 0xffff0000u); pkfma(ac[2], x, p);
    x[0] = ubf(v.w << 16); x[1] = ubf(v.w & 0xffff0000u); pkfma(ac[3], x, p);
}

__device__ __forceinline__ void gat_n_et(
    int gnode, int inode, int lane, int sub8, int grp8,
    const int* __restrict__ rp, const int* __restrict__ cnt, const u16* __restrict__ csr,
    const float* __restrict__ als, const float* __restrict__ ald,
    const uint4* __restrict__ xs,        // row = 8 uint4
    f32x2 oa[4])
{
    int deg = cnt[gnode];
    if (deg <= 0) return;
    int beg = rp[gnode];
    float ad = ald[inode];
    f32x2 ac[4];
#pragma unroll
    for (int q = 0; q < 4; ++q) { ac[q][0] = 0.f; ac[q][1] = 0.f; }
    float ssl = 0.f;
    for (int base = 0; base < deg; base += 64) {
        int j = base + lane;
        int sj = 0; float pv = 0.f;
        if (j < deg) {
            sj = csr[beg + j];
            float tv = als[sj] + ad;
            pv = __expf(fmaxf(tv, 0.2f * tv));
        }
        ssl += pv;
        u32 pk = (u32)sj | (bf16r(pv) << 16);
        int c = deg - base; if (c > 64) c = 64;
        int b = 0;
        for (; b + 32 <= c; b += 32) {
            u32 kk[4];
#pragma unroll
            for (int u = 0; u < 4; ++u) kk[u] = (u32)__shfl((int)pk, b + 8 * u + grp8, 64);
            uint4 vv[4];
#pragma unroll
            for (int u = 0; u < 4; ++u) vv[u] = xs[(size_t)(kk[u] & 0xffffu) * 8 + sub8];
#pragma unroll
            for (int u = 0; u < 4; ++u) {
                f32x2 p; p[0] = ubf(kk[u] & 0xffff0000u); p[1] = p[0];
                n_pk4(ac, vv[u], p);
            }
        }
        for (; b < c; b += 8) {
            u32 k0 = (u32)__shfl((int)pk, b + grp8, 64);
            uint4 v0 = xs[(size_t)(k0 & 0xffffu) * 8 + sub8];
            f32x2 p; p[0] = ubf(k0 & 0xffff0000u); p[1] = p[0];
            n_pk4(ac, v0, p);
        }
    }
    float ss = wsum64(ssl);
    float rs = 1.f / (ss + 1e-16f);
#pragma unroll
    for (int q = 0; q < 4; ++q) {
        oa[q][0] = fmaf(ac[q][0], rs, oa[q][0]);
        oa[q][1] = fmaf(ac[q][1], rs, oa[q][1]);
    }
}

// ---------------- aggregate kernels (A and B merged) ----------------
struct ZrArgs {
    const int *rp, *cnt;
    const u16 *csr;
    const float2 *als0, *ald0, *als1, *ald1, *als2, *ald2;
    const uint4 *xs0, *xs1, *xs2;
    const u32 *dzrA, *dzrB;
    const float *hA, *hB;
    float *zA, *zB;
    u16 *rhA, *rhB;      // bf16 output (feeds n-GEMM, which quantizes anyway)
};

__global__ void __launch_bounds__(256) aggregate_zr_k(ZrArgs P)
{
    int t = threadIdx.x, lane = t & 63, wid = t >> 6;
    int sub = lane & 15, grp = lane >> 4;
    float oz[4] = {0.f, 0.f, 0.f, 0.f}, orr[4] = {0.f, 0.f, 0.f, 0.f};
    int blk = blockIdx.x;
    const u32* dzr; const float* Hp; float* Zp; u16* RHp;
    if (blk < NA / 4) {
        int i = blk * 4 + wid;
        gat_zr_et(i, i, lane, sub, grp, P.rp, P.cnt, P.csr, P.als0, P.ald0, P.xs0, oz, orr);
        gat_zr_et(NA + NB + i, i, lane, sub, grp, P.rp, P.cnt, P.csr, P.als2, P.ald2, P.xs2, oz, orr);
        dzr = P.dzrA + (size_t)i * 64; Hp = P.hA + (size_t)i * 64;
        Zp = P.zA + (size_t)i * 64; RHp = P.rhA + (size_t)i * 64;
    } else {
        int i = (blk - NA / 4) * 4 + wid;
        gat_zr_et(NA + i, i, lane, sub, grp, P.rp, P.cnt, P.csr, P.als1, P.ald1, P.xs1, oz, orr);
        dzr = P.dzrB + (size_t)i * 64; Hp = P.hB + (size_t)i * 64;
        Zp = P.zB + (size_t)i * 64; RHp = P.rhB + (size_t)i * 64;
    }
#pragma unroll
    for (int q = 0; q < 4; ++q) {
        oz[q] += __shfl_xor(oz[q], 16, 64); oz[q] += __shfl_xor(oz[q], 32, 64);
        orr[q] += __shfl_xor(orr[q], 16, 64); orr[q] += __shfl_xor(orr[q], 32, 64);
    }
    if (grp == 0) {
        uint4 d = *(const uint4*)(dzr + sub * 4);
        float4 h = *(const float4*)(Hp + sub * 4);
        float z0 = sigm(oz[0] + ubf(d.x << 16)), r0 = sigm(orr[0] + ubf(d.x & 0xffff0000u)) * h.x;
        float z1 = sigm(oz[1] + ubf(d.y << 16)), r1 = sigm(orr[1] + ubf(d.y & 0xffff0000u)) * h.y;
        float z2 = sigm(oz[2] + ubf(d.z << 16)), r2 = sigm(orr[2] + ubf(d.z & 0xffff0000u)) * h.z;
        float z3 = sigm(oz[3] + ubf(d.w << 16)), r3 = sigm(orr[3] + ubf(d.w & 0xffff0000u)) * h.w;
        *(float4*)(Zp + sub * 4) = make_float4(z0, z1, z2, z3);
        uint2 rhp;
        rhp.x = cvtpk(r0, r1);
        rhp.y = cvtpk(r2, r3);
        *(uint2*)(RHp + sub * 4) = rhp;
    }
}

struct NArgs {
    const int *rp, *cnt;
    const u16 *csr;
    const float *als0, *ald0, *als1, *ald1, *als2, *ald2;
    const uint4 *xs0, *xs1, *xs2;
    const u16 *dnA, *dnB;
    const float *hA, *hB, *zA, *zB;
    float *outA, *outB;
};

__global__ void __launch_bounds__(256) aggregate_n_k(NArgs P)
{
    int t = threadIdx.x, lane = t & 63, wid = t >> 6;
    int sub8 = lane & 7, grp8 = lane >> 3;
    f32x2 oa[4];
#pragma unroll
    for (int q = 0; q < 4; ++q) { oa[q][0] = 0.f; oa[q][1] = 0.f; }
    int blk = blockIdx.x;
    const u16* dn; const float *Hp, *Zp; float* Op;
    if (blk < NA / 4) {
        int i = blk * 4 + wid;
        gat_n_et(i, i, lane, sub8, grp8, P.rp, P.cnt, P.csr, P.als0, P.ald0, P.xs0, oa);
        gat_n_et(NA + NB + i, i, lane, sub8, grp8, P.rp, P.cnt, P.csr, P.als2, P.ald2, P.xs2, oa);
        dn = P.dnA + (size_t)i * 64; Hp = P.hA + (size_t)i * 64;
        Zp = P.zA + (size_t)i * 64; Op = P.outA + (size_t)i * 64;
    } else {
        int i = (blk - NA / 4) * 4 + wid;
        gat_n_et(NA + i, i, lane, sub8, grp8, P.rp, P.cnt, P.csr, P.als1, P.ald1, P.xs1, oa);
        dn = P.dnB + (size_t)i * 64; Hp = P.hB + (size_t)i * 64;
        Zp = P.zB + (size_t)i * 64; Op = P.outB + (size_t)i * 64;
    }
#pragma unroll
    for (int q = 0; q < 4; ++q) {
#pragma unroll
        for (int e = 0; e < 2; ++e) {
            oa[q][e] += __shfl_xor(oa[q][e], 8, 64);
            oa[q][e] += __shfl_xor(oa[q][e], 16, 64);
            oa[q][e] += __shfl_xor(oa[q][e], 32, 64);
        }
    }
    if (grp8 == 0) {
        uint4 d = *(const uint4*)(dn + sub8 * 8);
        float4 h0 = *(const float4*)(Hp + sub8 * 8);
        float4 h1 = *(const float4*)(Hp + sub8 * 8 + 4);
        float4 zv0 = *(const float4*)(Zp + sub8 * 8);
        float4 zv1 = *(const float4*)(Zp + sub8 * 8 + 4);
        float pre[8];
        pre[0] = oa[0][0] + ubf(d.x << 16); pre[1] = oa[0][1] + ubf(d.x & 0xffff0000u);
        pre[2] = oa[1][0] + ubf(d.y << 16); pre[3] = oa[1][1] + ubf(d.y & 0xffff0000u);
        pre[4] = oa[2][0] + ubf(d.z << 16); pre[5] = oa[2][1] + ubf(d.z & 0xffff0000u);
        pre[6] = oa[3][0] + ubf(d.w << 16); pre[7] = oa[3][1] + ubf(d.w & 0xffff0000u);
        float hh[8] = {h0.x, h0.y, h0.z, h0.w, h1.x, h1.y, h1.z, h1.w};
        float zz[8] = {zv0.x, zv0.y, zv0.z, zv0.w, zv1.x, zv1.y, zv1.z, zv1.w};
        float o[8];
#pragma unroll
        for (int q = 0; q < 8; ++q) {
            float x2 = fminf(fmaxf(pre[q] * 2.f, -30.f), 30.f);
            float ex = __expf(x2);
            float nv = (ex - 1.f) / (ex + 1.f);
            o[q] = (1.f - zz[q]) * nv + zz[q] * hh[q];
        }
        *(float4*)(Op + sub8 * 8) = make_float4(o[0], o[1], o[2], o[3]);
        *(float4*)(Op + sub8 * 8 + 4) = make_float4(o[4], o[5], o[6], o[7]);
    }
}

// ---------------- host side ----------------
extern "C" void kernel_launch(void* const* d_in, const int* in_sizes, int n_in,
                              void* d_out, int out_size, void* d_ws, size_t ws_size,
                              hipStream_t stream)
{
    (void)in_sizes; (void)n_in; (void)out_size; (void)ws_size;
    const float* x_a = (const float*)d_in[0];
    const float* x_b = (const float*)d_in[1];
    const float* h_a = (const float*)d_in[2];
    const float* h_b = (const float*)d_in[3];
    const float* Wx  = (const float*)d_in[4];
    const float* bx  = (const float*)d_in[5];
    const float* gws = (const float*)d_in[6];
    const float* gwd = (const float*)d_in[7];
    const float* gas = (const float*)d_in[8];
    const float* gad = (const float*)d_in[9];
    const float* gb  = (const float*)d_in[10];
    const int* ea2a_s = (const int*)d_in[11];
    const int* ea2a_d = (const int*)d_in[12];
    const int* ea2b_s = (const int*)d_in[13];
    const int* ea2b_d = (const int*)d_in[14];
    const int* eb2a_s = (const int*)d_in[15];
    const int* eb2a_d = (const int*)d_in[16];
    float* out = (float*)d_out;

    char* w = (char*)d_ws;
    auto alloc = [&](size_t bytes) -> char* {
        char* p = w;
        w += (bytes + 255) & ~(size_t)255;
        return p;
    };
    char* xsblk = alloc((size_t)(NA + NA + NB) * 64 * 4);
    u32* xs_zr0 = (u32*)xsblk;
    u32* xs_zr1 = (u32*)(xsblk + (size_t)NA * 64 * 4);
    u32* xs_zr2 = (u32*)(xsblk + (size_t)(NA + NA) * 64 * 4);
    u16* xs_n0 = (u16*)xsblk;
    u16* xs_n1 = (u16*)(xsblk + (size_t)NA * 64 * 2);
    u16* xs_n2 = (u16*)(xsblk + (size_t)(NA + NA) * 64 * 2);
    char* alblk = alloc((size_t)(4 * NA + 2 * NB) * 2 * 4);
    float* als_zr0 = (float*)alblk;
    float* als_zr1 = als_zr0 + (size_t)NA * 2;
    float* als_zr2 = als_zr1 + (size_t)NA * 2;
    float* ald_zr0 = als_zr2 + (size_t)NB * 2;
    float* ald_zr1 = ald_zr0 + (size_t)NA * 2;
    float* ald_zr2 = ald_zr1 + (size_t)NB * 2;
    float* als_n0 = (float*)alblk;
    float* als_n1 = als_n0 + NA;
    float* als_n2 = als_n1 + NA;
    float* ald_n0 = als_n2 + NB;
    float* ald_n1 = ald_n0 + NA;
    float* ald_n2 = ald_n1 + NB;
    float* zbuf  = (float*)alloc((size_t)(NA + NB) * 64 * 4);
    u16* rhbuf = (u16*)alloc((size_t)(NA + NB) * 64 * 2);
    u32* dzrA = (u32*)alloc((size_t)NA * 64 * 4);
    u32* dzrB = (u32*)alloc((size_t)NB * 64 * 4);
    u16* dnA = (u16*)alloc((size_t)NA * 64 * 2);
    u16* dnB = (u16*)alloc((size_t)NB * 64 * 2);
    u16* partial = (u16*)alloc((size_t)NSLICE * NCAT * 2);
    u16* soff    = (u16*)alloc((size_t)NSLICE * NCAT * 2);
    int* cnt = (int*)alloc((size_t)NCAT * 4);
    int* rp  = (int*)alloc((size_t)NCAT * 4);
    u16* csr = (u16*)alloc((size_t)ETOT * 2);
    int* bsum = (int*)alloc(512 * 4);
    u16* nscr = (u16*)alloc((size_t)NB * 64 * 2);   // dummy second output for n-B region

    const int nbC = (NCAT + 255) / 256;

    // ---- CSR build (4 kernels, no global atomics, no memset) ----
    hist_k<<<NCHUNK * NSLICE, 512, 0, stream>>>(ea2a_d, ea2b_d, eb2a_d, partial);
    scan_partial<<<nbC, 256, 0, stream>>>(partial, bsum, NCAT);
    scan_final<<<nbC, 256, 0, stream>>>(partial, bsum, rp, cnt, soff, NCAT);
    fill_k<<<NCHUNK * NSLICE, 512, 0, stream>>>(ea2a_s, ea2a_d, ea2b_s, ea2b_d, eb2a_s, eb2a_d,
                                                rp, soff, csr);

    // ---- dense precompute (all 3 gates, both node types) ----
    gemm_x_k<<<512, 256, 0, stream>>>(x_a, x_b, Wx, bx, gb, dzrA, dzrB, dnA, dnB);

    u16* rh_a = rhbuf;
    u16* rh_b = rhbuf + (size_t)NA * 64;
    float* z_a = zbuf;
    float* z_b = zbuf + (size_t)NA * 64;

    // ---- z+r MFMA GEMMs (one multi-region launch) ----
    {
        MmMulti M{};
        M.n0 = 320; M.n1 = 320;   // region2 = 80 blocks
        // region 0: (z,a2a)+(r,a2a) on h_a + 8 scalar streams
        M.r[0].H = h_a; M.r[0].ntiles = NA / 16;
        M.r[0].W0 = gws + 0 * 4096; M.r[0].W1 = gws + 3 * 4096;
        M.r[0].XS = xs_zr0;
        M.r[0].SW[0] = gws + 0 * 4096; M.r[0].SA[0] = gas + 0 * 64; M.r[0].SOUT[0] = als_zr0;
        M.r[0].SW[1] = gws + 3 * 4096; M.r[0].SA[1] = gas + 3 * 64; M.r[0].SOUT[1] = als_zr0 + 1;
        M.r[0].SW[2] = gws + 1 * 4096; M.r[0].SA[2] = gas + 1 * 64; M.r[0].SOUT[2] = als_zr1;
        M.r[0].SW[3] = gws + 4 * 4096; M.r[0].SA[3] = gas + 4 * 64; M.r[0].SOUT[3] = als_zr1 + 1;
        M.r[0].SW[4] = gwd + 0 * 4096; M.r[0].SA[4] = gad + 0 * 64; M.r[0].SOUT[4] = ald_zr0;
        M.r[0].SW[5] = gwd + 3 * 4096; M.r[0].SA[5] = gad + 3 * 64; M.r[0].SOUT[5] = ald_zr0 + 1;
        M.r[0].SW[6] = gwd + 2 * 4096; M.r[0].SA[6] = gad + 2 * 64; M.r[0].SOUT[6] = ald_zr2;
        M.r[0].SW[7] = gwd + 5 * 4096; M.r[0].SA[7] = gad + 5 * 64; M.r[0].SOUT[7] = ald_zr2 + 1;
        M.r[0].sstride = 2; M.r[0].nsc = 8;
        // region 1: (z,a2b)+(r,a2b) on h_a
        M.r[1].H = h_a; M.r[1].ntiles = NA / 16;
        M.r[1].W0 = gws + 1 * 4096; M.r[1].W1 = gws + 4 * 4096;
        M.r[1].XS = xs_zr1;
        M.r[1].sstride = 1; M.r[1].nsc = 0;
        // region 2: (z,b2a)+(r,b2a) on h_b + 4 scalar streams
        M.r[2].H = h_b; M.r[2].ntiles = NB / 16;
        M.r[2].W0 = gws + 2 * 4096; M.r[2].W1 = gws + 5 * 4096;
        M.r[2].XS = xs_zr2;
        M.r[2].SW[0] = gws + 2 * 4096; M.r[2].SA[0] = gas + 2 * 64; M.r[2].SOUT[0] = als_zr2;
        M.r[2].SW[1] = gws + 5 * 4096; M.r[2].SA[1] = gas + 5 * 64; M.r[2].SOUT[1] = als_zr2 + 1;
        M.r[2].SW[2] = gwd + 1 * 4096; M.r[2].SA[2] = gad + 1 * 64; M.r[2].SOUT[2] = ald_zr1;
        M.r[2].SW[3] = gwd + 4 * 4096; M.r[2].SA[3] = gad + 4 * 64; M.r[2].SOUT[3] = ald_zr1 + 1;
        M.r[2].sstride = 2; M.r[2].nsc = 4;
        gemm_mfma<2, 1, 0><<<720, 256, 0, stream>>>(M);
    }

    // ---- z+r aggregation ----
    {
        ZrArgs P{};
        P.rp = rp; P.cnt = cnt; P.csr = csr;
        P.als0 = (const float2*)als_zr0; P.ald0 = (const float2*)ald_zr0;
        P.als1 = (const float2*)als_zr1; P.ald1 = (const float2*)ald_zr1;
        P.als2 = (const float2*)als_zr2; P.ald2 = (const float2*)ald_zr2;
        P.xs0 = (const uint4*)xs_zr0; P.xs1 = (const uint4*)xs_zr1; P.xs2 = (const uint4*)xs_zr2;
        P.dzrA = dzrA; P.dzrB = dzrB;
        P.hA = h_a; P.hB = h_b;
        P.zA = z_a; P.zB = z_b; P.rhA = rh_a; P.rhB = rh_b;
        aggregate_zr_k<<<(NA + NB) / 4, 256, 0, stream>>>(P);
    }

    // ---- n MFMA GEMMs (one multi-region launch; H is bf16 rh) ----
    {
        MmMulti M{};
        M.n0 = 320; M.n1 = 80;   // region2 unused (grid = 400)
        // region 0: (n,a2a)->xs_n0, (n,a2b)->xs_n1, reads rh_a once
        M.r[0].H = rh_a; M.r[0].ntiles = NA / 16;
        M.r[0].W0 = gws + 6 * 4096; M.r[0].W1 = gws + 7 * 4096;
        M.r[0].XS = xs_n0; M.r[0].XS1 = xs_n1;
        M.r[0].SW[0] = gws + 6 * 4096; M.r[0].SA[0] = gas + 6 * 64; M.r[0].SOUT[0] = als_n0;
        M.r[0].SW[1] = gws + 7 * 4096; M.r[0].SA[1] = gas + 7 * 64; M.r[0].SOUT[1] = als_n1;
        M.r[0].SW[2] = gwd + 6 * 4096; M.r[0].SA[2] = gad + 6 * 64; M.r[0].SOUT[2] = ald_n0;
        M.r[0].SW[3] = gwd + 8 * 4096; M.r[0].SA[3] = gad + 8 * 64; M.r[0].SOUT[3] = ald_n2;
        M.r[0].sstride = 1; M.r[0].nsc = 4;
        // region 1: (n,b2a) on rh_b (second matrix duplicated into scratch)
        M.r[1].H = rh_b; M.r[1].ntiles = NB / 16;
        M.r[1].W0 = gws + 8 * 4096; M.r[1].W1 = gws + 8 * 4096;
        M.r[1].XS = xs_n2; M.r[1].XS1 = nscr;
        M.r[1].SW[0] = gws + 8 * 4096; M.r[1].SA[0] = gas + 8 * 64; M.r[1].SOUT[0] = als_n2;
        M.r[1].SW[1] = gwd + 7 * 4096; M.r[1].SA[1] = gad + 7 * 64; M.r[1].SOUT[1] = ald_n1;
        M.r[1].sstride = 1; M.r[1].nsc = 2;
        gemm_mfma<2, 0, 1><<<400, 256, 0, stream>>>(M);
    }

    // ---- n aggregation + GRU combine ----
    {
        NArgs P{};
        P.rp = rp; P.cnt = cnt; P.csr = csr;
        P.als0 = als_n0; P.ald0 = ald_n0;
        P.als1 = als_n1; P.ald1 = ald_n1;
        P.als2 = als_n2; P.ald2 = ald_n2;
        P.xs0 = (const uint4*)xs_n0; P.xs1 = (const uint4*)xs_n1; P.xs2 = (const uint4*)xs_n2;
        P.dnA = dnA; P.dnB = dnB;
        P.hA = h_a; P.hB = h_b; P.zA = z_a; P.zB = z_b;
        P.outA = out; P.outB = out + (size_t)NA * 64;
        aggregate_n_k<<<(NA + NB) / 4, 256, 0, stream>>>(P);
    }
}